// Round 1
// baseline (4348.566 us; speedup 1.0000x reference)
//
#include <hip/hip_runtime.h>
#include <hip/hip_bf16.h>

// Problem constants (static per reference)
#define NN   512    // nodes
#define EE   512    // edges == nb-graph nodes (En)
#define MM   16384  // nb-graph edges
#define FINN 64
#define HIDN 128

__device__ __forceinline__ float silu_f(float v) { return v / (1.0f + __expf(-v)); }

// ---------------- K1: per original edge: coord_diff + efn = MLP([h_r|h_c]) ----
__global__ __launch_bounds__(128) void k_edge(
    const float* __restrict__ h, const float* __restrict__ x,
    const int* __restrict__ edges,
    const float* __restrict__ ew1, const float* __restrict__ eb1,
    const float* __restrict__ ew2, const float* __restrict__ eb2,
    float* __restrict__ coord_diff, float* __restrict__ efn) {
  __shared__ float hin[128];
  __shared__ float hs[128];
  int e = blockIdx.x;
  int t = threadIdx.x;
  int r = edges[e], c = edges[EE + e];
  if (t < 3) coord_diff[e * 3 + t] = x[r * 3 + t] - x[c * 3 + t];
  if (t < 64) { hin[t] = h[r * 64 + t]; hin[64 + t] = h[c * 64 + t]; }
  __syncthreads();
  float acc = eb1[t];
  for (int k = 0; k < 128; ++k) acc += hin[k] * ew1[k * 128 + t];
  hs[t] = silu_f(acc);
  __syncthreads();
  if (t < 64) {
    float o = eb2[t];
    for (int k = 0; k < 128; ++k) o += hs[k] * ew2[k * 64 + t];
    efn[e * 64 + t] = o;
  }
}

// ---------------- K2: nb_feat (pe | efn_a*efn_b) scatter-add into dense T ----
__global__ __launch_bounds__(256) void k_nbscatter(
    const int* __restrict__ nb_edge,
    const float* __restrict__ coord_diff,
    const float* __restrict__ efn,
    float* __restrict__ T) {
  int tid = blockIdx.x * blockDim.x + threadIdx.x;
  if (tid >= MM * 96) return;
  int m = tid / 96, c = tid % 96;
  int a = nb_edge[m], b = nb_edge[MM + m];
  float val;
  if (c < 32) {
    float vtv = coord_diff[a * 3 + 0] * coord_diff[b * 3 + 0]
              + coord_diff[a * 3 + 1] * coord_diff[b * 3 + 1]
              + coord_diff[a * 3 + 2] * coord_diff[b * 3 + 2];
    int i = c >> 1;
    // ang = vtv * (D/2) / 10000^(i/16); ln(10000)/16 = 0.57564627324851143
    float ang = vtv * 16.0f * __expf(-0.57564627324851143f * (float)i);
    val = (c & 1) ? cosf(ang) : sinf(ang);
  } else {
    int f = c - 32;
    val = efn[a * 64 + f] * efn[b * 64 + f];
  }
  atomicAdd(&T[(a * 512 + b) * 96 + c], val);
}

// ---------------- K3: dense MLP 96->128(silu)->64 over cells, bf16 output ----
// 64 cells/block, 256 threads; thread = (hg = t>>3 [32], cg = t&7 [8])
// layer1: thread owns 8 cells x 4 h; layer2: 8 cells x 2 h.
__global__ __launch_bounds__(256) void k_mlp96(
    const float* __restrict__ T,
    const float* __restrict__ w1, const float* __restrict__ b1,
    const float* __restrict__ w2, const float* __restrict__ b2,
    __hip_bfloat16* __restrict__ outm) {
  __shared__ float XH[64 * 129];   // X phase stride 97, hidden phase stride 129
  __shared__ float Wc[48 * 128];   // weight chunk (layer2 chunk 64x64 also fits)
  int t = threadIdx.x;
  int cg = t & 7, hg = t >> 3;
  int cell0 = blockIdx.x * 64;
  for (int e = t; e < 64 * 96; e += 256)
    XH[(e / 96) * 97 + (e % 96)] = T[cell0 * 96 + e];
  float acc[8][4];
#pragma unroll
  for (int i = 0; i < 8; ++i)
#pragma unroll
    for (int j = 0; j < 4; ++j) acc[i][j] = 0.f;
  for (int kc = 0; kc < 96; kc += 48) {
    __syncthreads();
    for (int e = t; e < 48 * 128; e += 256) Wc[e] = w1[kc * 128 + e];
    __syncthreads();
    for (int kk = 0; kk < 48; ++kk) {
      int k = kc + kk;
      float xv[8];
#pragma unroll
      for (int cc = 0; cc < 8; ++cc) xv[cc] = XH[(cg * 8 + cc) * 97 + k];
      float4 wv = *(const float4*)&Wc[kk * 128 + hg * 4];
#pragma unroll
      for (int cc = 0; cc < 8; ++cc) {
        acc[cc][0] += xv[cc] * wv.x; acc[cc][1] += xv[cc] * wv.y;
        acc[cc][2] += xv[cc] * wv.z; acc[cc][3] += xv[cc] * wv.w;
      }
    }
  }
  __syncthreads();
#pragma unroll
  for (int cc = 0; cc < 8; ++cc)
#pragma unroll
    for (int hh = 0; hh < 4; ++hh) {
      int hc = hg * 4 + hh;
      XH[(cg * 8 + cc) * 129 + hc] = silu_f(acc[cc][hh] + b1[hc]);
    }
  __syncthreads();
  float acc2[8][2];
#pragma unroll
  for (int i = 0; i < 8; ++i) { acc2[i][0] = 0.f; acc2[i][1] = 0.f; }
  for (int kc = 0; kc < 128; kc += 64) {
    for (int e = t; e < 64 * 64; e += 256) Wc[e] = w2[kc * 64 + e];
    __syncthreads();
    for (int kk = 0; kk < 64; ++kk) {
      int k = kc + kk;
      float xv[8];
#pragma unroll
      for (int cc = 0; cc < 8; ++cc) xv[cc] = XH[(cg * 8 + cc) * 129 + k];
      float2 wv = *(const float2*)&Wc[kk * 64 + hg * 2];
#pragma unroll
      for (int cc = 0; cc < 8; ++cc) {
        acc2[cc][0] += xv[cc] * wv.x; acc2[cc][1] += xv[cc] * wv.y;
      }
    }
    __syncthreads();
  }
#pragma unroll
  for (int cc = 0; cc < 8; ++cc)
#pragma unroll
    for (int hh = 0; hh < 2; ++hh) {
      int hc = hg * 2 + hh;
      int cell = cell0 + cg * 8 + cc;
      outm[cell * 64 + hc] = __float2bfloat16(acc2[cc][hh] + b2[hc]);
    }
}

// ---------------- K4: mult[i,j,f] = sum_k m1[i,k,f]*m2[k,j,f] (16x16 tile) ----
// 256 thr: thread = (f = t&63, quad = t>>6 -> 8x8 cell sub-tile), acc[8][8].
__global__ __launch_bounds__(256) void k_einsum(
    const __hip_bfloat16* __restrict__ m1,
    const __hip_bfloat16* __restrict__ m2,
    __hip_bfloat16* __restrict__ mult) {
  __shared__ float smem[8192];           // s1[16][4][64] | s2[4][16][64]; reused as bf16 ts[16384]
  float* s1 = smem;
  float* s2 = smem + 4096;
  int t = threadIdx.x;
  int f = t & 63;
  int quad = t >> 6;
  int qi = (quad >> 1) * 8, qj = (quad & 1) * 8;
  int bi = blockIdx.x >> 5, bj = blockIdx.x & 31;
  int i0 = bi * 16, j0 = bj * 16;
  float acc[8][8];
#pragma unroll
  for (int i = 0; i < 8; ++i)
#pragma unroll
    for (int j = 0; j < 8; ++j) acc[i][j] = 0.f;
  for (int k0 = 0; k0 < 512; k0 += 4) {
    __syncthreads();
    for (int e = t; e < 4096; e += 256) {
      int i = e >> 8, rem = e & 255;        // rem = kk*64+f (4 consecutive cells)
      s1[e] = __bfloat162float(m1[((i0 + i) * 512 + k0) * 64 + rem]);
    }
    for (int e = t; e < 4096; e += 256) {
      int kk = e >> 10, rem = e & 1023;     // rem = j*64+f
      s2[e] = __bfloat162float(m2[((k0 + kk) * 512 + j0) * 64 + rem]);
    }
    __syncthreads();
#pragma unroll
    for (int kk = 0; kk < 4; ++kk) {
      float av[8], bv[8];
#pragma unroll
      for (int ii = 0; ii < 8; ++ii) av[ii] = s1[((qi + ii) * 4 + kk) * 64 + f];
#pragma unroll
      for (int jj = 0; jj < 8; ++jj) bv[jj] = s2[(kk * 16 + qj + jj) * 64 + f];
#pragma unroll
      for (int jj = 0; jj < 8; ++jj)
#pragma unroll
        for (int ii = 0; ii < 8; ++ii) acc[ii][jj] += av[ii] * bv[jj];
    }
  }
  __syncthreads();
  __hip_bfloat16* ts = (__hip_bfloat16*)smem;  // [cell(16x16)][f] bf16 = 32KB
#pragma unroll
  for (int jj = 0; jj < 8; ++jj)
#pragma unroll
    for (int ii = 0; ii < 8; ++ii)
      ts[((qi + ii) * 16 + qj + jj) * 64 + f] = __float2bfloat16(acc[ii][jj]);
  __syncthreads();
  for (int e = t; e < 16384; e += 256) {
    int i = e >> 10, rem = e & 1023;          // rem = j*64+f
    mult[((i0 + i) * 512 + j0) * 64 + rem] = ts[e];
  }
}

// ------- K5: z = [T|mult]@p3w1+b1, s=silu(z); reduce s over rows/cols/diag ----
// 8x8 cell tile per block (bi,bj); 256 thr: t = hg*8+cg; thread = row ci=cg, all 8 cj, 4 h.
__global__ __launch_bounds__(256) void k_tout_reduce(
    const float* __restrict__ T, const __hip_bfloat16* __restrict__ mult,
    const float* __restrict__ w1, const float* __restrict__ b1,
    float* __restrict__ row_part, float* __restrict__ col_part,
    float* __restrict__ diag_silu) {
  __shared__ float Xs[64 * 161];  // 64 cells x 160 (pad 161)
  __shared__ float Ws[32 * 128];
  int t = threadIdx.x;
  int cg = t & 7, hg = t >> 3;
  int bi = blockIdx.x >> 6, bj = blockIdx.x & 63;
  int i0 = bi * 8, j0 = bj * 8;
  for (int e = t; e < 64 * 96; e += 256) {
    int c = e / 96, k = e % 96;
    Xs[c * 161 + k] = T[((i0 + (c >> 3)) * 512 + j0 + (c & 7)) * 96 + k];
  }
  for (int e = t; e < 64 * 64; e += 256) {
    int c = e >> 6, fx = e & 63;
    Xs[c * 161 + 96 + fx] =
        __bfloat162float(mult[((i0 + (c >> 3)) * 512 + j0 + (c & 7)) * 64 + fx]);
  }
  float acc[8][4];
#pragma unroll
  for (int i = 0; i < 8; ++i)
#pragma unroll
    for (int j = 0; j < 4; ++j) acc[i][j] = 0.f;
  for (int k0 = 0; k0 < 160; k0 += 32) {
    __syncthreads();
    for (int e = t; e < 4096; e += 256) Ws[e] = w1[k0 * 128 + e];
    __syncthreads();
    for (int kk = 0; kk < 32; ++kk) {
      int k = k0 + kk;
      float4 wv = *(const float4*)&Ws[kk * 128 + hg * 4];
      float xv[8];
#pragma unroll
      for (int cj = 0; cj < 8; ++cj) xv[cj] = Xs[(cg * 8 + cj) * 161 + k];
#pragma unroll
      for (int cj = 0; cj < 8; ++cj) {
        acc[cj][0] += xv[cj] * wv.x; acc[cj][1] += xv[cj] * wv.y;
        acc[cj][2] += xv[cj] * wv.z; acc[cj][3] += xv[cj] * wv.w;
      }
    }
  }
  float s[8][4];
  float4 bb = *(const float4*)&b1[hg * 4];
#pragma unroll
  for (int cj = 0; cj < 8; ++cj) {
    s[cj][0] = silu_f(acc[cj][0] + bb.x);
    s[cj][1] = silu_f(acc[cj][1] + bb.y);
    s[cj][2] = silu_f(acc[cj][2] + bb.z);
    s[cj][3] = silu_f(acc[cj][3] + bb.w);
  }
  // rowsum over cj (thread-local); row i = i0+cg, h = hg*4..+3
  float4 rs = make_float4(0.f, 0.f, 0.f, 0.f);
#pragma unroll
  for (int cj = 0; cj < 8; ++cj) { rs.x += s[cj][0]; rs.y += s[cj][1]; rs.z += s[cj][2]; rs.w += s[cj][3]; }
  *(float4*)&row_part[(bj * 512 + i0 + cg) * 128 + hg * 4] = rs;
  // colsum over ci = cg: butterfly over 8 consecutive lanes
#pragma unroll
  for (int cj = 0; cj < 8; ++cj) {
    float4 cs = make_float4(s[cj][0], s[cj][1], s[cj][2], s[cj][3]);
#pragma unroll
    for (int msk = 1; msk < 8; msk <<= 1) {
      cs.x += __shfl_xor(cs.x, msk); cs.y += __shfl_xor(cs.y, msk);
      cs.z += __shfl_xor(cs.z, msk); cs.w += __shfl_xor(cs.w, msk);
    }
    if (cg == 0)
      *(float4*)&col_part[(bi * 512 + j0 + cj) * 128 + hg * 4] = cs;
  }
  if (bi == bj) {
#pragma unroll
    for (int cj = 0; cj < 8; ++cj)
      if (cj == cg)
        *(float4*)&diag_silu[(i0 + cg) * 128 + hg * 4] =
            make_float4(s[cj][0], s[cj][1], s[cj][2], s[cj][3]);
  }
}

// ---------------- K6a: reduce 64 partial slices -> rowsum_silu / colsum_silu --
__global__ __launch_bounds__(256) void k_sumparts(
    const float* __restrict__ row_part, const float* __restrict__ col_part,
    float* __restrict__ rowsum, float* __restrict__ colsum) {
  int i = blockIdx.x, t = threadIdx.x;
  const float* src = (t < 128) ? row_part : col_part;
  float* dst = (t < 128) ? rowsum : colsum;
  int hc = t & 127;
  float a = 0.f;
  for (int p = 0; p < 64; ++p) a += src[(p * 512 + i) * 128 + hc];
  dst[i * 128 + hc] = a;
}

// ------- K6b: second layer of p3 MLP applied to reduced silu sums -------------
__global__ __launch_bounds__(64) void k_tout2(
    const float* __restrict__ diag_silu, const float* __restrict__ rowsum_silu,
    const float* __restrict__ colsum_silu,
    const float* __restrict__ w2, const float* __restrict__ b2,
    float* __restrict__ diag_T, float* __restrict__ row_T, float* __restrict__ col_T) {
  __shared__ float in[128];
  int e = blockIdx.x, which = blockIdx.y, t = threadIdx.x;
  const float* src = (which == 0) ? diag_silu : (which == 1) ? rowsum_silu : colsum_silu;
  in[t] = src[e * 128 + t]; in[64 + t] = src[e * 128 + 64 + t];
  __syncthreads();
  float a = 0.f;
  for (int k = 0; k < 128; ++k) a += in[k] * w2[k * 64 + t];
  float bias = b2[t] * ((which == 0) ? 1.0f : 512.0f);
  float* dst = (which == 0) ? diag_T : (which == 1) ? row_T : col_T;
  dst[e * 64 + t] = a + bias;
}

// ---------------- K6c: tot / tr ----------------------------------------------
__global__ __launch_bounds__(128) void k_totr(
    const float* __restrict__ row_T, const float* __restrict__ diag_T,
    float* __restrict__ tot, float* __restrict__ tr) {
  int t = threadIdx.x;
  const float* src = (t < 64) ? row_T : diag_T;
  int f = t & 63;
  float a = 0.f;
  for (int e = 0; e < 512; ++e) a += src[e * 64 + f];
  if (t < 64) tot[f] = a; else tr[f] = a;
}

// ---------------- K6d: nb_t1 = [diag|row|col|tot|tr] @ ign_w + ign_b ---------
__global__ __launch_bounds__(64) void k_nbt1(
    const float* __restrict__ diag_T, const float* __restrict__ row_T,
    const float* __restrict__ col_T, const float* __restrict__ tot,
    const float* __restrict__ tr,
    const float* __restrict__ gw, const float* __restrict__ gb,
    float* __restrict__ nb_t1) {
  __shared__ float in[320];
  int e = blockIdx.x, t = threadIdx.x;
  in[t] = diag_T[e * 64 + t]; in[64 + t] = row_T[e * 64 + t];
  in[128 + t] = col_T[e * 64 + t]; in[192 + t] = tot[t]; in[256 + t] = tr[t];
  __syncthreads();
  float a = gb[t];
  for (int k = 0; k < 320; ++k) a += in[k] * gw[k * 64 + t];
  nb_t1[e * 64 + t] = a;
}

// ----- K7: coord weight w_e, seg/cnt/nb_t0 scatters, edge_attr passthrough ---
__global__ __launch_bounds__(128) void k_edge_out(
    const int* __restrict__ edges, const float* __restrict__ coord_diff,
    const float* __restrict__ nb_t1, const float* __restrict__ edge_attr,
    const float* __restrict__ cw1, const float* __restrict__ cb1,
    const float* __restrict__ cw2,
    float* __restrict__ seg, float* __restrict__ cnt, float* __restrict__ nb_t0,
    float* __restrict__ out_ea) {
  __shared__ float in[64];
  __shared__ float red[128];
  int e = blockIdx.x, t = threadIdx.x;
  if (t < 64) in[t] = nb_t1[e * 64 + t];
  __syncthreads();
  float a = cb1[t];
  for (int k = 0; k < 64; ++k) a += in[k] * cw1[k * 128 + t];
  red[t] = silu_f(a) * cw2[t];
  __syncthreads();
  for (int s2 = 64; s2 > 0; s2 >>= 1) {
    if (t < s2) red[t] += red[t + s2];
    __syncthreads();
  }
  float w = red[0];
  int r = edges[e];
  if (t < 3) atomicAdd(&seg[r * 3 + t], coord_diff[e * 3 + t] * w);
  if (t == 64) atomicAdd(&cnt[r], 1.0f);
  if (t < 64) atomicAdd(&nb_t0[r * 64 + t], in[t]);
  if (t < 4) out_ea[e * 4 + t] = edge_attr[e * 4 + t];
}

// ---------------- K8: x_new and h_new ----------------------------------------
__global__ __launch_bounds__(128) void k_node_out(
    const float* __restrict__ h, const float* __restrict__ x,
    const float* __restrict__ seg, const float* __restrict__ cnt,
    const float* __restrict__ nb_t0,
    const float* __restrict__ w1, const float* __restrict__ b1,
    const float* __restrict__ w2, const float* __restrict__ b2,
    float* __restrict__ out_h, float* __restrict__ out_x) {
  __shared__ float in[64];
  __shared__ float hs[128];
  int n = blockIdx.x, t = threadIdx.x;
  if (t < 3) {
    float c = cnt[n]; if (c < 1.f) c = 1.f;
    out_x[n * 3 + t] = x[n * 3 + t] + seg[n * 3 + t] / c;
  }
  if (t < 64) in[t] = nb_t0[n * 64 + t];
  __syncthreads();
  float a = b1[t];
  for (int k = 0; k < 64; ++k) a += in[k] * w1[k * 128 + t];
  hs[t] = silu_f(a);
  __syncthreads();
  if (t < 64) {
    float o = b2[t];
    for (int k = 0; k < 128; ++k) o += hs[k] * w2[k * 64 + t];
    out_h[n * 64 + t] = h[n * 64 + t] + o;
  }
}

extern "C" void kernel_launch(void* const* d_in, const int* in_sizes, int n_in,
                              void* d_out, int out_size, void* d_ws, size_t ws_size,
                              hipStream_t stream) {
  (void)in_sizes; (void)n_in; (void)out_size; (void)ws_size;
  const float* h  = (const float*)d_in[0];
  const float* x  = (const float*)d_in[1];
  const int* edges   = (const int*)d_in[2];
  const int* nb_edge = (const int*)d_in[3];
  const float* edge_attr = (const float*)d_in[4];
  const float* ew1 = (const float*)d_in[6],  *eb1 = (const float*)d_in[7];
  const float* ew2 = (const float*)d_in[8],  *eb2 = (const float*)d_in[9];
  const float* p1w1 = (const float*)d_in[10], *p1b1 = (const float*)d_in[11];
  const float* p1w2 = (const float*)d_in[12], *p1b2 = (const float*)d_in[13];
  const float* p2w1 = (const float*)d_in[14], *p2b1 = (const float*)d_in[15];
  const float* p2w2 = (const float*)d_in[16], *p2b2 = (const float*)d_in[17];
  const float* p3w1 = (const float*)d_in[18], *p3b1 = (const float*)d_in[19];
  const float* p3w2 = (const float*)d_in[20], *p3b2 = (const float*)d_in[21];
  const float* ignw = (const float*)d_in[22], *ignb = (const float*)d_in[23];
  const float* cw1 = (const float*)d_in[24], *cb1 = (const float*)d_in[25];
  const float* cw2 = (const float*)d_in[26];
  const float* ndw1 = (const float*)d_in[27], *ndb1 = (const float*)d_in[28];
  const float* ndw2 = (const float*)d_in[29], *ndb2 = (const float*)d_in[30];

  // ---- workspace layout (~203 MB) ----
  char* ws = (char*)d_ws;
  float* T = (float*)ws;                                        // 100,663,296 B fp32 [512*512][96]
  __hip_bfloat16* m1   = (__hip_bfloat16*)(ws + 100663296);     // 33.5 MB bf16
  __hip_bfloat16* m2   = (__hip_bfloat16*)(ws + 134217728);     // 33.5 MB
  __hip_bfloat16* mult = (__hip_bfloat16*)(ws + 167772160);     // 33.5 MB
  // m1/m2 are dead after k_einsum -> alias partial reduction buffers there
  float* row_part = (float*)(ws + 100663296);                   // [64][512][128] fp32
  float* col_part = (float*)(ws + 117440512);                   // [64][512][128]
  char* S = ws + 201326592;
  float* coord_diff  = (float*)S; S += 1536 * 4;
  float* efn         = (float*)S; S += 32768 * 4;
  float* diag_silu   = (float*)S; S += 65536 * 4;
  float* rowsum_silu = (float*)S; S += 65536 * 4;
  float* colsum_silu = (float*)S; S += 65536 * 4;
  float* diag_T      = (float*)S; S += 32768 * 4;
  float* row_T       = (float*)S; S += 32768 * 4;
  float* col_T       = (float*)S; S += 32768 * 4;
  float* tot         = (float*)S; S += 64 * 4;
  float* tr          = (float*)S; S += 64 * 4;
  float* nb_t1       = (float*)S; S += 32768 * 4;
  float* seg         = (float*)S; S += 1536 * 4;   // seg, cnt, nb_t0 contiguous (one memset)
  float* cnt         = (float*)S; S += 512 * 4;
  float* nb_t0       = (float*)S; S += 32768 * 4;

  float* out_h  = (float*)d_out;
  float* out_x  = out_h + 512 * 64;
  float* out_ea = out_x + 512 * 3;

  hipMemsetAsync(T, 0, 100663296, stream);
  hipMemsetAsync(seg, 0, (1536 + 512 + 32768) * 4, stream);

  k_edge<<<512, 128, 0, stream>>>(h, x, edges, ew1, eb1, ew2, eb2, coord_diff, efn);
  k_nbscatter<<<(MM * 96 + 255) / 256, 256, 0, stream>>>(nb_edge, coord_diff, efn, T);
  k_mlp96<<<4096, 256, 0, stream>>>(T, p1w1, p1b1, p1w2, p1b2, m1);
  k_mlp96<<<4096, 256, 0, stream>>>(T, p2w1, p2b1, p2w2, p2b2, m2);
  k_einsum<<<1024, 256, 0, stream>>>(m1, m2, mult);
  k_tout_reduce<<<4096, 256, 0, stream>>>(T, mult, p3w1, p3b1, row_part, col_part, diag_silu);
  k_sumparts<<<512, 256, 0, stream>>>(row_part, col_part, rowsum_silu, colsum_silu);
  k_tout2<<<dim3(512, 3), 64, 0, stream>>>(diag_silu, rowsum_silu, colsum_silu,
                                           p3w2, p3b2, diag_T, row_T, col_T);
  k_totr<<<1, 128, 0, stream>>>(row_T, diag_T, tot, tr);
  k_nbt1<<<512, 64, 0, stream>>>(diag_T, row_T, col_T, tot, tr, ignw, ignb, nb_t1);
  k_edge_out<<<512, 128, 0, stream>>>(edges, coord_diff, nb_t1, edge_attr,
                                      cw1, cb1, cw2, seg, cnt, nb_t0, out_ea);
  k_node_out<<<512, 128, 0, stream>>>(h, x, seg, cnt, nb_t0,
                                      ndw1, ndb1, ndw2, ndb2, out_h, out_x);
}

// Round 2
// 789.271 us; speedup vs baseline: 5.5096x; 5.5096x over previous
//
#include <hip/hip_runtime.h>
#include <hip/hip_bf16.h>

// Problem constants (static per reference)
#define NN   512    // nodes
#define EE   512    // edges == nb-graph nodes (En)
#define MM   16384  // nb-graph edges

__device__ __forceinline__ float silu_f(float v) { return v / (1.0f + __expf(-v)); }

// ---------------- K1: per original edge: coord_diff + efn = MLP([h_r|h_c]) ----
__global__ __launch_bounds__(128) void k_edge(
    const float* __restrict__ h, const float* __restrict__ x,
    const int* __restrict__ edges,
    const float* __restrict__ ew1, const float* __restrict__ eb1,
    const float* __restrict__ ew2, const float* __restrict__ eb2,
    float* __restrict__ coord_diff, float* __restrict__ efn) {
  __shared__ float hin[128];
  __shared__ float hs[128];
  int e = blockIdx.x;
  int t = threadIdx.x;
  int r = edges[e], c = edges[EE + e];
  if (t < 3) coord_diff[e * 3 + t] = x[r * 3 + t] - x[c * 3 + t];
  if (t < 64) { hin[t] = h[r * 64 + t]; hin[64 + t] = h[c * 64 + t]; }
  __syncthreads();
  float acc = eb1[t];
  for (int k = 0; k < 128; ++k) acc += hin[k] * ew1[k * 128 + t];
  hs[t] = silu_f(acc);
  __syncthreads();
  if (t < 64) {
    float o = eb2[t];
    for (int k = 0; k < 128; ++k) o += hs[k] * ew2[k * 64 + t];
    efn[e * 64 + t] = o;
  }
}

// ---------------- K2: constants c1 = MLP1(0), c2 = MLP2(0) -------------------
__global__ __launch_bounds__(128) void k_consts(
    const float* __restrict__ p1b1, const float* __restrict__ p1w2, const float* __restrict__ p1b2,
    const float* __restrict__ p2b1, const float* __restrict__ p2w2, const float* __restrict__ p2b2,
    float* __restrict__ c1, float* __restrict__ c2) {
  __shared__ float h1[128], h2[128];
  int t = threadIdx.x;
  h1[t] = silu_f(p1b1[t]); h2[t] = silu_f(p2b1[t]);
  __syncthreads();
  if (t < 64) {
    float a1 = p1b2[t], a2 = p2b2[t];
    for (int k = 0; k < 128; ++k) { a1 += h1[k] * p1w2[k * 64 + t]; a2 += h2[k] * p2w2[k * 64 + t]; }
    c1[t] = a1; c2[t] = a2;
  }
}

// ---------------- K3: mark touched cells -------------------------------------
__global__ __launch_bounds__(256) void k_mark(const int* __restrict__ nb_edge,
                                              int* __restrict__ slotmap) {
  int m = blockIdx.x * 256 + threadIdx.x;
  if (m >= MM) return;
  int cell = nb_edge[m] * 512 + nb_edge[MM + m];
  atomicCAS(&slotmap[cell], -1, -2);
}

// ---------------- K4: compact marked cells -> slots, degree histograms -------
__global__ __launch_bounds__(256) void k_compact(int* __restrict__ slotmap,
                                                 int* __restrict__ cells,
                                                 int* __restrict__ nC,
                                                 int* __restrict__ cntA,
                                                 int* __restrict__ cntB) {
  int cell = blockIdx.x * 256 + threadIdx.x;
  if (slotmap[cell] != -2) return;
  int s = atomicAdd(nC, 1);
  slotmap[cell] = s;
  cells[s] = cell;
  atomicAdd(&cntA[cell >> 9], 1);   // group by first coord a
  atomicAdd(&cntB[cell & 511], 1);  // group by second coord b
}

// ---------------- K5: prefix sums for the two CSRs ---------------------------
__global__ __launch_bounds__(512) void k_scan(const int* __restrict__ cntA, const int* __restrict__ cntB,
                                              int* __restrict__ offA, int* __restrict__ offB,
                                              int* __restrict__ curA, int* __restrict__ curB) {
  __shared__ int sA[512], sB[512];
  int t = threadIdx.x;
  int a0 = cntA[t], b0 = cntB[t];
  sA[t] = a0; sB[t] = b0;
  for (int off = 1; off < 512; off <<= 1) {
    __syncthreads();
    int a = (t >= off) ? sA[t - off] : 0;
    int b = (t >= off) ? sB[t - off] : 0;
    __syncthreads();
    sA[t] += a; sB[t] += b;
  }
  __syncthreads();
  offA[t] = sA[t] - a0; offB[t] = sB[t] - b0;
  curA[t] = sA[t] - a0; curB[t] = sB[t] - b0;
}

// ---------------- K6: fill CSR lists -----------------------------------------
__global__ __launch_bounds__(256) void k_fill(const int* __restrict__ cells, const int* __restrict__ nC,
                                              int* __restrict__ curA, int* __restrict__ curB,
                                              int* __restrict__ listA, int* __restrict__ listB) {
  int s = blockIdx.x * 256 + threadIdx.x;
  if (s >= *nC) return;
  int cell = cells[s];
  listA[atomicAdd(&curA[cell >> 9], 1)] = s;
  listB[atomicAdd(&curB[cell & 511], 1)] = s;
}

// ---------------- K7: nb_feat scatter-add into COMPACT Tc --------------------
__global__ __launch_bounds__(256) void k_scatterT(
    const int* __restrict__ nb_edge, const int* __restrict__ slotmap,
    const float* __restrict__ coord_diff, const float* __restrict__ efn,
    float* __restrict__ Tc) {
  int tid = blockIdx.x * 256 + threadIdx.x;
  if (tid >= MM * 96) return;
  int m = tid / 96, c = tid % 96;
  int a = nb_edge[m], b = nb_edge[MM + m];
  float val;
  if (c < 32) {
    float vtv = coord_diff[a * 3 + 0] * coord_diff[b * 3 + 0]
              + coord_diff[a * 3 + 1] * coord_diff[b * 3 + 1]
              + coord_diff[a * 3 + 2] * coord_diff[b * 3 + 2];
    int i = c >> 1;
    float ang = vtv * 16.0f * __expf(-0.57564627324851143f * (float)i);
    val = (c & 1) ? cosf(ang) : sinf(ang);
  } else {
    int f = c - 32;
    val = efn[a * 64 + f] * efn[b * 64 + f];
  }
  int s = slotmap[a * 512 + b];
  atomicAdd(&Tc[s * 96 + c], val);
}

// ---------------- K8: compact MLPs -> Delta1/Delta2, row/col sums A,B --------
__global__ __launch_bounds__(128) void k_mlp96c(
    const int* __restrict__ cells, const int* __restrict__ nC, const float* __restrict__ Tc,
    const float* __restrict__ w11, const float* __restrict__ b11,
    const float* __restrict__ w12, const float* __restrict__ b12,
    const float* __restrict__ w21, const float* __restrict__ b21,
    const float* __restrict__ w22, const float* __restrict__ b22,
    const float* __restrict__ c1, const float* __restrict__ c2,
    float* __restrict__ D1, float* __restrict__ D2,
    float* __restrict__ A, float* __restrict__ B) {
  int s = blockIdx.x;
  if (s >= *nC) return;
  __shared__ float xs[96];
  __shared__ float hid[128];
  int t = threadIdx.x;
  if (t < 96) xs[t] = Tc[s * 96 + t];
  int cell = cells[s];
  int ai = cell >> 9, bj = cell & 511;
  __syncthreads();
  { // MLP1
    float a = b11[t];
    for (int k = 0; k < 96; ++k) a += xs[k] * w11[k * 128 + t];
    hid[t] = silu_f(a);
  }
  __syncthreads();
  if (t < 64) {
    float o = b12[t];
    for (int k = 0; k < 128; ++k) o += hid[k] * w12[k * 64 + t];
    float d = o - c1[t];
    D1[s * 64 + t] = d;
    atomicAdd(&A[ai * 64 + t], d);
  }
  __syncthreads();
  { // MLP2
    float a = b21[t];
    for (int k = 0; k < 96; ++k) a += xs[k] * w21[k * 128 + t];
    __syncthreads();
    hid[t] = silu_f(a);
  }
  __syncthreads();
  if (t < 64) {
    float o = b22[t];
    for (int k = 0; k < 128; ++k) o += hid[k] * w22[k * 64 + t];
    float d = o - c2[t];
    D2[s * 64 + t] = d;
    atomicAdd(&B[bj * 64 + t], d);
  }
}

// ---------------- K9: TWc[slot] = Tc[slot] @ w1T (rows 0..95 of p3w1) --------
__global__ __launch_bounds__(128) void k_tw(
    const int* __restrict__ nC, const float* __restrict__ Tc,
    const float* __restrict__ p3w1, float* __restrict__ TWc) {
  int s = blockIdx.x;
  if (s >= *nC) return;
  __shared__ float xs[96];
  int t = threadIdx.x;
  if (t < 96) xs[t] = Tc[s * 96 + t];
  __syncthreads();
  float a = 0.f;
  for (int k = 0; k < 96; ++k) a += xs[k] * p3w1[k * 128 + t];
  TWc[s * 128 + t] = a;
}

// ---------------- K10: u[i] = b1 + (512 c1c2 + c2*A[i])@w1m ; v[j] = (c1*B[j])@w1m
__global__ __launch_bounds__(128) void k_uv(
    const float* __restrict__ A, const float* __restrict__ B,
    const float* __restrict__ c1, const float* __restrict__ c2,
    const float* __restrict__ p3w1, const float* __restrict__ p3b1,
    float* __restrict__ u, float* __restrict__ v) {
  __shared__ float vec[64];
  int i = blockIdx.x, y = blockIdx.y, t = threadIdx.x;
  if (t < 64)
    vec[t] = (y == 0) ? (512.0f * c1[t] * c2[t] + c2[t] * A[i * 64 + t])
                      : (c1[t] * B[i * 64 + t]);
  __syncthreads();
  float a = (y == 0) ? p3b1[t] : 0.f;
  for (int f = 0; f < 64; ++f) a += vec[f] * p3w1[(96 + f) * 128 + t];
  (y == 0 ? u : v)[i * 128 + t] = a;
}

// ---------------- K11: sparse-sparse S[i,j,f] += D1[(i,k)]*D2[(k,j)] ---------
// block per middle-node k; 4 groups of 64 lanes, lane = f.
__global__ __launch_bounds__(256) void k_pairs(
    const int* __restrict__ cntA, const int* __restrict__ cntB,
    const int* __restrict__ offA, const int* __restrict__ offB,
    const int* __restrict__ listA, const int* __restrict__ listB,
    const int* __restrict__ cells,
    const float* __restrict__ D1, const float* __restrict__ D2,
    float* __restrict__ S) {
  int k = blockIdx.x;
  int t = threadIdx.x;
  int f = t & 63, g = t >> 6;
  int n1 = cntB[k], n2 = cntA[k];   // D1 cells with b==k; D2 cells with a==k
  if (n1 == 0 || n2 == 0) return;
  int o1 = offB[k], o2 = offA[k];
  for (int p1 = 0; p1 < n1; ++p1) {
    int s1 = listB[o1 + p1];
    int i = cells[s1] >> 9;
    float d1 = D1[s1 * 64 + f];
    for (int p2 = g; p2 < n2; p2 += 4) {
      int s2 = listA[o2 + p2];
      int j = cells[s2] & 511;
      float d2 = D2[s2 * 64 + f];
      atomicAdd(&S[(i * 512 + j) * 64 + f], d1 * d2);
    }
  }
}

// ------- K12: fused z = u[i]+v[j]+S@w1m+TW, silu, row/col/diag reduce --------
// 8x8 cell tile; 256 thr: cg=t&7 -> ci, hg=t>>3 -> 4 h-cols; acc[8](float4).
__global__ __launch_bounds__(256) void k_tout_fused(
    const float* __restrict__ S, const float* __restrict__ u, const float* __restrict__ v,
    const float* __restrict__ TWc, const int* __restrict__ slotmap,
    const float* __restrict__ p3w1,
    float* __restrict__ row_part, float* __restrict__ col_part,
    float* __restrict__ diag_silu) {
  __shared__ float Ss[64 * 65];     // 16,640 B
  __shared__ float Wm[64 * 128];    // 32,768 B
  __shared__ float uvs[2048];       // 8,192 B  (u rows | v rows)
  __shared__ int slotL[64];
  int t = threadIdx.x;
  int cg = t & 7, hg = t >> 3;
  int bi = blockIdx.x >> 6, bj = blockIdx.x & 63;
  int i0 = bi * 8, j0 = bj * 8;
  for (int e = t; e < 4096; e += 256) {
    int cl = e >> 6, f = e & 63;
    Ss[cl * 65 + f] = S[((i0 + (cl >> 3)) * 512 + j0 + (cl & 7)) * 64 + f];
  }
  for (int e = t; e < 8192; e += 256) Wm[e] = p3w1[96 * 128 + e];
  for (int e = t; e < 1024; e += 256) uvs[e] = u[(i0 + (e >> 7)) * 128 + (e & 127)];
  for (int e = t; e < 1024; e += 256) uvs[1024 + e] = v[(j0 + (e >> 7)) * 128 + (e & 127)];
  if (t < 64) slotL[t] = slotmap[(i0 + (t >> 3)) * 512 + j0 + (t & 7)];
  __syncthreads();
  float4 acc[8];
#pragma unroll
  for (int cj = 0; cj < 8; ++cj) acc[cj] = make_float4(0.f, 0.f, 0.f, 0.f);
  for (int kk = 0; kk < 64; ++kk) {
    float4 wv = *(const float4*)&Wm[kk * 128 + hg * 4];
#pragma unroll
    for (int cj = 0; cj < 8; ++cj) {
      float xv = Ss[(cg * 8 + cj) * 65 + kk];
      acc[cj].x += xv * wv.x; acc[cj].y += xv * wv.y;
      acc[cj].z += xv * wv.z; acc[cj].w += xv * wv.w;
    }
  }
  float4 uu = *(const float4*)&uvs[cg * 128 + hg * 4];
#pragma unroll
  for (int cj = 0; cj < 8; ++cj) {
    float4 vv = *(const float4*)&uvs[1024 + cj * 128 + hg * 4];
    float4 z = make_float4(acc[cj].x + uu.x + vv.x, acc[cj].y + uu.y + vv.y,
                           acc[cj].z + uu.z + vv.z, acc[cj].w + uu.w + vv.w);
    int s = slotL[cg * 8 + cj];
    if (s >= 0) {
      float4 tw = *(const float4*)&TWc[s * 128 + hg * 4];
      z.x += tw.x; z.y += tw.y; z.z += tw.z; z.w += tw.w;
    }
    acc[cj] = make_float4(silu_f(z.x), silu_f(z.y), silu_f(z.z), silu_f(z.w));
  }
  // rowsum over cj; row i = i0+cg
  float4 rs = make_float4(0.f, 0.f, 0.f, 0.f);
#pragma unroll
  for (int cj = 0; cj < 8; ++cj) {
    rs.x += acc[cj].x; rs.y += acc[cj].y; rs.z += acc[cj].z; rs.w += acc[cj].w;
  }
  *(float4*)&row_part[(bj * 512 + i0 + cg) * 128 + hg * 4] = rs;
  // colsum over ci=cg (lanes differing in low 3 bits)
#pragma unroll
  for (int cj = 0; cj < 8; ++cj) {
    float4 cs = acc[cj];
#pragma unroll
    for (int msk = 1; msk < 8; msk <<= 1) {
      cs.x += __shfl_xor(cs.x, msk); cs.y += __shfl_xor(cs.y, msk);
      cs.z += __shfl_xor(cs.z, msk); cs.w += __shfl_xor(cs.w, msk);
    }
    if (cg == 0)
      *(float4*)&col_part[(bi * 512 + j0 + cj) * 128 + hg * 4] = cs;
  }
  if (bi == bj) {
#pragma unroll
    for (int cj = 0; cj < 8; ++cj)
      if (cj == cg)
        *(float4*)&diag_silu[(i0 + cg) * 128 + hg * 4] = acc[cj];
  }
}

// ---------------- K13: reduce 64 partial slices ------------------------------
__global__ __launch_bounds__(256) void k_sumparts(
    const float* __restrict__ row_part, const float* __restrict__ col_part,
    float* __restrict__ rowsum, float* __restrict__ colsum) {
  int i = blockIdx.x, t = threadIdx.x;
  const float* src = (t < 128) ? row_part : col_part;
  float* dst = (t < 128) ? rowsum : colsum;
  int hc = t & 127;
  float a = 0.f;
  for (int p = 0; p < 64; ++p) a += src[(p * 512 + i) * 128 + hc];
  dst[i * 128 + hc] = a;
}

// ---------------- K14: second layer of p3 MLP on reduced silu sums -----------
__global__ __launch_bounds__(64) void k_tout2(
    const float* __restrict__ diag_silu, const float* __restrict__ rowsum_silu,
    const float* __restrict__ colsum_silu,
    const float* __restrict__ w2, const float* __restrict__ b2,
    float* __restrict__ diag_T, float* __restrict__ row_T, float* __restrict__ col_T) {
  __shared__ float in[128];
  int e = blockIdx.x, which = blockIdx.y, t = threadIdx.x;
  const float* src = (which == 0) ? diag_silu : (which == 1) ? rowsum_silu : colsum_silu;
  in[t] = src[e * 128 + t]; in[64 + t] = src[e * 128 + 64 + t];
  __syncthreads();
  float a = 0.f;
  for (int k = 0; k < 128; ++k) a += in[k] * w2[k * 64 + t];
  float bias = b2[t] * ((which == 0) ? 1.0f : 512.0f);
  float* dst = (which == 0) ? diag_T : (which == 1) ? row_T : col_T;
  dst[e * 64 + t] = a + bias;
}

// ---------------- K15: tot / tr ----------------------------------------------
__global__ __launch_bounds__(128) void k_totr(
    const float* __restrict__ row_T, const float* __restrict__ diag_T,
    float* __restrict__ tot, float* __restrict__ tr) {
  int t = threadIdx.x;
  const float* src = (t < 64) ? row_T : diag_T;
  int f = t & 63;
  float a = 0.f;
  for (int e = 0; e < 512; ++e) a += src[e * 64 + f];
  if (t < 64) tot[f] = a; else tr[f] = a;
}

// ---------------- K16: nb_t1 = [diag|row|col|tot|tr] @ ign_w + ign_b ---------
__global__ __launch_bounds__(64) void k_nbt1(
    const float* __restrict__ diag_T, const float* __restrict__ row_T,
    const float* __restrict__ col_T, const float* __restrict__ tot,
    const float* __restrict__ tr,
    const float* __restrict__ gw, const float* __restrict__ gb,
    float* __restrict__ nb_t1) {
  __shared__ float in[320];
  int e = blockIdx.x, t = threadIdx.x;
  in[t] = diag_T[e * 64 + t]; in[64 + t] = row_T[e * 64 + t];
  in[128 + t] = col_T[e * 64 + t]; in[192 + t] = tot[t]; in[256 + t] = tr[t];
  __syncthreads();
  float a = gb[t];
  for (int k = 0; k < 320; ++k) a += in[k] * gw[k * 64 + t];
  nb_t1[e * 64 + t] = a;
}

// ----- K17: coord weight w_e, seg/cnt/nb_t0 scatters, edge_attr passthrough --
__global__ __launch_bounds__(128) void k_edge_out(
    const int* __restrict__ edges, const float* __restrict__ coord_diff,
    const float* __restrict__ nb_t1, const float* __restrict__ edge_attr,
    const float* __restrict__ cw1, const float* __restrict__ cb1,
    const float* __restrict__ cw2,
    float* __restrict__ seg, float* __restrict__ cnt, float* __restrict__ nb_t0,
    float* __restrict__ out_ea) {
  __shared__ float in[64];
  __shared__ float red[128];
  int e = blockIdx.x, t = threadIdx.x;
  if (t < 64) in[t] = nb_t1[e * 64 + t];
  __syncthreads();
  float a = cb1[t];
  for (int k = 0; k < 64; ++k) a += in[k] * cw1[k * 128 + t];
  red[t] = silu_f(a) * cw2[t];
  __syncthreads();
  for (int s2 = 64; s2 > 0; s2 >>= 1) {
    if (t < s2) red[t] += red[t + s2];
    __syncthreads();
  }
  float w = red[0];
  int r = edges[e];
  if (t < 3) atomicAdd(&seg[r * 3 + t], coord_diff[e * 3 + t] * w);
  if (t == 64) atomicAdd(&cnt[r], 1.0f);
  if (t < 64) atomicAdd(&nb_t0[r * 64 + t], in[t]);
  if (t < 4) out_ea[e * 4 + t] = edge_attr[e * 4 + t];
}

// ---------------- K18: x_new and h_new ---------------------------------------
__global__ __launch_bounds__(128) void k_node_out(
    const float* __restrict__ h, const float* __restrict__ x,
    const float* __restrict__ seg, const float* __restrict__ cnt,
    const float* __restrict__ nb_t0,
    const float* __restrict__ w1, const float* __restrict__ b1,
    const float* __restrict__ w2, const float* __restrict__ b2,
    float* __restrict__ out_h, float* __restrict__ out_x) {
  __shared__ float in[64];
  __shared__ float hs[128];
  int n = blockIdx.x, t = threadIdx.x;
  if (t < 3) {
    float c = cnt[n]; if (c < 1.f) c = 1.f;
    out_x[n * 3 + t] = x[n * 3 + t] + seg[n * 3 + t] / c;
  }
  if (t < 64) in[t] = nb_t0[n * 64 + t];
  __syncthreads();
  float a = b1[t];
  for (int k = 0; k < 64; ++k) a += in[k] * w1[k * 128 + t];
  hs[t] = silu_f(a);
  __syncthreads();
  if (t < 64) {
    float o = b2[t];
    for (int k = 0; k < 128; ++k) o += hs[k] * w2[k * 64 + t];
    out_h[n * 64 + t] = h[n * 64 + t] + o;
  }
}

extern "C" void kernel_launch(void* const* d_in, const int* in_sizes, int n_in,
                              void* d_out, int out_size, void* d_ws, size_t ws_size,
                              hipStream_t stream) {
  (void)in_sizes; (void)n_in; (void)out_size; (void)ws_size;
  const float* h  = (const float*)d_in[0];
  const float* x  = (const float*)d_in[1];
  const int* edges   = (const int*)d_in[2];
  const int* nb_edge = (const int*)d_in[3];
  const float* edge_attr = (const float*)d_in[4];
  const float* ew1 = (const float*)d_in[6],  *eb1 = (const float*)d_in[7];
  const float* ew2 = (const float*)d_in[8],  *eb2 = (const float*)d_in[9];
  const float* p1w1 = (const float*)d_in[10], *p1b1 = (const float*)d_in[11];
  const float* p1w2 = (const float*)d_in[12], *p1b2 = (const float*)d_in[13];
  const float* p2w1 = (const float*)d_in[14], *p2b1 = (const float*)d_in[15];
  const float* p2w2 = (const float*)d_in[16], *p2b2 = (const float*)d_in[17];
  const float* p3w1 = (const float*)d_in[18], *p3b1 = (const float*)d_in[19];
  const float* p3w2 = (const float*)d_in[20], *p3b2 = (const float*)d_in[21];
  const float* ignw = (const float*)d_in[22], *ignb = (const float*)d_in[23];
  const float* cw1 = (const float*)d_in[24], *cb1 = (const float*)d_in[25];
  const float* cw2 = (const float*)d_in[26];
  const float* ndw1 = (const float*)d_in[27], *ndb1 = (const float*)d_in[28];
  const float* ndw2 = (const float*)d_in[29], *ndb2 = (const float*)d_in[30];

  // ---- workspace layout (~127.4 MB) ----
  char* ws = (char*)d_ws;
  float* S        = (float*)(ws + 0);           // [262144][64] = 67,108,864 B
  float* row_part = (float*)(ws + 67108864);    // [64][512][128] = 16,777,216 B
  float* col_part = (float*)(ws + 83886080);    // 16,777,216 B
  float* Tc       = (float*)(ws + 100663296);   // [16384][96] = 6,291,456 B
  float* D1       = (float*)(ws + 106954752);   // [16384][64] = 4,194,304 B
  float* D2       = (float*)(ws + 111149056);   // 4,194,304 B
  float* TWc      = (float*)(ws + 115343360);   // [16384][128] = 8,388,608 B
  int*   slotmap  = (int*)(ws + 123731968);     // [262144] = 1,048,576 B
  int*   cells    = (int*)(ws + 124780544);     // [16384] = 65,536 B
  int*   ib       = (int*)(ws + 124846080);
  int* cntA = ib;          int* cntB = ib + 512;  int* nC = ib + 1024;  // zeroed block [0..1040)
  int* offA = ib + 1040;   int* offB = ib + 1552;
  int* curA = ib + 2064;   int* curB = ib + 2576;
  int* listA = ib + 3088;  int* listB = ib + 19472;                      // ends ib+35856
  float* fb = (float*)(ib + 35856);
  float* c1 = fb;            float* c2 = fb + 64;
  float* A  = fb + 128;      float* B  = fb + 32896;       // A,B contiguous 65536 floats @fb+128
  float* u  = fb + 65664;    float* v  = fb + 131200;
  float* coord_diff  = fb + 196736;
  float* efn         = fb + 198272;
  float* diag_silu   = fb + 231040;
  float* rowsum_silu = fb + 296576;
  float* colsum_silu = fb + 362112;
  float* diag_T      = fb + 427648;
  float* row_T       = fb + 460416;
  float* col_T       = fb + 493184;
  float* tot         = fb + 525952;
  float* tr          = fb + 526016;
  float* nb_t1       = fb + 526080;
  float* seg         = fb + 558848;   // seg,cnt,nb_t0 contiguous (one memset)
  float* cnt         = fb + 560384;
  float* nb_t0       = fb + 560896;

  float* out_h  = (float*)d_out;
  float* out_x  = out_h + 512 * 64;
  float* out_ea = out_x + 512 * 3;

  hipMemsetAsync(slotmap, 0xFF, 1048576, stream);               // -1
  hipMemsetAsync(Tc, 0, 6291456, stream);
  hipMemsetAsync(S, 0, 67108864, stream);
  hipMemsetAsync(ib, 0, 1040 * 4, stream);                      // cntA,cntB,nC
  hipMemsetAsync(A, 0, 65536 * 4, stream);                      // A and B
  hipMemsetAsync(seg, 0, (1536 + 512 + 32768) * 4, stream);

  k_edge<<<512, 128, 0, stream>>>(h, x, edges, ew1, eb1, ew2, eb2, coord_diff, efn);
  k_consts<<<1, 128, 0, stream>>>(p1b1, p1w2, p1b2, p2b1, p2w2, p2b2, c1, c2);
  k_mark<<<64, 256, 0, stream>>>(nb_edge, slotmap);
  k_compact<<<1024, 256, 0, stream>>>(slotmap, cells, nC, cntA, cntB);
  k_scan<<<1, 512, 0, stream>>>(cntA, cntB, offA, offB, curA, curB);
  k_fill<<<64, 256, 0, stream>>>(cells, nC, curA, curB, listA, listB);
  k_scatterT<<<6144, 256, 0, stream>>>(nb_edge, slotmap, coord_diff, efn, Tc);
  k_mlp96c<<<16384, 128, 0, stream>>>(cells, nC, Tc,
                                      p1w1, p1b1, p1w2, p1b2,
                                      p2w1, p2b1, p2w2, p2b2,
                                      c1, c2, D1, D2, A, B);
  k_tw<<<16384, 128, 0, stream>>>(nC, Tc, p3w1, TWc);
  k_uv<<<dim3(512, 2), 128, 0, stream>>>(A, B, c1, c2, p3w1, p3b1, u, v);
  k_pairs<<<512, 256, 0, stream>>>(cntA, cntB, offA, offB, listA, listB, cells, D1, D2, S);
  k_tout_fused<<<4096, 256, 0, stream>>>(S, u, v, TWc, slotmap, p3w1,
                                         row_part, col_part, diag_silu);
  k_sumparts<<<512, 256, 0, stream>>>(row_part, col_part, rowsum_silu, colsum_silu);
  k_tout2<<<dim3(512, 3), 64, 0, stream>>>(diag_silu, rowsum_silu, colsum_silu,
                                           p3w2, p3b2, diag_T, row_T, col_T);
  k_totr<<<1, 128, 0, stream>>>(row_T, diag_T, tot, tr);
  k_nbt1<<<512, 64, 0, stream>>>(diag_T, row_T, col_T, tot, tr, ignw, ignb, nb_t1);
  k_edge_out<<<512, 128, 0, stream>>>(edges, coord_diff, nb_t1, edge_attr,
                                      cw1, cb1, cw2, seg, cnt, nb_t0, out_ea);
  k_node_out<<<512, 128, 0, stream>>>(h, x, seg, cnt, nb_t0,
                                      ndw1, ndb1, ndw2, ndb2, out_h, out_x);
}

// Round 3
// 712.534 us; speedup vs baseline: 6.1030x; 1.1077x over previous
//
#include <hip/hip_runtime.h>
#include <hip/hip_bf16.h>

// Problem constants (static per reference)
#define NN   512    // nodes
#define EE   512    // edges == nb-graph nodes (En)
#define MM   16384  // nb-graph edges

__device__ __forceinline__ float silu_f(float v) { return v / (1.0f + __expf(-v)); }

// ---------------- K1: per original edge: coord_diff + efn = MLP([h_r|h_c]) ----
__global__ __launch_bounds__(128) void k_edge(
    const float* __restrict__ h, const float* __restrict__ x,
    const int* __restrict__ edges,
    const float* __restrict__ ew1, const float* __restrict__ eb1,
    const float* __restrict__ ew2, const float* __restrict__ eb2,
    float* __restrict__ coord_diff, float* __restrict__ efn) {
  __shared__ float hin[128];
  __shared__ float hs[128];
  int e = blockIdx.x;
  int t = threadIdx.x;
  int r = edges[e], c = edges[EE + e];
  if (t < 3) coord_diff[e * 3 + t] = x[r * 3 + t] - x[c * 3 + t];
  if (t < 64) { hin[t] = h[r * 64 + t]; hin[64 + t] = h[c * 64 + t]; }
  __syncthreads();
  float acc = eb1[t];
  for (int k = 0; k < 128; ++k) acc += hin[k] * ew1[k * 128 + t];
  hs[t] = silu_f(acc);
  __syncthreads();
  if (t < 64) {
    float o = eb2[t];
    for (int k = 0; k < 128; ++k) o += hs[k] * ew2[k * 64 + t];
    efn[e * 64 + t] = o;
  }
}

// ---------------- K2: constants c1 = MLP1(0), c2 = MLP2(0) -------------------
__global__ __launch_bounds__(128) void k_consts(
    const float* __restrict__ p1b1, const float* __restrict__ p1w2, const float* __restrict__ p1b2,
    const float* __restrict__ p2b1, const float* __restrict__ p2w2, const float* __restrict__ p2b2,
    float* __restrict__ c1, float* __restrict__ c2) {
  __shared__ float h1[128], h2[128];
  int t = threadIdx.x;
  h1[t] = silu_f(p1b1[t]); h2[t] = silu_f(p2b1[t]);
  __syncthreads();
  if (t < 64) {
    float a1 = p1b2[t], a2 = p2b2[t];
    for (int k = 0; k < 128; ++k) { a1 += h1[k] * p1w2[k * 64 + t]; a2 += h2[k] * p2w2[k * 64 + t]; }
    c1[t] = a1; c2[t] = a2;
  }
}

// ---------------- K3: mark touched cells -------------------------------------
__global__ __launch_bounds__(256) void k_mark(const int* __restrict__ nb_edge,
                                              int* __restrict__ slotmap) {
  int m = blockIdx.x * 256 + threadIdx.x;
  if (m >= MM) return;
  int cell = nb_edge[m] * 512 + nb_edge[MM + m];
  atomicCAS(&slotmap[cell], -1, -2);
}

// ---------------- K4: compact marked cells -> slots, degree histogram --------
__global__ __launch_bounds__(256) void k_compact(int* __restrict__ slotmap,
                                                 int* __restrict__ cells,
                                                 int* __restrict__ nC,
                                                 int* __restrict__ cntA) {
  int cell = blockIdx.x * 256 + threadIdx.x;
  if (slotmap[cell] != -2) return;
  int s = atomicAdd(nC, 1);
  slotmap[cell] = s;
  cells[s] = cell;
  atomicAdd(&cntA[cell >> 9], 1);   // group by first coord a
}

// ---------------- K5: prefix sum for the CSR ---------------------------------
__global__ __launch_bounds__(512) void k_scan(const int* __restrict__ cntA,
                                              int* __restrict__ offA,
                                              int* __restrict__ curA) {
  __shared__ int sA[512];
  int t = threadIdx.x;
  int a0 = cntA[t];
  sA[t] = a0;
  for (int off = 1; off < 512; off <<= 1) {
    __syncthreads();
    int a = (t >= off) ? sA[t - off] : 0;
    __syncthreads();
    sA[t] += a;
  }
  __syncthreads();
  offA[t] = sA[t] - a0;
  curA[t] = sA[t] - a0;
}

// ---------------- K6: fill CSR list (cells grouped by first coord) -----------
__global__ __launch_bounds__(256) void k_fill(const int* __restrict__ cells, const int* __restrict__ nC,
                                              int* __restrict__ curA,
                                              int* __restrict__ listA) {
  int s = blockIdx.x * 256 + threadIdx.x;
  if (s >= *nC) return;
  int cell = cells[s];
  listA[atomicAdd(&curA[cell >> 9], 1)] = s;
}

// ---------------- K7: nb_feat scatter-add into COMPACT Tc --------------------
__global__ __launch_bounds__(256) void k_scatterT(
    const int* __restrict__ nb_edge, const int* __restrict__ slotmap,
    const float* __restrict__ coord_diff, const float* __restrict__ efn,
    float* __restrict__ Tc) {
  int tid = blockIdx.x * 256 + threadIdx.x;
  if (tid >= MM * 96) return;
  int m = tid / 96, c = tid % 96;
  int a = nb_edge[m], b = nb_edge[MM + m];
  float val;
  if (c < 32) {
    float vtv = coord_diff[a * 3 + 0] * coord_diff[b * 3 + 0]
              + coord_diff[a * 3 + 1] * coord_diff[b * 3 + 1]
              + coord_diff[a * 3 + 2] * coord_diff[b * 3 + 2];
    int i = c >> 1;
    float ang = vtv * 16.0f * __expf(-0.57564627324851143f * (float)i);
    val = (c & 1) ? cosf(ang) : sinf(ang);
  } else {
    int f = c - 32;
    val = efn[a * 64 + f] * efn[b * 64 + f];
  }
  int s = slotmap[a * 512 + b];
  atomicAdd(&Tc[s * 96 + c], val);
}

// ------- K8: compact MLPs -> D1/D2, row/col sums A,B; fused TWc = Tc@w1T -----
__global__ __launch_bounds__(128) void k_mlp96c(
    const int* __restrict__ cells, const int* __restrict__ nC, const float* __restrict__ Tc,
    const float* __restrict__ w11, const float* __restrict__ b11,
    const float* __restrict__ w12, const float* __restrict__ b12,
    const float* __restrict__ w21, const float* __restrict__ b21,
    const float* __restrict__ w22, const float* __restrict__ b22,
    const float* __restrict__ c1, const float* __restrict__ c2,
    const float* __restrict__ p3w1,
    float* __restrict__ D1, float* __restrict__ D2,
    float* __restrict__ A, float* __restrict__ B,
    float* __restrict__ TWc) {
  int s = blockIdx.x;
  if (s >= *nC) return;
  __shared__ float xs[96];
  __shared__ float hid[128];
  int t = threadIdx.x;
  if (t < 96) xs[t] = Tc[s * 96 + t];
  int cell = cells[s];
  int ai = cell >> 9, bj = cell & 511;
  __syncthreads();
  { // TWc = Tc @ w1T (rows 0..95 of p3w1)
    float a = 0.f;
    for (int k = 0; k < 96; ++k) a += xs[k] * p3w1[k * 128 + t];
    TWc[s * 128 + t] = a;
  }
  { // MLP1
    float a = b11[t];
    for (int k = 0; k < 96; ++k) a += xs[k] * w11[k * 128 + t];
    hid[t] = silu_f(a);
  }
  __syncthreads();
  if (t < 64) {
    float o = b12[t];
    for (int k = 0; k < 128; ++k) o += hid[k] * w12[k * 64 + t];
    float d = o - c1[t];
    D1[s * 64 + t] = d;
    atomicAdd(&A[ai * 64 + t], d);
  }
  __syncthreads();
  { // MLP2
    float a = b21[t];
    for (int k = 0; k < 96; ++k) a += xs[k] * w21[k * 128 + t];
    __syncthreads();
    hid[t] = silu_f(a);
  }
  __syncthreads();
  if (t < 64) {
    float o = b22[t];
    for (int k = 0; k < 128; ++k) o += hid[k] * w22[k * 64 + t];
    float d = o - c2[t];
    D2[s * 64 + t] = d;
    atomicAdd(&B[bj * 64 + t], d);
  }
}

// ---------------- K10: u[i] = b1 + (512 c1c2 + c2*A[i])@w1m ; v[j] = (c1*B[j])@w1m
__global__ __launch_bounds__(128) void k_uv(
    const float* __restrict__ A, const float* __restrict__ B,
    const float* __restrict__ c1, const float* __restrict__ c2,
    const float* __restrict__ p3w1, const float* __restrict__ p3b1,
    float* __restrict__ u, float* __restrict__ v) {
  __shared__ float vec[64];
  int i = blockIdx.x, y = blockIdx.y, t = threadIdx.x;
  if (t < 64)
    vec[t] = (y == 0) ? (512.0f * c1[t] * c2[t] + c2[t] * A[i * 64 + t])
                      : (c1[t] * B[i * 64 + t]);
  __syncthreads();
  float a = (y == 0) ? p3b1[t] : 0.f;
  for (int f = 0; f < 64; ++f) a += vec[f] * p3w1[(96 + f) * 128 + t];
  (y == 0 ? u : v)[i * 128 + t] = a;
}

// ---------------- K11: sparse-sparse S row-wise in LDS -----------------------
// One block per output row i. Two passes of 32 features (64 KB LDS each).
// lane f = t&31 owns feature f (bank-conflict-free); 8 subgroups over pairs.
// LDS atomics only; dense coalesced writeback (no global atomics, no S memset).
__global__ __launch_bounds__(256) void k_pairs_rows(
    const int* __restrict__ cntA, const int* __restrict__ offA,
    const int* __restrict__ listA, const int* __restrict__ cells,
    const float* __restrict__ D1, const float* __restrict__ D2,
    float* __restrict__ S) {
  __shared__ float Srow[512 * 32];   // 64 KB
  int i = blockIdx.x;
  int t = threadIdx.x;
  int f = t & 31, g = t >> 5;        // 8 subgroups of 32 lanes
  int n1 = cntA[i], o1 = offA[i];
  for (int pass = 0; pass < 2; ++pass) {
    for (int e = t; e < 16384; e += 256) Srow[e] = 0.f;
    __syncthreads();
    int fofs = pass * 32 + f;
    for (int p1 = 0; p1 < n1; ++p1) {
      int s1 = listA[o1 + p1];
      int k = cells[s1] & 511;
      float d1 = D1[s1 * 64 + fofs];
      int n2 = cntA[k], o2 = offA[k];
      for (int p2 = g; p2 < n2; p2 += 8) {
        int s2 = listA[o2 + p2];
        int j = cells[s2] & 511;
        float d2 = D2[s2 * 64 + fofs];
        atomicAdd(&Srow[j * 32 + f], d1 * d2);
      }
    }
    __syncthreads();
    for (int e = t; e < 16384; e += 256) {
      int j = e >> 5, ff = e & 31;
      S[(i * 512 + j) * 64 + pass * 32 + ff] = Srow[e];
    }
    __syncthreads();
  }
}

// ------- K12: fused z = u[i]+v[j]+S@w1m+TW, silu, row/col/diag reduce --------
// 8x8 cell tile; 256 thr: cg=t&7 -> ci, hg=t>>3 -> 4 h-cols; acc[8](float4).
__global__ __launch_bounds__(256) void k_tout_fused(
    const float* __restrict__ S, const float* __restrict__ u, const float* __restrict__ v,
    const float* __restrict__ TWc, const int* __restrict__ slotmap,
    const float* __restrict__ p3w1,
    float* __restrict__ row_part, float* __restrict__ col_part,
    float* __restrict__ diag_silu) {
  __shared__ float Ss[64 * 65];     // 16,640 B
  __shared__ float Wm[64 * 128];    // 32,768 B
  __shared__ float uvs[2048];       // 8,192 B  (u rows | v rows)
  __shared__ int slotL[64];
  int t = threadIdx.x;
  int cg = t & 7, hg = t >> 3;
  int bi = blockIdx.x >> 6, bj = blockIdx.x & 63;
  int i0 = bi * 8, j0 = bj * 8;
  for (int e = t; e < 4096; e += 256) {
    int cl = e >> 6, f = e & 63;
    Ss[cl * 65 + f] = S[((i0 + (cl >> 3)) * 512 + j0 + (cl & 7)) * 64 + f];
  }
  for (int e = t; e < 8192; e += 256) Wm[e] = p3w1[96 * 128 + e];
  for (int e = t; e < 1024; e += 256) uvs[e] = u[(i0 + (e >> 7)) * 128 + (e & 127)];
  for (int e = t; e < 1024; e += 256) uvs[1024 + e] = v[(j0 + (e >> 7)) * 128 + (e & 127)];
  if (t < 64) slotL[t] = slotmap[(i0 + (t >> 3)) * 512 + j0 + (t & 7)];
  __syncthreads();
  float4 acc[8];
#pragma unroll
  for (int cj = 0; cj < 8; ++cj) acc[cj] = make_float4(0.f, 0.f, 0.f, 0.f);
  for (int kk = 0; kk < 64; ++kk) {
    float4 wv = *(const float4*)&Wm[kk * 128 + hg * 4];
#pragma unroll
    for (int cj = 0; cj < 8; ++cj) {
      float xv = Ss[(cg * 8 + cj) * 65 + kk];
      acc[cj].x += xv * wv.x; acc[cj].y += xv * wv.y;
      acc[cj].z += xv * wv.z; acc[cj].w += xv * wv.w;
    }
  }
  float4 uu = *(const float4*)&uvs[cg * 128 + hg * 4];
#pragma unroll
  for (int cj = 0; cj < 8; ++cj) {
    float4 vv = *(const float4*)&uvs[1024 + cj * 128 + hg * 4];
    float4 z = make_float4(acc[cj].x + uu.x + vv.x, acc[cj].y + uu.y + vv.y,
                           acc[cj].z + uu.z + vv.z, acc[cj].w + uu.w + vv.w);
    int s = slotL[cg * 8 + cj];
    if (s >= 0) {
      float4 tw = *(const float4*)&TWc[s * 128 + hg * 4];
      z.x += tw.x; z.y += tw.y; z.z += tw.z; z.w += tw.w;
    }
    acc[cj] = make_float4(silu_f(z.x), silu_f(z.y), silu_f(z.z), silu_f(z.w));
  }
  // rowsum over cj; row i = i0+cg
  float4 rs = make_float4(0.f, 0.f, 0.f, 0.f);
#pragma unroll
  for (int cj = 0; cj < 8; ++cj) {
    rs.x += acc[cj].x; rs.y += acc[cj].y; rs.z += acc[cj].z; rs.w += acc[cj].w;
  }
  *(float4*)&row_part[(bj * 512 + i0 + cg) * 128 + hg * 4] = rs;
  // colsum over ci=cg (lanes differing in low 3 bits)
#pragma unroll
  for (int cj = 0; cj < 8; ++cj) {
    float4 cs = acc[cj];
#pragma unroll
    for (int msk = 1; msk < 8; msk <<= 1) {
      cs.x += __shfl_xor(cs.x, msk); cs.y += __shfl_xor(cs.y, msk);
      cs.z += __shfl_xor(cs.z, msk); cs.w += __shfl_xor(cs.w, msk);
    }
    if (cg == 0)
      *(float4*)&col_part[(bi * 512 + j0 + cj) * 128 + hg * 4] = cs;
  }
  if (bi == bj) {
#pragma unroll
    for (int cj = 0; cj < 8; ++cj)
      if (cj == cg)
        *(float4*)&diag_silu[(i0 + cg) * 128 + hg * 4] = acc[cj];
  }
}

// ---------------- K13: reduce 64 partial slices ------------------------------
__global__ __launch_bounds__(256) void k_sumparts(
    const float* __restrict__ row_part, const float* __restrict__ col_part,
    float* __restrict__ rowsum, float* __restrict__ colsum) {
  int i = blockIdx.x, t = threadIdx.x;
  const float* src = (t < 128) ? row_part : col_part;
  float* dst = (t < 128) ? rowsum : colsum;
  int hc = t & 127;
  float a = 0.f;
  for (int p = 0; p < 64; ++p) a += src[(p * 512 + i) * 128 + hc];
  dst[i * 128 + hc] = a;
}

// ---------------- K14: second layer of p3 MLP on reduced silu sums -----------
__global__ __launch_bounds__(64) void k_tout2(
    const float* __restrict__ diag_silu, const float* __restrict__ rowsum_silu,
    const float* __restrict__ colsum_silu,
    const float* __restrict__ w2, const float* __restrict__ b2,
    float* __restrict__ diag_T, float* __restrict__ row_T, float* __restrict__ col_T) {
  __shared__ float in[128];
  int e = blockIdx.x, which = blockIdx.y, t = threadIdx.x;
  const float* src = (which == 0) ? diag_silu : (which == 1) ? rowsum_silu : colsum_silu;
  in[t] = src[e * 128 + t]; in[64 + t] = src[e * 128 + 64 + t];
  __syncthreads();
  float a = 0.f;
  for (int k = 0; k < 128; ++k) a += in[k] * w2[k * 64 + t];
  float bias = b2[t] * ((which == 0) ? 1.0f : 512.0f);
  float* dst = (which == 0) ? diag_T : (which == 1) ? row_T : col_T;
  dst[e * 64 + t] = a + bias;
}

// ---------------- K15: tot / tr ----------------------------------------------
__global__ __launch_bounds__(128) void k_totr(
    const float* __restrict__ row_T, const float* __restrict__ diag_T,
    float* __restrict__ tot, float* __restrict__ tr) {
  int t = threadIdx.x;
  const float* src = (t < 64) ? row_T : diag_T;
  int f = t & 63;
  float a = 0.f;
  for (int e = 0; e < 512; ++e) a += src[e * 64 + f];
  if (t < 64) tot[f] = a; else tr[f] = a;
}

// ---------------- K16: nb_t1 = [diag|row|col|tot|tr] @ ign_w + ign_b ---------
__global__ __launch_bounds__(64) void k_nbt1(
    const float* __restrict__ diag_T, const float* __restrict__ row_T,
    const float* __restrict__ col_T, const float* __restrict__ tot,
    const float* __restrict__ tr,
    const float* __restrict__ gw, const float* __restrict__ gb,
    float* __restrict__ nb_t1) {
  __shared__ float in[320];
  int e = blockIdx.x, t = threadIdx.x;
  in[t] = diag_T[e * 64 + t]; in[64 + t] = row_T[e * 64 + t];
  in[128 + t] = col_T[e * 64 + t]; in[192 + t] = tot[t]; in[256 + t] = tr[t];
  __syncthreads();
  float a = gb[t];
  for (int k = 0; k < 320; ++k) a += in[k] * gw[k * 64 + t];
  nb_t1[e * 64 + t] = a;
}

// ----- K17: coord weight w_e, seg/cnt/nb_t0 scatters, edge_attr passthrough --
__global__ __launch_bounds__(128) void k_edge_out(
    const int* __restrict__ edges, const float* __restrict__ coord_diff,
    const float* __restrict__ nb_t1, const float* __restrict__ edge_attr,
    const float* __restrict__ cw1, const float* __restrict__ cb1,
    const float* __restrict__ cw2,
    float* __restrict__ seg, float* __restrict__ cnt, float* __restrict__ nb_t0,
    float* __restrict__ out_ea) {
  __shared__ float in[64];
  __shared__ float red[128];
  int e = blockIdx.x, t = threadIdx.x;
  if (t < 64) in[t] = nb_t1[e * 64 + t];
  __syncthreads();
  float a = cb1[t];
  for (int k = 0; k < 64; ++k) a += in[k] * cw1[k * 128 + t];
  red[t] = silu_f(a) * cw2[t];
  __syncthreads();
  for (int s2 = 64; s2 > 0; s2 >>= 1) {
    if (t < s2) red[t] += red[t + s2];
    __syncthreads();
  }
  float w = red[0];
  int r = edges[e];
  if (t < 3) atomicAdd(&seg[r * 3 + t], coord_diff[e * 3 + t] * w);
  if (t == 64) atomicAdd(&cnt[r], 1.0f);
  if (t < 64) atomicAdd(&nb_t0[r * 64 + t], in[t]);
  if (t < 4) out_ea[e * 4 + t] = edge_attr[e * 4 + t];
}

// ---------------- K18: x_new and h_new ---------------------------------------
__global__ __launch_bounds__(128) void k_node_out(
    const float* __restrict__ h, const float* __restrict__ x,
    const float* __restrict__ seg, const float* __restrict__ cnt,
    const float* __restrict__ nb_t0,
    const float* __restrict__ w1, const float* __restrict__ b1,
    const float* __restrict__ w2, const float* __restrict__ b2,
    float* __restrict__ out_h, float* __restrict__ out_x) {
  __shared__ float in[64];
  __shared__ float hs[128];
  int n = blockIdx.x, t = threadIdx.x;
  if (t < 3) {
    float c = cnt[n]; if (c < 1.f) c = 1.f;
    out_x[n * 3 + t] = x[n * 3 + t] + seg[n * 3 + t] / c;
  }
  if (t < 64) in[t] = nb_t0[n * 64 + t];
  __syncthreads();
  float a = b1[t];
  for (int k = 0; k < 64; ++k) a += in[k] * w1[k * 128 + t];
  hs[t] = silu_f(a);
  __syncthreads();
  if (t < 64) {
    float o = b2[t];
    for (int k = 0; k < 128; ++k) o += hs[k] * w2[k * 64 + t];
    out_h[n * 64 + t] = h[n * 64 + t] + o;
  }
}

extern "C" void kernel_launch(void* const* d_in, const int* in_sizes, int n_in,
                              void* d_out, int out_size, void* d_ws, size_t ws_size,
                              hipStream_t stream) {
  (void)in_sizes; (void)n_in; (void)out_size; (void)ws_size;
  const float* h  = (const float*)d_in[0];
  const float* x  = (const float*)d_in[1];
  const int* edges   = (const int*)d_in[2];
  const int* nb_edge = (const int*)d_in[3];
  const float* edge_attr = (const float*)d_in[4];
  const float* ew1 = (const float*)d_in[6],  *eb1 = (const float*)d_in[7];
  const float* ew2 = (const float*)d_in[8],  *eb2 = (const float*)d_in[9];
  const float* p1w1 = (const float*)d_in[10], *p1b1 = (const float*)d_in[11];
  const float* p1w2 = (const float*)d_in[12], *p1b2 = (const float*)d_in[13];
  const float* p2w1 = (const float*)d_in[14], *p2b1 = (const float*)d_in[15];
  const float* p2w2 = (const float*)d_in[16], *p2b2 = (const float*)d_in[17];
  const float* p3w1 = (const float*)d_in[18], *p3b1 = (const float*)d_in[19];
  const float* p3w2 = (const float*)d_in[20], *p3b2 = (const float*)d_in[21];
  const float* ignw = (const float*)d_in[22], *ignb = (const float*)d_in[23];
  const float* cw1 = (const float*)d_in[24], *cb1 = (const float*)d_in[25];
  const float* cw2 = (const float*)d_in[26];
  const float* ndw1 = (const float*)d_in[27], *ndb1 = (const float*)d_in[28];
  const float* ndw2 = (const float*)d_in[29], *ndb2 = (const float*)d_in[30];

  // ---- workspace layout (~127.4 MB) ----
  char* ws = (char*)d_ws;
  float* S        = (float*)(ws + 0);           // [262144][64] = 67,108,864 B
  float* row_part = (float*)(ws + 67108864);    // [64][512][128] = 16,777,216 B
  float* col_part = (float*)(ws + 83886080);    // 16,777,216 B
  float* Tc       = (float*)(ws + 100663296);   // [16384][96] = 6,291,456 B
  float* D1       = (float*)(ws + 106954752);   // [16384][64] = 4,194,304 B
  float* D2       = (float*)(ws + 111149056);   // 4,194,304 B
  float* TWc      = (float*)(ws + 115343360);   // [16384][128] = 8,388,608 B
  int*   slotmap  = (int*)(ws + 123731968);     // [262144] = 1,048,576 B
  int*   cells    = (int*)(ws + 124780544);     // [16384] = 65,536 B
  int*   ib       = (int*)(ws + 124846080);
  int* cntA = ib;          int* nC = ib + 512;  // zeroed block [0..513)
  int* offA = ib + 1040;
  int* curA = ib + 2064;
  int* listA = ib + 3088;                        // 16384 ints, ends ib+19472
  float* fb = (float*)(ib + 35856);
  float* c1 = fb;            float* c2 = fb + 64;
  float* A  = fb + 128;      float* B  = fb + 32896;       // A,B contiguous 65536 floats @fb+128
  float* u  = fb + 65664;    float* v  = fb + 131200;
  float* coord_diff  = fb + 196736;
  float* efn         = fb + 198272;
  float* diag_silu   = fb + 231040;
  float* rowsum_silu = fb + 296576;
  float* colsum_silu = fb + 362112;
  float* diag_T      = fb + 427648;
  float* row_T       = fb + 460416;
  float* col_T       = fb + 493184;
  float* tot         = fb + 525952;
  float* tr          = fb + 526016;
  float* nb_t1       = fb + 526080;
  float* seg         = fb + 558848;   // seg,cnt,nb_t0 contiguous (one memset)
  float* cnt         = fb + 560384;
  float* nb_t0       = fb + 560896;

  float* out_h  = (float*)d_out;
  float* out_x  = out_h + 512 * 64;
  float* out_ea = out_x + 512 * 3;

  hipMemsetAsync(slotmap, 0xFF, 1048576, stream);               // -1
  hipMemsetAsync(Tc, 0, 6291456, stream);
  hipMemsetAsync(ib, 0, 513 * 4, stream);                       // cntA, nC
  hipMemsetAsync(A, 0, 65536 * 4, stream);                      // A and B
  hipMemsetAsync(seg, 0, (1536 + 512 + 32768) * 4, stream);

  k_edge<<<512, 128, 0, stream>>>(h, x, edges, ew1, eb1, ew2, eb2, coord_diff, efn);
  k_consts<<<1, 128, 0, stream>>>(p1b1, p1w2, p1b2, p2b1, p2w2, p2b2, c1, c2);
  k_mark<<<64, 256, 0, stream>>>(nb_edge, slotmap);
  k_compact<<<1024, 256, 0, stream>>>(slotmap, cells, nC, cntA);
  k_scan<<<1, 512, 0, stream>>>(cntA, offA, curA);
  k_fill<<<64, 256, 0, stream>>>(cells, nC, curA, listA);
  k_scatterT<<<6144, 256, 0, stream>>>(nb_edge, slotmap, coord_diff, efn, Tc);
  k_mlp96c<<<16384, 128, 0, stream>>>(cells, nC, Tc,
                                      p1w1, p1b1, p1w2, p1b2,
                                      p2w1, p2b1, p2w2, p2b2,
                                      c1, c2, p3w1, D1, D2, A, B, TWc);
  k_uv<<<dim3(512, 2), 128, 0, stream>>>(A, B, c1, c2, p3w1, p3b1, u, v);
  k_pairs_rows<<<512, 256, 0, stream>>>(cntA, offA, listA, cells, D1, D2, S);
  k_tout_fused<<<4096, 256, 0, stream>>>(S, u, v, TWc, slotmap, p3w1,
                                         row_part, col_part, diag_silu);
  k_sumparts<<<512, 256, 0, stream>>>(row_part, col_part, rowsum_silu, colsum_silu);
  k_tout2<<<dim3(512, 3), 64, 0, stream>>>(diag_silu, rowsum_silu, colsum_silu,
                                           p3w2, p3b2, diag_T, row_T, col_T);
  k_totr<<<1, 128, 0, stream>>>(row_T, diag_T, tot, tr);
  k_nbt1<<<512, 64, 0, stream>>>(diag_T, row_T, col_T, tot, tr, ignw, ignb, nb_t1);
  k_edge_out<<<512, 128, 0, stream>>>(edges, coord_diff, nb_t1, edge_attr,
                                      cw1, cb1, cw2, seg, cnt, nb_t0, out_ea);
  k_node_out<<<512, 128, 0, stream>>>(h, x, seg, cnt, nb_t0,
                                      ndw1, ndb1, ndw2, ndb2, out_h, out_x);
}

// Round 4
// 668.587 us; speedup vs baseline: 6.5041x; 1.0657x over previous
//
#include <hip/hip_runtime.h>
#include <hip/hip_bf16.h>

// Problem constants (static per reference)
#define NN   512    // nodes
#define EE   512    // edges == nb-graph nodes (En)
#define MM   16384  // nb-graph edges
#define PCAP 4194304 // pair-list capacity (actual ~524K)

__device__ __forceinline__ float silu_f(float v) { return v / (1.0f + __expf(-v)); }

// ---------------- K1: per original edge: coord_diff + efn = MLP([h_r|h_c]) ----
__global__ __launch_bounds__(128) void k_edge(
    const float* __restrict__ h, const float* __restrict__ x,
    const int* __restrict__ edges,
    const float* __restrict__ ew1, const float* __restrict__ eb1,
    const float* __restrict__ ew2, const float* __restrict__ eb2,
    float* __restrict__ coord_diff, float* __restrict__ efn) {
  __shared__ float hin[128];
  __shared__ float hs[128];
  int e = blockIdx.x;
  int t = threadIdx.x;
  int r = edges[e], c = edges[EE + e];
  if (t < 3) coord_diff[e * 3 + t] = x[r * 3 + t] - x[c * 3 + t];
  if (t < 64) { hin[t] = h[r * 64 + t]; hin[64 + t] = h[c * 64 + t]; }
  __syncthreads();
  float acc = eb1[t];
  for (int k = 0; k < 128; ++k) acc += hin[k] * ew1[k * 128 + t];
  hs[t] = silu_f(acc);
  __syncthreads();
  if (t < 64) {
    float o = eb2[t];
    for (int k = 0; k < 128; ++k) o += hs[k] * ew2[k * 64 + t];
    efn[e * 64 + t] = o;
  }
}

// ---------------- K2: constants c1 = MLP1(0), c2 = MLP2(0) -------------------
__global__ __launch_bounds__(128) void k_consts(
    const float* __restrict__ p1b1, const float* __restrict__ p1w2, const float* __restrict__ p1b2,
    const float* __restrict__ p2b1, const float* __restrict__ p2w2, const float* __restrict__ p2b2,
    float* __restrict__ c1, float* __restrict__ c2) {
  __shared__ float h1[128], h2[128];
  int t = threadIdx.x;
  h1[t] = silu_f(p1b1[t]); h2[t] = silu_f(p2b1[t]);
  __syncthreads();
  if (t < 64) {
    float a1 = p1b2[t], a2 = p2b2[t];
    for (int k = 0; k < 128; ++k) { a1 += h1[k] * p1w2[k * 64 + t]; a2 += h2[k] * p2w2[k * 64 + t]; }
    c1[t] = a1; c2[t] = a2;
  }
}

// ---------------- K3: mark touched cells -------------------------------------
__global__ __launch_bounds__(256) void k_mark(const int* __restrict__ nb_edge,
                                              int* __restrict__ slotmap) {
  int m = blockIdx.x * 256 + threadIdx.x;
  if (m >= MM) return;
  int cell = nb_edge[m] * 512 + nb_edge[MM + m];
  atomicCAS(&slotmap[cell], -1, -2);
}

// ---------------- K4: compact marked cells -> slots, degree histogram --------
__global__ __launch_bounds__(256) void k_compact(int* __restrict__ slotmap,
                                                 int* __restrict__ cells,
                                                 int* __restrict__ nC,
                                                 int* __restrict__ cntA) {
  int cell = blockIdx.x * 256 + threadIdx.x;
  if (slotmap[cell] != -2) return;
  int s = atomicAdd(nC, 1);
  slotmap[cell] = s;
  cells[s] = cell;
  atomicAdd(&cntA[cell >> 9], 1);   // group by first coord a
}

// ---------------- K5: prefix sum for the CSR ---------------------------------
__global__ __launch_bounds__(512) void k_scan(const int* __restrict__ cntA,
                                              int* __restrict__ offA,
                                              int* __restrict__ curA) {
  __shared__ int sA[512];
  int t = threadIdx.x;
  int a0 = cntA[t];
  sA[t] = a0;
  for (int off = 1; off < 512; off <<= 1) {
    __syncthreads();
    int a = (t >= off) ? sA[t - off] : 0;
    __syncthreads();
    sA[t] += a;
  }
  __syncthreads();
  offA[t] = sA[t] - a0;
  curA[t] = sA[t] - a0;
}

// ---------------- K6: fill CSR list (cells grouped by first coord) -----------
__global__ __launch_bounds__(256) void k_fill(const int* __restrict__ cells, const int* __restrict__ nC,
                                              int* __restrict__ curA,
                                              int* __restrict__ listA) {
  int s = blockIdx.x * 256 + threadIdx.x;
  if (s >= *nC) return;
  int cell = cells[s];
  listA[atomicAdd(&curA[cell >> 9], 1)] = s;
}

// ------- K6b: exclusive scan of per-cell pair counts pc[q]=cntA[second(listA[q])]
__global__ __launch_bounds__(1024) void k_pscan(
    const int* __restrict__ nC, const int* __restrict__ cntA,
    const int* __restrict__ listA, const int* __restrict__ cells,
    int* __restrict__ pOff) {
  __shared__ int part[1024];
  int t = threadIdx.x, nc = *nC;
  int v[16]; int sum = 0;
#pragma unroll
  for (int ii = 0; ii < 16; ++ii) {
    int q = t * 16 + ii;
    int xv = 0;
    if (q < nc) xv = cntA[cells[listA[q]] & 511];
    v[ii] = xv; sum += xv;
  }
  part[t] = sum;
  for (int off = 1; off < 1024; off <<= 1) {
    __syncthreads();
    int a = (t >= off) ? part[t - off] : 0;
    __syncthreads();
    part[t] += a;
  }
  __syncthreads();
  int r = part[t] - sum;   // exclusive base
#pragma unroll
  for (int ii = 0; ii < 16; ++ii) {
    int q = t * 16 + ii;
    if (q <= nc) pOff[q] = r;
    r += v[ii];
  }
  if (t == 1023 && nc == 16384) pOff[16384] = r;
}

// ------- K6c: per-row pair ranges --------------------------------------------
__global__ __launch_bounds__(512) void k_rowpair(
    const int* __restrict__ nC, const int* __restrict__ offA,
    const int* __restrict__ pOff,
    int* __restrict__ rpOff, int* __restrict__ rpCnt) {
  int i = threadIdx.x;
  int nc = *nC;
  int q0 = offA[i];
  int q1 = (i == 511) ? nc : offA[i + 1];
  int a = pOff[q0], b = pOff[q1];
  rpOff[i] = a; rpCnt[i] = b - a;
}

// ------- K6d: fill flat pair list (grouped by row i) -------------------------
__global__ __launch_bounds__(64) void k_pfill(
    const int* __restrict__ nC, const int* __restrict__ cntA, const int* __restrict__ offA,
    const int* __restrict__ listA, const int* __restrict__ cells,
    const int* __restrict__ pOff, uint2* __restrict__ pairList) {
  int q = blockIdx.x;
  if (q >= *nC) return;
  int s1 = listA[q];
  int k = cells[s1] & 511;
  int n2 = cntA[k], o2 = offA[k], base = pOff[q];
  for (int p2 = threadIdx.x; p2 < n2; p2 += 64) {
    int s2 = listA[o2 + p2];
    int j = cells[s2] & 511;
    int idx = base + p2;
    if (idx < PCAP)
      pairList[idx] = make_uint2((unsigned)s1, (unsigned)s2 | ((unsigned)j << 18));
  }
}

// ---------------- K7: nb_feat scatter-add into COMPACT Tc --------------------
__global__ __launch_bounds__(256) void k_scatterT(
    const int* __restrict__ nb_edge, const int* __restrict__ slotmap,
    const float* __restrict__ coord_diff, const float* __restrict__ efn,
    float* __restrict__ Tc) {
  int tid = blockIdx.x * 256 + threadIdx.x;
  if (tid >= MM * 96) return;
  int m = tid / 96, c = tid % 96;
  int a = nb_edge[m], b = nb_edge[MM + m];
  float val;
  if (c < 32) {
    float vtv = coord_diff[a * 3 + 0] * coord_diff[b * 3 + 0]
              + coord_diff[a * 3 + 1] * coord_diff[b * 3 + 1]
              + coord_diff[a * 3 + 2] * coord_diff[b * 3 + 2];
    int i = c >> 1;
    float ang = vtv * 16.0f * __expf(-0.57564627324851143f * (float)i);
    val = (c & 1) ? cosf(ang) : sinf(ang);
  } else {
    int f = c - 32;
    val = efn[a * 64 + f] * efn[b * 64 + f];
  }
  int s = slotmap[a * 512 + b];
  atomicAdd(&Tc[s * 96 + c], val);
}

// ------- K8: batched (8 cells/block) MLPs -> D1/D2, sums A,B; TWc = Tc@w1T ---
// Padding cells read zeros from Tc (memset) -> D = MLP(0)-c = 0; stores guarded.
__global__ __launch_bounds__(128) void k_mlp96b(
    const int* __restrict__ cells, const int* __restrict__ nC, const float* __restrict__ Tc,
    const float* __restrict__ w11, const float* __restrict__ b11,
    const float* __restrict__ w12, const float* __restrict__ b12,
    const float* __restrict__ w21, const float* __restrict__ b21,
    const float* __restrict__ w22, const float* __restrict__ b22,
    const float* __restrict__ c1, const float* __restrict__ c2,
    const float* __restrict__ p3w1,
    float* __restrict__ D1, float* __restrict__ D2,
    float* __restrict__ A, float* __restrict__ B,
    float* __restrict__ TWc) {
  __shared__ float xs[8][96];
  __shared__ float hid[8][128];
  __shared__ int cl[8];
  int t = threadIdx.x;
  int nc = *nC;
  int s0 = blockIdx.x * 8;
  if (s0 >= nc) return;
  for (int e = t; e < 768; e += 128) ((float*)xs)[e] = Tc[s0 * 96 + e];
  if (t < 8) cl[t] = (s0 + t < nc) ? cells[s0 + t] : 0;
  __syncthreads();
  // phase 1: thread t = hidden unit h; fused TW + both hidden layers
  float tw[8], a1[8], a2[8];
#pragma unroll
  for (int c = 0; c < 8; ++c) { tw[c] = 0.f; a1[c] = b11[t]; a2[c] = b21[t]; }
  for (int k = 0; k < 96; ++k) {
    float wt = p3w1[k * 128 + t];
    float w1v = w11[k * 128 + t];
    float w2v = w21[k * 128 + t];
#pragma unroll
    for (int c = 0; c < 8; ++c) {
      float xv = xs[c][k];
      tw[c] += xv * wt; a1[c] += xv * w1v; a2[c] += xv * w2v;
    }
  }
#pragma unroll
  for (int c = 0; c < 8; ++c) {
    if (s0 + c < nc) TWc[(s0 + c) * 128 + t] = tw[c];
    hid[c][t] = silu_f(a1[c]);
  }
  __syncthreads();
  if (t < 64) {
    float o[8];
#pragma unroll
    for (int c = 0; c < 8; ++c) o[c] = b12[t];
    for (int k = 0; k < 128; ++k) {
      float w = w12[k * 64 + t];
#pragma unroll
      for (int c = 0; c < 8; ++c) o[c] += hid[c][k] * w;
    }
#pragma unroll
    for (int c = 0; c < 8; ++c)
      if (s0 + c < nc) {
        float d = o[c] - c1[t];
        D1[(s0 + c) * 64 + t] = d;
        atomicAdd(&A[(cl[c] >> 9) * 64 + t], d);
      }
  }
  __syncthreads();
#pragma unroll
  for (int c = 0; c < 8; ++c) hid[c][t] = silu_f(a2[c]);
  __syncthreads();
  if (t < 64) {
    float o[8];
#pragma unroll
    for (int c = 0; c < 8; ++c) o[c] = b22[t];
    for (int k = 0; k < 128; ++k) {
      float w = w22[k * 64 + t];
#pragma unroll
      for (int c = 0; c < 8; ++c) o[c] += hid[c][k] * w;
    }
#pragma unroll
    for (int c = 0; c < 8; ++c)
      if (s0 + c < nc) {
        float d = o[c] - c2[t];
        D2[(s0 + c) * 64 + t] = d;
        atomicAdd(&B[(cl[c] & 511) * 64 + t], d);
      }
  }
}

// ---------------- K10: u[i] = b1 + (512 c1c2 + c2*A[i])@w1m ; v[j] = (c1*B[j])@w1m
__global__ __launch_bounds__(128) void k_uv(
    const float* __restrict__ A, const float* __restrict__ B,
    const float* __restrict__ c1, const float* __restrict__ c2,
    const float* __restrict__ p3w1, const float* __restrict__ p3b1,
    float* __restrict__ u, float* __restrict__ v) {
  __shared__ float vec[64];
  int i = blockIdx.x, y = blockIdx.y, t = threadIdx.x;
  if (t < 64)
    vec[t] = (y == 0) ? (512.0f * c1[t] * c2[t] + c2[t] * A[i * 64 + t])
                      : (c1[t] * B[i * 64 + t]);
  __syncthreads();
  float a = (y == 0) ? p3b1[t] : 0.f;
  for (int f = 0; f < 64; ++f) a += vec[f] * p3w1[(96 + f) * 128 + t];
  (y == 0 ? u : v)[i * 128 + t] = a;
}

// ---------------- K11: flat-pair-list S accumulation in LDS ------------------
// Block = (row i, feature-half). 512 thr = 16 groups x 32 lanes (lane=f).
// Flat loop over precomputed pairs with prefetch; LDS atomics; dense writeback.
__global__ __launch_bounds__(512) void k_pairs_flat(
    const int* __restrict__ rpOff, const int* __restrict__ rpCnt,
    const uint2* __restrict__ pairList,
    const float* __restrict__ D1, const float* __restrict__ D2,
    float* __restrict__ S) {
  __shared__ float Srow[512 * 32];   // 64 KB
  int i = blockIdx.x, half = blockIdx.y;
  int t = threadIdx.x;
  int f = t & 31, g = t >> 5;        // 16 groups
  for (int e = t; e < 16384; e += 512) Srow[e] = 0.f;
  __syncthreads();
  int n = rpCnt[i], base = rpOff[i];
  int fofs = half * 32 + f;
  int p = g;
  if (p < n) {
    uint2 nxt = pairList[base + p];
    while (true) {
      uint2 cur = nxt;
      p += 16;
      bool more = (p < n);
      if (more) nxt = pairList[base + p];
      float d1 = D1[cur.x * 64 + fofs];
      float d2 = D2[(cur.y & 0x3FFFFu) * 64 + fofs];
      atomicAdd(&Srow[(cur.y >> 18) * 32 + f], d1 * d2);
      if (!more) break;
    }
  }
  __syncthreads();
  for (int e = t; e < 16384; e += 512) {
    int j = e >> 5, ff = e & 31;
    S[(i * 512 + j) * 64 + half * 32 + ff] = Srow[e];
  }
}

// ------- K12: fused z = u[i]+v[j]+S@w1m+TW, silu, row/col/diag reduce --------
__global__ __launch_bounds__(256) void k_tout_fused(
    const float* __restrict__ S, const float* __restrict__ u, const float* __restrict__ v,
    const float* __restrict__ TWc, const int* __restrict__ slotmap,
    const float* __restrict__ p3w1,
    float* __restrict__ row_part, float* __restrict__ col_part,
    float* __restrict__ diag_silu) {
  __shared__ float Ss[64 * 65];
  __shared__ float Wm[64 * 128];
  __shared__ float uvs[2048];
  __shared__ int slotL[64];
  int t = threadIdx.x;
  int cg = t & 7, hg = t >> 3;
  int bi = blockIdx.x >> 6, bj = blockIdx.x & 63;
  int i0 = bi * 8, j0 = bj * 8;
  for (int e = t; e < 4096; e += 256) {
    int cl = e >> 6, f = e & 63;
    Ss[cl * 65 + f] = S[((i0 + (cl >> 3)) * 512 + j0 + (cl & 7)) * 64 + f];
  }
  for (int e = t; e < 8192; e += 256) Wm[e] = p3w1[96 * 128 + e];
  for (int e = t; e < 1024; e += 256) uvs[e] = u[(i0 + (e >> 7)) * 128 + (e & 127)];
  for (int e = t; e < 1024; e += 256) uvs[1024 + e] = v[(j0 + (e >> 7)) * 128 + (e & 127)];
  if (t < 64) slotL[t] = slotmap[(i0 + (t >> 3)) * 512 + j0 + (t & 7)];
  __syncthreads();
  float4 acc[8];
#pragma unroll
  for (int cj = 0; cj < 8; ++cj) acc[cj] = make_float4(0.f, 0.f, 0.f, 0.f);
  for (int kk = 0; kk < 64; ++kk) {
    float4 wv = *(const float4*)&Wm[kk * 128 + hg * 4];
#pragma unroll
    for (int cj = 0; cj < 8; ++cj) {
      float xv = Ss[(cg * 8 + cj) * 65 + kk];
      acc[cj].x += xv * wv.x; acc[cj].y += xv * wv.y;
      acc[cj].z += xv * wv.z; acc[cj].w += xv * wv.w;
    }
  }
  float4 uu = *(const float4*)&uvs[cg * 128 + hg * 4];
#pragma unroll
  for (int cj = 0; cj < 8; ++cj) {
    float4 vv = *(const float4*)&uvs[1024 + cj * 128 + hg * 4];
    float4 z = make_float4(acc[cj].x + uu.x + vv.x, acc[cj].y + uu.y + vv.y,
                           acc[cj].z + uu.z + vv.z, acc[cj].w + uu.w + vv.w);
    int s = slotL[cg * 8 + cj];
    if (s >= 0) {
      float4 tw = *(const float4*)&TWc[s * 128 + hg * 4];
      z.x += tw.x; z.y += tw.y; z.z += tw.z; z.w += tw.w;
    }
    acc[cj] = make_float4(silu_f(z.x), silu_f(z.y), silu_f(z.z), silu_f(z.w));
  }
  float4 rs = make_float4(0.f, 0.f, 0.f, 0.f);
#pragma unroll
  for (int cj = 0; cj < 8; ++cj) {
    rs.x += acc[cj].x; rs.y += acc[cj].y; rs.z += acc[cj].z; rs.w += acc[cj].w;
  }
  *(float4*)&row_part[(bj * 512 + i0 + cg) * 128 + hg * 4] = rs;
#pragma unroll
  for (int cj = 0; cj < 8; ++cj) {
    float4 cs = acc[cj];
#pragma unroll
    for (int msk = 1; msk < 8; msk <<= 1) {
      cs.x += __shfl_xor(cs.x, msk); cs.y += __shfl_xor(cs.y, msk);
      cs.z += __shfl_xor(cs.z, msk); cs.w += __shfl_xor(cs.w, msk);
    }
    if (cg == 0)
      *(float4*)&col_part[(bi * 512 + j0 + cj) * 128 + hg * 4] = cs;
  }
  if (bi == bj) {
#pragma unroll
    for (int cj = 0; cj < 8; ++cj)
      if (cj == cg)
        *(float4*)&diag_silu[(i0 + cg) * 128 + hg * 4] = acc[cj];
  }
}

// ---------------- K13: reduce 64 partial slices ------------------------------
__global__ __launch_bounds__(256) void k_sumparts(
    const float* __restrict__ row_part, const float* __restrict__ col_part,
    float* __restrict__ rowsum, float* __restrict__ colsum) {
  int i = blockIdx.x, t = threadIdx.x;
  const float* src = (t < 128) ? row_part : col_part;
  float* dst = (t < 128) ? rowsum : colsum;
  int hc = t & 127;
  float a = 0.f;
  for (int p = 0; p < 64; ++p) a += src[(p * 512 + i) * 128 + hc];
  dst[i * 128 + hc] = a;
}

// ---------------- K14: second layer of p3 MLP on reduced silu sums -----------
__global__ __launch_bounds__(64) void k_tout2(
    const float* __restrict__ diag_silu, const float* __restrict__ rowsum_silu,
    const float* __restrict__ colsum_silu,
    const float* __restrict__ w2, const float* __restrict__ b2,
    float* __restrict__ diag_T, float* __restrict__ row_T, float* __restrict__ col_T) {
  __shared__ float in[128];
  int e = blockIdx.x, which = blockIdx.y, t = threadIdx.x;
  const float* src = (which == 0) ? diag_silu : (which == 1) ? rowsum_silu : colsum_silu;
  in[t] = src[e * 128 + t]; in[64 + t] = src[e * 128 + 64 + t];
  __syncthreads();
  float a = 0.f;
  for (int k = 0; k < 128; ++k) a += in[k] * w2[k * 64 + t];
  float bias = b2[t] * ((which == 0) ? 1.0f : 512.0f);
  float* dst = (which == 0) ? diag_T : (which == 1) ? row_T : col_T;
  dst[e * 64 + t] = a + bias;
}

// ---------------- K15: tot / tr ----------------------------------------------
__global__ __launch_bounds__(128) void k_totr(
    const float* __restrict__ row_T, const float* __restrict__ diag_T,
    float* __restrict__ tot, float* __restrict__ tr) {
  int t = threadIdx.x;
  const float* src = (t < 64) ? row_T : diag_T;
  int f = t & 63;
  float a = 0.f;
  for (int e = 0; e < 512; ++e) a += src[e * 64 + f];
  if (t < 64) tot[f] = a; else tr[f] = a;
}

// ---------------- K16: nb_t1 = [diag|row|col|tot|tr] @ ign_w + ign_b ---------
__global__ __launch_bounds__(64) void k_nbt1(
    const float* __restrict__ diag_T, const float* __restrict__ row_T,
    const float* __restrict__ col_T, const float* __restrict__ tot,
    const float* __restrict__ tr,
    const float* __restrict__ gw, const float* __restrict__ gb,
    float* __restrict__ nb_t1) {
  __shared__ float in[320];
  int e = blockIdx.x, t = threadIdx.x;
  in[t] = diag_T[e * 64 + t]; in[64 + t] = row_T[e * 64 + t];
  in[128 + t] = col_T[e * 64 + t]; in[192 + t] = tot[t]; in[256 + t] = tr[t];
  __syncthreads();
  float a = gb[t];
  for (int k = 0; k < 320; ++k) a += in[k] * gw[k * 64 + t];
  nb_t1[e * 64 + t] = a;
}

// ----- K17: coord weight w_e, seg/cnt/nb_t0 scatters, edge_attr passthrough --
__global__ __launch_bounds__(128) void k_edge_out(
    const int* __restrict__ edges, const float* __restrict__ coord_diff,
    const float* __restrict__ nb_t1, const float* __restrict__ edge_attr,
    const float* __restrict__ cw1, const float* __restrict__ cb1,
    const float* __restrict__ cw2,
    float* __restrict__ seg, float* __restrict__ cnt, float* __restrict__ nb_t0,
    float* __restrict__ out_ea) {
  __shared__ float in[64];
  __shared__ float red[128];
  int e = blockIdx.x, t = threadIdx.x;
  if (t < 64) in[t] = nb_t1[e * 64 + t];
  __syncthreads();
  float a = cb1[t];
  for (int k = 0; k < 64; ++k) a += in[k] * cw1[k * 128 + t];
  red[t] = silu_f(a) * cw2[t];
  __syncthreads();
  for (int s2 = 64; s2 > 0; s2 >>= 1) {
    if (t < s2) red[t] += red[t + s2];
    __syncthreads();
  }
  float w = red[0];
  int r = edges[e];
  if (t < 3) atomicAdd(&seg[r * 3 + t], coord_diff[e * 3 + t] * w);
  if (t == 64) atomicAdd(&cnt[r], 1.0f);
  if (t < 64) atomicAdd(&nb_t0[r * 64 + t], in[t]);
  if (t < 4) out_ea[e * 4 + t] = edge_attr[e * 4 + t];
}

// ---------------- K18: x_new and h_new ---------------------------------------
__global__ __launch_bounds__(128) void k_node_out(
    const float* __restrict__ h, const float* __restrict__ x,
    const float* __restrict__ seg, const float* __restrict__ cnt,
    const float* __restrict__ nb_t0,
    const float* __restrict__ w1, const float* __restrict__ b1,
    const float* __restrict__ w2, const float* __restrict__ b2,
    float* __restrict__ out_h, float* __restrict__ out_x) {
  __shared__ float in[64];
  __shared__ float hs[128];
  int n = blockIdx.x, t = threadIdx.x;
  if (t < 3) {
    float c = cnt[n]; if (c < 1.f) c = 1.f;
    out_x[n * 3 + t] = x[n * 3 + t] + seg[n * 3 + t] / c;
  }
  if (t < 64) in[t] = nb_t0[n * 64 + t];
  __syncthreads();
  float a = b1[t];
  for (int k = 0; k < 64; ++k) a += in[k] * w1[k * 128 + t];
  hs[t] = silu_f(a);
  __syncthreads();
  if (t < 64) {
    float o = b2[t];
    for (int k = 0; k < 128; ++k) o += hs[k] * w2[k * 64 + t];
    out_h[n * 64 + t] = h[n * 64 + t] + o;
  }
}

extern "C" void kernel_launch(void* const* d_in, const int* in_sizes, int n_in,
                              void* d_out, int out_size, void* d_ws, size_t ws_size,
                              hipStream_t stream) {
  (void)in_sizes; (void)n_in; (void)out_size; (void)ws_size;
  const float* h  = (const float*)d_in[0];
  const float* x  = (const float*)d_in[1];
  const int* edges   = (const int*)d_in[2];
  const int* nb_edge = (const int*)d_in[3];
  const float* edge_attr = (const float*)d_in[4];
  const float* ew1 = (const float*)d_in[6],  *eb1 = (const float*)d_in[7];
  const float* ew2 = (const float*)d_in[8],  *eb2 = (const float*)d_in[9];
  const float* p1w1 = (const float*)d_in[10], *p1b1 = (const float*)d_in[11];
  const float* p1w2 = (const float*)d_in[12], *p1b2 = (const float*)d_in[13];
  const float* p2w1 = (const float*)d_in[14], *p2b1 = (const float*)d_in[15];
  const float* p2w2 = (const float*)d_in[16], *p2b2 = (const float*)d_in[17];
  const float* p3w1 = (const float*)d_in[18], *p3b1 = (const float*)d_in[19];
  const float* p3w2 = (const float*)d_in[20], *p3b2 = (const float*)d_in[21];
  const float* ignw = (const float*)d_in[22], *ignb = (const float*)d_in[23];
  const float* cw1 = (const float*)d_in[24], *cb1 = (const float*)d_in[25];
  const float* cw2 = (const float*)d_in[26];
  const float* ndw1 = (const float*)d_in[27], *ndb1 = (const float*)d_in[28];
  const float* ndw2 = (const float*)d_in[29], *ndb2 = (const float*)d_in[30];

  // ---- workspace layout (~168 MB) ----
  char* ws = (char*)d_ws;
  float* S        = (float*)(ws + 0);           // [262144][64] = 67,108,864 B
  float* row_part = (float*)(ws + 67108864);    // [64][512][128] = 16,777,216 B
  float* col_part = (float*)(ws + 83886080);    // 16,777,216 B
  float* Tc       = (float*)(ws + 100663296);   // [16384][96] = 6,291,456 B
  float* D1       = (float*)(ws + 106954752);   // [16384][64] = 4,194,304 B
  float* D2       = (float*)(ws + 111149056);   // 4,194,304 B
  float* TWc      = (float*)(ws + 115343360);   // [16384][128] = 8,388,608 B
  int*   slotmap  = (int*)(ws + 123731968);     // [262144] = 1,048,576 B
  int*   cells    = (int*)(ws + 124780544);     // [16384] = 65,536 B
  int*   ib       = (int*)(ws + 124846080);
  int* cntA = ib;          int* nC = ib + 512;  // zeroed block [0..513)
  int* offA = ib + 1040;
  int* curA = ib + 2064;
  int* listA = ib + 3088;                        // 16384 ints, ends ib+19472
  float* fb = (float*)(ib + 35856);
  float* c1 = fb;            float* c2 = fb + 64;
  float* A  = fb + 128;      float* B  = fb + 32896;       // A,B contiguous 65536 floats @fb+128
  float* u  = fb + 65664;    float* v  = fb + 131200;
  float* coord_diff  = fb + 196736;
  float* efn         = fb + 198272;
  float* diag_silu   = fb + 231040;
  float* rowsum_silu = fb + 296576;
  float* colsum_silu = fb + 362112;
  float* diag_T      = fb + 427648;
  float* row_T       = fb + 460416;
  float* col_T       = fb + 493184;
  float* tot         = fb + 525952;
  float* tr          = fb + 526016;
  float* nb_t1       = fb + 526080;
  float* seg         = fb + 558848;   // seg,cnt,nb_t0 contiguous (one memset)
  float* cnt         = fb + 560384;
  float* nb_t0       = fb + 560896;
  uint2* pairList = (uint2*)(ws + 134217728);   // PCAP*8 = 33,554,432 B
  int*   pOff     = (int*)(ws + 167772160);     // 16385 ints
  int*   rpOff    = (int*)(ws + 167903232);     // 512 ints
  int*   rpCnt    = (int*)(ws + 167905280);     // 512 ints

  float* out_h  = (float*)d_out;
  float* out_x  = out_h + 512 * 64;
  float* out_ea = out_x + 512 * 3;

  hipMemsetAsync(slotmap, 0xFF, 1048576, stream);               // -1
  hipMemsetAsync(Tc, 0, 6291456, stream);
  hipMemsetAsync(ib, 0, 513 * 4, stream);                       // cntA, nC
  hipMemsetAsync(A, 0, 65536 * 4, stream);                      // A and B
  hipMemsetAsync(seg, 0, (1536 + 512 + 32768) * 4, stream);

  k_edge<<<512, 128, 0, stream>>>(h, x, edges, ew1, eb1, ew2, eb2, coord_diff, efn);
  k_consts<<<1, 128, 0, stream>>>(p1b1, p1w2, p1b2, p2b1, p2w2, p2b2, c1, c2);
  k_mark<<<64, 256, 0, stream>>>(nb_edge, slotmap);
  k_compact<<<1024, 256, 0, stream>>>(slotmap, cells, nC, cntA);
  k_scan<<<1, 512, 0, stream>>>(cntA, offA, curA);
  k_fill<<<64, 256, 0, stream>>>(cells, nC, curA, listA);
  k_pscan<<<1, 1024, 0, stream>>>(nC, cntA, listA, cells, pOff);
  k_rowpair<<<1, 512, 0, stream>>>(nC, offA, pOff, rpOff, rpCnt);
  k_pfill<<<16384, 64, 0, stream>>>(nC, cntA, offA, listA, cells, pOff, pairList);
  k_scatterT<<<6144, 256, 0, stream>>>(nb_edge, slotmap, coord_diff, efn, Tc);
  k_mlp96b<<<2048, 128, 0, stream>>>(cells, nC, Tc,
                                     p1w1, p1b1, p1w2, p1b2,
                                     p2w1, p2b1, p2w2, p2b2,
                                     c1, c2, p3w1, D1, D2, A, B, TWc);
  k_uv<<<dim3(512, 2), 128, 0, stream>>>(A, B, c1, c2, p3w1, p3b1, u, v);
  k_pairs_flat<<<dim3(512, 2), 512, 0, stream>>>(rpOff, rpCnt, pairList, D1, D2, S);
  k_tout_fused<<<4096, 256, 0, stream>>>(S, u, v, TWc, slotmap, p3w1,
                                         row_part, col_part, diag_silu);
  k_sumparts<<<512, 256, 0, stream>>>(row_part, col_part, rowsum_silu, colsum_silu);
  k_tout2<<<dim3(512, 3), 64, 0, stream>>>(diag_silu, rowsum_silu, colsum_silu,
                                           p3w2, p3b2, diag_T, row_T, col_T);
  k_totr<<<1, 128, 0, stream>>>(row_T, diag_T, tot, tr);
  k_nbt1<<<512, 64, 0, stream>>>(diag_T, row_T, col_T, tot, tr, ignw, ignb, nb_t1);
  k_edge_out<<<512, 128, 0, stream>>>(edges, coord_diff, nb_t1, edge_attr,
                                      cw1, cb1, cw2, seg, cnt, nb_t0, out_ea);
  k_node_out<<<512, 128, 0, stream>>>(h, x, seg, cnt, nb_t0,
                                      ndw1, ndb1, ndw2, ndb2, out_h, out_x);
}

// Round 5
// 519.854 us; speedup vs baseline: 8.3650x; 1.2861x over previous
//
#include <hip/hip_runtime.h>
#include <hip/hip_bf16.h>

// Problem constants (static per reference)
#define NN   512    // nodes
#define EE   512    // edges == nb-graph nodes (En)
#define MM   16384  // nb-graph edges

__device__ __forceinline__ float silu_f(float v) { return v / (1.0f + __expf(-v)); }

// ---------------- K1: per original edge: coord_diff + efn = MLP([h_r|h_c]) ----
__global__ __launch_bounds__(128) void k_edge(
    const float* __restrict__ h, const float* __restrict__ x,
    const int* __restrict__ edges,
    const float* __restrict__ ew1, const float* __restrict__ eb1,
    const float* __restrict__ ew2, const float* __restrict__ eb2,
    float* __restrict__ coord_diff, float* __restrict__ efn) {
  __shared__ float hin[128];
  __shared__ float hs[128];
  int e = blockIdx.x;
  int t = threadIdx.x;
  int r = edges[e], c = edges[EE + e];
  if (t < 3) coord_diff[e * 3 + t] = x[r * 3 + t] - x[c * 3 + t];
  if (t < 64) { hin[t] = h[r * 64 + t]; hin[64 + t] = h[c * 64 + t]; }
  __syncthreads();
  float acc = eb1[t];
  for (int k = 0; k < 128; ++k) acc += hin[k] * ew1[k * 128 + t];
  hs[t] = silu_f(acc);
  __syncthreads();
  if (t < 64) {
    float o = eb2[t];
    for (int k = 0; k < 128; ++k) o += hs[k] * ew2[k * 64 + t];
    efn[e * 64 + t] = o;
  }
}

// ---------------- K2: constants c1 = MLP1(0), c2 = MLP2(0) -------------------
__global__ __launch_bounds__(128) void k_consts(
    const float* __restrict__ p1b1, const float* __restrict__ p1w2, const float* __restrict__ p1b2,
    const float* __restrict__ p2b1, const float* __restrict__ p2w2, const float* __restrict__ p2b2,
    float* __restrict__ c1, float* __restrict__ c2) {
  __shared__ float h1[128], h2[128];
  int t = threadIdx.x;
  h1[t] = silu_f(p1b1[t]); h2[t] = silu_f(p2b1[t]);
  __syncthreads();
  if (t < 64) {
    float a1 = p1b2[t], a2 = p2b2[t];
    for (int k = 0; k < 128; ++k) { a1 += h1[k] * p1w2[k * 64 + t]; a2 += h2[k] * p2w2[k * 64 + t]; }
    c1[t] = a1; c2[t] = a2;
  }
}

// ---------------- K3: mark touched cells -------------------------------------
__global__ __launch_bounds__(256) void k_mark(const int* __restrict__ nb_edge,
                                              int* __restrict__ slotmap) {
  int m = blockIdx.x * 256 + threadIdx.x;
  if (m >= MM) return;
  int cell = nb_edge[m] * 512 + nb_edge[MM + m];
  atomicCAS(&slotmap[cell], -1, -2);
}

// ---------------- K4: compact marked cells -> slots, degree histogram --------
__global__ __launch_bounds__(256) void k_compact(int* __restrict__ slotmap,
                                                 int* __restrict__ cells,
                                                 int* __restrict__ nC,
                                                 int* __restrict__ cntA) {
  int cell = blockIdx.x * 256 + threadIdx.x;
  if (slotmap[cell] != -2) return;
  int s = atomicAdd(nC, 1);
  slotmap[cell] = s;
  cells[s] = cell;
  atomicAdd(&cntA[cell >> 9], 1);   // group by first coord a
}

// ---------------- K5: prefix sum for the CSR ---------------------------------
__global__ __launch_bounds__(512) void k_scan(const int* __restrict__ cntA,
                                              int* __restrict__ offA,
                                              int* __restrict__ curA) {
  __shared__ int sA[512];
  int t = threadIdx.x;
  int a0 = cntA[t];
  sA[t] = a0;
  for (int off = 1; off < 512; off <<= 1) {
    __syncthreads();
    int a = (t >= off) ? sA[t - off] : 0;
    __syncthreads();
    sA[t] += a;
  }
  __syncthreads();
  offA[t] = sA[t] - a0;
  curA[t] = sA[t] - a0;
}

// -------- K6: fill CSR list, packing slot | (second-coord << 18) -------------
__global__ __launch_bounds__(256) void k_fill(const int* __restrict__ cells, const int* __restrict__ nC,
                                              int* __restrict__ curA,
                                              int* __restrict__ listAJ) {
  int s = blockIdx.x * 256 + threadIdx.x;
  if (s >= *nC) return;
  int cell = cells[s];
  listAJ[atomicAdd(&curA[cell >> 9], 1)] = s | ((cell & 511) << 18);
}

// ---------------- K7: nb_feat scatter-add into COMPACT Tc (2 edges/block) ----
__global__ __launch_bounds__(192) void k_scatterT(
    const int* __restrict__ nb_edge, const int* __restrict__ slotmap,
    const float* __restrict__ coord_diff, const float* __restrict__ efn,
    float* __restrict__ Tc) {
  int t = threadIdx.x;
  int sub = (t >= 96) ? 1 : 0;
  int c = t - sub * 96;
  int m = blockIdx.x * 2 + sub;
  int a = nb_edge[m], b = nb_edge[MM + m];
  int s = slotmap[a * 512 + b];
  float val;
  if (c < 32) {
    float vtv = coord_diff[a * 3 + 0] * coord_diff[b * 3 + 0]
              + coord_diff[a * 3 + 1] * coord_diff[b * 3 + 1]
              + coord_diff[a * 3 + 2] * coord_diff[b * 3 + 2];
    int i = c >> 1;
    float ang = vtv * 16.0f * __expf(-0.57564627324851143f * (float)i);
    val = (c & 1) ? cosf(ang) : sinf(ang);
  } else {
    int f = c - 32;
    val = efn[a * 64 + f] * efn[b * 64 + f];
  }
  atomicAdd(&Tc[s * 96 + c], val);
}

// ------- K8: batched (8 cells/block) MLPs -> D1/D2, sums A,B; TWc = Tc@w1T ---
// Padding cells read zeros from Tc (memset) -> D = MLP(0)-c = 0; stores guarded.
__global__ __launch_bounds__(128) void k_mlp96b(
    const int* __restrict__ cells, const int* __restrict__ nC, const float* __restrict__ Tc,
    const float* __restrict__ w11, const float* __restrict__ b11,
    const float* __restrict__ w12, const float* __restrict__ b12,
    const float* __restrict__ w21, const float* __restrict__ b21,
    const float* __restrict__ w22, const float* __restrict__ b22,
    const float* __restrict__ c1, const float* __restrict__ c2,
    const float* __restrict__ p3w1,
    float* __restrict__ D1, float* __restrict__ D2,
    float* __restrict__ A, float* __restrict__ B,
    float* __restrict__ TWc) {
  __shared__ float xsT[96 * 8];    // [k][cell] transposed for b128 reads
  __shared__ float hid[8][128];
  __shared__ int cl[8];
  int t = threadIdx.x;
  int nc = *nC;
  int s0 = blockIdx.x * 8;
  if (s0 >= nc) return;
  for (int e = t; e < 768; e += 128) xsT[(e % 96) * 8 + e / 96] = Tc[s0 * 96 + e];
  if (t < 8) cl[t] = (s0 + t < nc) ? cells[s0 + t] : 0;
  __syncthreads();
  // phase 1: thread t = hidden unit h; fused TW + both hidden layers
  float tw[8], a1[8], a2[8];
#pragma unroll
  for (int c = 0; c < 8; ++c) { tw[c] = 0.f; a1[c] = b11[t]; a2[c] = b21[t]; }
  for (int k = 0; k < 96; ++k) {
    float wt = p3w1[k * 128 + t];
    float w1v = w11[k * 128 + t];
    float w2v = w21[k * 128 + t];
    float4 xlo = *(const float4*)&xsT[k * 8];
    float4 xhi = *(const float4*)&xsT[k * 8 + 4];
    float xv[8] = {xlo.x, xlo.y, xlo.z, xlo.w, xhi.x, xhi.y, xhi.z, xhi.w};
#pragma unroll
    for (int c = 0; c < 8; ++c) {
      tw[c] += xv[c] * wt; a1[c] += xv[c] * w1v; a2[c] += xv[c] * w2v;
    }
  }
#pragma unroll
  for (int c = 0; c < 8; ++c) {
    if (s0 + c < nc) TWc[(s0 + c) * 128 + t] = tw[c];
    hid[c][t] = silu_f(a1[c]);
  }
  __syncthreads();
  {
    int hh = t & 63, cq = t >> 6;   // 128 threads: 2 half-waves x 4 cells
    float o[4];
#pragma unroll
    for (int cc = 0; cc < 4; ++cc) o[cc] = b12[hh];
    for (int k = 0; k < 128; ++k) {
      float w = w12[k * 64 + hh];
#pragma unroll
      for (int cc = 0; cc < 4; ++cc) o[cc] += hid[cq * 4 + cc][k] * w;
    }
#pragma unroll
    for (int cc = 0; cc < 4; ++cc) {
      int c = cq * 4 + cc;
      if (s0 + c < nc) {
        float d = o[cc] - c1[hh];
        D1[(s0 + c) * 64 + hh] = d;
        atomicAdd(&A[(cl[c] >> 9) * 64 + hh], d);
      }
    }
  }
  __syncthreads();
#pragma unroll
  for (int c = 0; c < 8; ++c) hid[c][t] = silu_f(a2[c]);
  __syncthreads();
  {
    int hh = t & 63, cq = t >> 6;
    float o[4];
#pragma unroll
    for (int cc = 0; cc < 4; ++cc) o[cc] = b22[hh];
    for (int k = 0; k < 128; ++k) {
      float w = w22[k * 64 + hh];
#pragma unroll
      for (int cc = 0; cc < 4; ++cc) o[cc] += hid[cq * 4 + cc][k] * w;
    }
#pragma unroll
    for (int cc = 0; cc < 4; ++cc) {
      int c = cq * 4 + cc;
      if (s0 + c < nc) {
        float d = o[cc] - c2[hh];
        D2[(s0 + c) * 64 + hh] = d;
        atomicAdd(&B[(cl[c] & 511) * 64 + hh], d);
      }
    }
  }
}

// ---------------- K10: u[i] = b1 + (512 c1c2 + c2*A[i])@w1m ; v[j] = (c1*B[j])@w1m
__global__ __launch_bounds__(128) void k_uv(
    const float* __restrict__ A, const float* __restrict__ B,
    const float* __restrict__ c1, const float* __restrict__ c2,
    const float* __restrict__ p3w1, const float* __restrict__ p3b1,
    float* __restrict__ u, float* __restrict__ v) {
  __shared__ float vec[64];
  int i = blockIdx.x, y = blockIdx.y, t = threadIdx.x;
  if (t < 64)
    vec[t] = (y == 0) ? (512.0f * c1[t] * c2[t] + c2[t] * A[i * 64 + t])
                      : (c1[t] * B[i * 64 + t]);
  __syncthreads();
  float a = (y == 0) ? p3b1[t] : 0.f;
  for (int f = 0; f < 64; ++f) a += vec[f] * p3w1[(96 + f) * 128 + t];
  (y == 0 ? u : v)[i * 128 + t] = a;
}

// ---------------- K11: S row accumulation, k-step, NO ATOMICS ----------------
// Block = (row i, feature-half). 512 thr: f = t&31, j-slot group = t>>5 (16).
// For each cell (i,k) of row i (serial steps): cells (k,j) have DISTINCT j, so
// each (j,f) LDS slot is owned by exactly one lane -> plain read-modify-write.
// __syncthreads between steps orders cross-step collisions. bf16 writeback.
__global__ __launch_bounds__(512) void k_pairs_steps(
    const int* __restrict__ cntA, const int* __restrict__ offA,
    const int* __restrict__ listAJ,
    const float* __restrict__ D1, const float* __restrict__ D2,
    __hip_bfloat16* __restrict__ S) {
  __shared__ float Srow[512 * 32];   // 64 KB -> 2 blocks/CU
  int i = blockIdx.x, half = blockIdx.y;
  int t = threadIdx.x;
  int f = t & 31, g = t >> 5;        // 16 j-groups
  for (int e = t; e < 16384; e += 512) Srow[e] = 0.f;
  __syncthreads();
  int n1 = cntA[i], o1 = offA[i];
  int fofs = half * 32 + f;
  for (int p1 = 0; p1 < n1; ++p1) {
    int e1 = listAJ[o1 + p1];
    int s1 = e1 & 0x3FFFF;
    int k = e1 >> 18;
    float d1 = D1[s1 * 64 + fofs];
    int n2 = cntA[k], o2 = offA[k];
    for (int jj = g; jj < n2; jj += 16) {
      int e2 = listAJ[o2 + jj];
      float d2 = D2[(e2 & 0x3FFFF) * 64 + fofs];
      int j = e2 >> 18;
      Srow[j * 32 + f] += d1 * d2;   // unique (j,f) per lane within this step
    }
    __syncthreads();
  }
  for (int e = t; e < 16384; e += 512) {
    int j = e >> 5, ff = e & 31;
    S[(i * 512 + j) * 64 + half * 32 + ff] = __float2bfloat16(Srow[e]);
  }
}

// ------- K12: fused z = u[i]+v[j]+S@w1m+TW, silu, row/col/diag reduce --------
__global__ __launch_bounds__(256) void k_tout_fused(
    const __hip_bfloat16* __restrict__ S, const float* __restrict__ u, const float* __restrict__ v,
    const float* __restrict__ TWc, const int* __restrict__ slotmap,
    const float* __restrict__ p3w1,
    float* __restrict__ row_part, float* __restrict__ col_part,
    float* __restrict__ diag_silu) {
  __shared__ float Ss[64 * 65];
  __shared__ float Wm[64 * 128];
  __shared__ float uvs[2048];
  __shared__ int slotL[64];
  int t = threadIdx.x;
  int cg = t & 7, hg = t >> 3;
  int bi = blockIdx.x >> 6, bj = blockIdx.x & 63;
  int i0 = bi * 8, j0 = bj * 8;
  for (int e = t; e < 4096; e += 256) {
    int cl = e >> 6, f = e & 63;
    Ss[cl * 65 + f] =
        __bfloat162float(S[((i0 + (cl >> 3)) * 512 + j0 + (cl & 7)) * 64 + f]);
  }
  for (int e = t; e < 8192; e += 256) Wm[e] = p3w1[96 * 128 + e];
  for (int e = t; e < 1024; e += 256) uvs[e] = u[(i0 + (e >> 7)) * 128 + (e & 127)];
  for (int e = t; e < 1024; e += 256) uvs[1024 + e] = v[(j0 + (e >> 7)) * 128 + (e & 127)];
  if (t < 64) slotL[t] = slotmap[(i0 + (t >> 3)) * 512 + j0 + (t & 7)];
  __syncthreads();
  float4 acc[8];
#pragma unroll
  for (int cj = 0; cj < 8; ++cj) acc[cj] = make_float4(0.f, 0.f, 0.f, 0.f);
  for (int kk = 0; kk < 64; ++kk) {
    float4 wv = *(const float4*)&Wm[kk * 128 + hg * 4];
#pragma unroll
    for (int cj = 0; cj < 8; ++cj) {
      float xv = Ss[(cg * 8 + cj) * 65 + kk];
      acc[cj].x += xv * wv.x; acc[cj].y += xv * wv.y;
      acc[cj].z += xv * wv.z; acc[cj].w += xv * wv.w;
    }
  }
  float4 uu = *(const float4*)&uvs[cg * 128 + hg * 4];
#pragma unroll
  for (int cj = 0; cj < 8; ++cj) {
    float4 vv = *(const float4*)&uvs[1024 + cj * 128 + hg * 4];
    float4 z = make_float4(acc[cj].x + uu.x + vv.x, acc[cj].y + uu.y + vv.y,
                           acc[cj].z + uu.z + vv.z, acc[cj].w + uu.w + vv.w);
    int s = slotL[cg * 8 + cj];
    if (s >= 0) {
      float4 tw = *(const float4*)&TWc[s * 128 + hg * 4];
      z.x += tw.x; z.y += tw.y; z.z += tw.z; z.w += tw.w;
    }
    acc[cj] = make_float4(silu_f(z.x), silu_f(z.y), silu_f(z.z), silu_f(z.w));
  }
  float4 rs = make_float4(0.f, 0.f, 0.f, 0.f);
#pragma unroll
  for (int cj = 0; cj < 8; ++cj) {
    rs.x += acc[cj].x; rs.y += acc[cj].y; rs.z += acc[cj].z; rs.w += acc[cj].w;
  }
  *(float4*)&row_part[(bj * 512 + i0 + cg) * 128 + hg * 4] = rs;
#pragma unroll
  for (int cj = 0; cj < 8; ++cj) {
    float4 cs = acc[cj];
#pragma unroll
    for (int msk = 1; msk < 8; msk <<= 1) {
      cs.x += __shfl_xor(cs.x, msk); cs.y += __shfl_xor(cs.y, msk);
      cs.z += __shfl_xor(cs.z, msk); cs.w += __shfl_xor(cs.w, msk);
    }
    if (cg == 0)
      *(float4*)&col_part[(bi * 512 + j0 + cj) * 128 + hg * 4] = cs;
  }
  if (bi == bj) {
#pragma unroll
    for (int cj = 0; cj < 8; ++cj)
      if (cj == cg)
        *(float4*)&diag_silu[(i0 + cg) * 128 + hg * 4] = acc[cj];
  }
}

// ---------------- K13: reduce 64 partial slices ------------------------------
__global__ __launch_bounds__(256) void k_sumparts(
    const float* __restrict__ row_part, const float* __restrict__ col_part,
    float* __restrict__ rowsum, float* __restrict__ colsum) {
  int i = blockIdx.x, t = threadIdx.x;
  const float* src = (t < 128) ? row_part : col_part;
  float* dst = (t < 128) ? rowsum : colsum;
  int hc = t & 127;
  float a = 0.f;
  for (int p = 0; p < 64; ++p) a += src[(p * 512 + i) * 128 + hc];
  dst[i * 128 + hc] = a;
}

// ---------------- K14: second layer of p3 MLP on reduced silu sums -----------
__global__ __launch_bounds__(64) void k_tout2(
    const float* __restrict__ diag_silu, const float* __restrict__ rowsum_silu,
    const float* __restrict__ colsum_silu,
    const float* __restrict__ w2, const float* __restrict__ b2,
    float* __restrict__ diag_T, float* __restrict__ row_T, float* __restrict__ col_T) {
  __shared__ float in[128];
  int e = blockIdx.x, which = blockIdx.y, t = threadIdx.x;
  const float* src = (which == 0) ? diag_silu : (which == 1) ? rowsum_silu : colsum_silu;
  in[t] = src[e * 128 + t]; in[64 + t] = src[e * 128 + 64 + t];
  __syncthreads();
  float a = 0.f;
  for (int k = 0; k < 128; ++k) a += in[k] * w2[k * 64 + t];
  float bias = b2[t] * ((which == 0) ? 1.0f : 512.0f);
  float* dst = (which == 0) ? diag_T : (which == 1) ? row_T : col_T;
  dst[e * 64 + t] = a + bias;
}

// ---------------- K15: tot / tr ----------------------------------------------
__global__ __launch_bounds__(128) void k_totr(
    const float* __restrict__ row_T, const float* __restrict__ diag_T,
    float* __restrict__ tot, float* __restrict__ tr) {
  int t = threadIdx.x;
  const float* src = (t < 64) ? row_T : diag_T;
  int f = t & 63;
  float a = 0.f;
  for (int e = 0; e < 512; ++e) a += src[e * 64 + f];
  if (t < 64) tot[f] = a; else tr[f] = a;
}

// ---------------- K16: nb_t1 = [diag|row|col|tot|tr] @ ign_w + ign_b ---------
__global__ __launch_bounds__(64) void k_nbt1(
    const float* __restrict__ diag_T, const float* __restrict__ row_T,
    const float* __restrict__ col_T, const float* __restrict__ tot,
    const float* __restrict__ tr,
    const float* __restrict__ gw, const float* __restrict__ gb,
    float* __restrict__ nb_t1) {
  __shared__ float in[320];
  int e = blockIdx.x, t = threadIdx.x;
  in[t] = diag_T[e * 64 + t]; in[64 + t] = row_T[e * 64 + t];
  in[128 + t] = col_T[e * 64 + t]; in[192 + t] = tot[t]; in[256 + t] = tr[t];
  __syncthreads();
  float a = gb[t];
  for (int k = 0; k < 320; ++k) a += in[k] * gw[k * 64 + t];
  nb_t1[e * 64 + t] = a;
}

// ----- K17: coord weight w_e, seg/cnt/nb_t0 scatters, edge_attr passthrough --
__global__ __launch_bounds__(128) void k_edge_out(
    const int* __restrict__ edges, const float* __restrict__ coord_diff,
    const float* __restrict__ nb_t1, const float* __restrict__ edge_attr,
    const float* __restrict__ cw1, const float* __restrict__ cb1,
    const float* __restrict__ cw2,
    float* __restrict__ seg, float* __restrict__ cnt, float* __restrict__ nb_t0,
    float* __restrict__ out_ea) {
  __shared__ float in[64];
  __shared__ float red[128];
  int e = blockIdx.x, t = threadIdx.x;
  if (t < 64) in[t] = nb_t1[e * 64 + t];
  __syncthreads();
  float a = cb1[t];
  for (int k = 0; k < 64; ++k) a += in[k] * cw1[k * 128 + t];
  red[t] = silu_f(a) * cw2[t];
  __syncthreads();
  for (int s2 = 64; s2 > 0; s2 >>= 1) {
    if (t < s2) red[t] += red[t + s2];
    __syncthreads();
  }
  float w = red[0];
  int r = edges[e];
  if (t < 3) atomicAdd(&seg[r * 3 + t], coord_diff[e * 3 + t] * w);
  if (t == 64) atomicAdd(&cnt[r], 1.0f);
  if (t < 64) atomicAdd(&nb_t0[r * 64 + t], in[t]);
  if (t < 4) out_ea[e * 4 + t] = edge_attr[e * 4 + t];
}

// ---------------- K18: x_new and h_new ---------------------------------------
__global__ __launch_bounds__(128) void k_node_out(
    const float* __restrict__ h, const float* __restrict__ x,
    const float* __restrict__ seg, const float* __restrict__ cnt,
    const float* __restrict__ nb_t0,
    const float* __restrict__ w1, const float* __restrict__ b1,
    const float* __restrict__ w2, const float* __restrict__ b2,
    float* __restrict__ out_h, float* __restrict__ out_x) {
  __shared__ float in[64];
  __shared__ float hs[128];
  int n = blockIdx.x, t = threadIdx.x;
  if (t < 3) {
    float c = cnt[n]; if (c < 1.f) c = 1.f;
    out_x[n * 3 + t] = x[n * 3 + t] + seg[n * 3 + t] / c;
  }
  if (t < 64) in[t] = nb_t0[n * 64 + t];
  __syncthreads();
  float a = b1[t];
  for (int k = 0; k < 64; ++k) a += in[k] * w1[k * 128 + t];
  hs[t] = silu_f(a);
  __syncthreads();
  if (t < 64) {
    float o = b2[t];
    for (int k = 0; k < 128; ++k) o += hs[k] * w2[k * 64 + t];
    out_h[n * 64 + t] = h[n * 64 + t] + o;
  }
}

extern "C" void kernel_launch(void* const* d_in, const int* in_sizes, int n_in,
                              void* d_out, int out_size, void* d_ws, size_t ws_size,
                              hipStream_t stream) {
  (void)in_sizes; (void)n_in; (void)out_size; (void)ws_size;
  const float* h  = (const float*)d_in[0];
  const float* x  = (const float*)d_in[1];
  const int* edges   = (const int*)d_in[2];
  const int* nb_edge = (const int*)d_in[3];
  const float* edge_attr = (const float*)d_in[4];
  const float* ew1 = (const float*)d_in[6],  *eb1 = (const float*)d_in[7];
  const float* ew2 = (const float*)d_in[8],  *eb2 = (const float*)d_in[9];
  const float* p1w1 = (const float*)d_in[10], *p1b1 = (const float*)d_in[11];
  const float* p1w2 = (const float*)d_in[12], *p1b2 = (const float*)d_in[13];
  const float* p2w1 = (const float*)d_in[14], *p2b1 = (const float*)d_in[15];
  const float* p2w2 = (const float*)d_in[16], *p2b2 = (const float*)d_in[17];
  const float* p3w1 = (const float*)d_in[18], *p3b1 = (const float*)d_in[19];
  const float* p3w2 = (const float*)d_in[20], *p3b2 = (const float*)d_in[21];
  const float* ignw = (const float*)d_in[22], *ignb = (const float*)d_in[23];
  const float* cw1 = (const float*)d_in[24], *cb1 = (const float*)d_in[25];
  const float* cw2 = (const float*)d_in[26];
  const float* ndw1 = (const float*)d_in[27], *ndb1 = (const float*)d_in[28];
  const float* ndw2 = (const float*)d_in[29], *ndb2 = (const float*)d_in[30];

  // ---- workspace layout (~94 MB) ----
  char* ws = (char*)d_ws;
  __hip_bfloat16* S = (__hip_bfloat16*)(ws + 0);   // [262144][64] bf16 = 33,554,432 B
  float* row_part = (float*)(ws + 33554432);       // [64][512][128] = 16,777,216 B
  float* col_part = (float*)(ws + 50331648);       // 16,777,216 B
  // ---- single zero-memset block [67,108,864 .. 73,803,792) ----
  float* Tc    = (float*)(ws + 67108864);          // [16384][96] = 6,291,456 B
  int*   cntA  = (int*)(ws + 73400320);            // 512 ints
  int*   nC    = (int*)(ws + 73402368);            // 1 int (+pad)
  float* A     = (float*)(ws + 73402384);          // 32768 floats
  float* B     = (float*)(ws + 73533456);          // 32768 floats
  float* seg   = (float*)(ws + 73664528);          // 1536 floats
  float* cnt   = (float*)(ws + 73670672);          // 512 floats
  float* nb_t0 = (float*)(ws + 73672720);          // 32768 floats -> end 73,803,792
  // ---- rest ----
  int*   slotmap = (int*)(ws + 73803792);          // 262144 ints (memset 0xFF)
  int*   cells   = (int*)(ws + 74852368);          // 16384 ints
  int*   offA    = (int*)(ws + 74917904);          // 512 ints
  int*   curA    = (int*)(ws + 74919952);          // 512 ints
  int*   listAJ  = (int*)(ws + 74922000);          // 16384 ints
  float* D1      = (float*)(ws + 74987536);        // [16384][64]
  float* D2      = (float*)(ws + 79181840);        // [16384][64]
  float* TWc     = (float*)(ws + 83376144);        // [16384][128]
  float* c1      = (float*)(ws + 91764752);        // 64
  float* c2      = (float*)(ws + 91765008);        // 64
  float* u       = (float*)(ws + 91765264);        // [512][128]
  float* v       = (float*)(ws + 92027408);        // [512][128]
  float* coord_diff  = (float*)(ws + 92289552);    // [512][3]
  float* efn         = (float*)(ws + 92295696);    // [512][64]
  float* diag_silu   = (float*)(ws + 92426768);    // [512][128]
  float* rowsum_silu = (float*)(ws + 92688912);
  float* colsum_silu = (float*)(ws + 92951056);
  float* diag_T      = (float*)(ws + 93213200);    // [512][64]
  float* row_T       = (float*)(ws + 93344272);
  float* col_T       = (float*)(ws + 93475344);
  float* tot         = (float*)(ws + 93606416);    // 64
  float* tr          = (float*)(ws + 93606672);    // 64
  float* nb_t1       = (float*)(ws + 93606928);    // [512][64]

  float* out_h  = (float*)d_out;
  float* out_x  = out_h + 512 * 64;
  float* out_ea = out_x + 512 * 3;

  hipMemsetAsync(slotmap, 0xFF, 1048576, stream);          // -1
  hipMemsetAsync(ws + 67108864, 0, 6694928, stream);       // Tc..nb_t0

  k_edge<<<512, 128, 0, stream>>>(h, x, edges, ew1, eb1, ew2, eb2, coord_diff, efn);
  k_consts<<<1, 128, 0, stream>>>(p1b1, p1w2, p1b2, p2b1, p2w2, p2b2, c1, c2);
  k_mark<<<64, 256, 0, stream>>>(nb_edge, slotmap);
  k_compact<<<1024, 256, 0, stream>>>(slotmap, cells, nC, cntA);
  k_scan<<<1, 512, 0, stream>>>(cntA, offA, curA);
  k_fill<<<64, 256, 0, stream>>>(cells, nC, curA, listAJ);
  k_scatterT<<<8192, 192, 0, stream>>>(nb_edge, slotmap, coord_diff, efn, Tc);
  k_mlp96b<<<2048, 128, 0, stream>>>(cells, nC, Tc,
                                     p1w1, p1b1, p1w2, p1b2,
                                     p2w1, p2b1, p2w2, p2b2,
                                     c1, c2, p3w1, D1, D2, A, B, TWc);
  k_uv<<<dim3(512, 2), 128, 0, stream>>>(A, B, c1, c2, p3w1, p3b1, u, v);
  k_pairs_steps<<<dim3(512, 2), 512, 0, stream>>>(cntA, offA, listAJ, D1, D2, S);
  k_tout_fused<<<4096, 256, 0, stream>>>(S, u, v, TWc, slotmap, p3w1,
                                         row_part, col_part, diag_silu);
  k_sumparts<<<512, 256, 0, stream>>>(row_part, col_part, rowsum_silu, colsum_silu);
  k_tout2<<<dim3(512, 3), 64, 0, stream>>>(diag_silu, rowsum_silu, colsum_silu,
                                           p3w2, p3b2, diag_T, row_T, col_T);
  k_totr<<<1, 128, 0, stream>>>(row_T, diag_T, tot, tr);
  k_nbt1<<<512, 64, 0, stream>>>(diag_T, row_T, col_T, tot, tr, ignw, ignb, nb_t1);
  k_edge_out<<<512, 128, 0, stream>>>(edges, coord_diff, nb_t1, edge_attr,
                                      cw1, cb1, cw2, seg, cnt, nb_t0, out_ea);
  k_node_out<<<512, 128, 0, stream>>>(h, x, seg, cnt, nb_t0,
                                      ndw1, ndb1, ndw2, ndb2, out_h, out_x);
}

// Round 6
// 460.294 us; speedup vs baseline: 9.4474x; 1.1294x over previous
//
#include <hip/hip_runtime.h>
#include <hip/hip_bf16.h>

// Problem constants (static per reference)
#define NN   512    // nodes
#define EE   512    // edges == nb-graph nodes (En)
#define MM   16384  // nb-graph edges

typedef float v4f __attribute__((ext_vector_type(4)));
typedef short short8v __attribute__((ext_vector_type(8)));

__device__ __forceinline__ float silu_f(float v) { return v / (1.0f + __expf(-v)); }

// ---------------- K1: per original edge: coord_diff + efn = MLP([h_r|h_c]) ----
__global__ __launch_bounds__(128) void k_edge(
    const float* __restrict__ h, const float* __restrict__ x,
    const int* __restrict__ edges,
    const float* __restrict__ ew1, const float* __restrict__ eb1,
    const float* __restrict__ ew2, const float* __restrict__ eb2,
    float* __restrict__ coord_diff, float* __restrict__ efn) {
  __shared__ float hin[128];
  __shared__ float hs[128];
  int e = blockIdx.x;
  int t = threadIdx.x;
  int r = edges[e], c = edges[EE + e];
  if (t < 3) coord_diff[e * 3 + t] = x[r * 3 + t] - x[c * 3 + t];
  if (t < 64) { hin[t] = h[r * 64 + t]; hin[64 + t] = h[c * 64 + t]; }
  __syncthreads();
  float acc = eb1[t];
  for (int k = 0; k < 128; ++k) acc += hin[k] * ew1[k * 128 + t];
  hs[t] = silu_f(acc);
  __syncthreads();
  if (t < 64) {
    float o = eb2[t];
    for (int k = 0; k < 128; ++k) o += hs[k] * ew2[k * 64 + t];
    efn[e * 64 + t] = o;
  }
}

// ---------------- K2: constants c1 = MLP1(0), c2 = MLP2(0) -------------------
__global__ __launch_bounds__(128) void k_consts(
    const float* __restrict__ p1b1, const float* __restrict__ p1w2, const float* __restrict__ p1b2,
    const float* __restrict__ p2b1, const float* __restrict__ p2w2, const float* __restrict__ p2b2,
    float* __restrict__ c1, float* __restrict__ c2) {
  __shared__ float h1[128], h2[128];
  int t = threadIdx.x;
  h1[t] = silu_f(p1b1[t]); h2[t] = silu_f(p2b1[t]);
  __syncthreads();
  if (t < 64) {
    float a1 = p1b2[t], a2 = p2b2[t];
    for (int k = 0; k < 128; ++k) { a1 += h1[k] * p1w2[k * 64 + t]; a2 += h2[k] * p2w2[k * 64 + t]; }
    c1[t] = a1; c2[t] = a2;
  }
}

// ---------------- K2b: Wt[h][f] = bf16(p3w1[96+f][h]) (B-operand for MFMA) ---
__global__ __launch_bounds__(256) void k_prep(const float* __restrict__ p3w1,
                                              __hip_bfloat16* __restrict__ Wt) {
  int e = blockIdx.x * 256 + threadIdx.x;   // 8192 = 128 h x 64 f
  int hh = e >> 6, f = e & 63;
  Wt[hh * 64 + f] = __float2bfloat16(p3w1[(96 + f) * 128 + hh]);
}

// ---------------- K3: mark touched cells -------------------------------------
__global__ __launch_bounds__(256) void k_mark(const int* __restrict__ nb_edge,
                                              int* __restrict__ slotmap) {
  int m = blockIdx.x * 256 + threadIdx.x;
  if (m >= MM) return;
  int cell = nb_edge[m] * 512 + nb_edge[MM + m];
  atomicCAS(&slotmap[cell], -1, -2);
}

// ---------------- K4: compact marked cells -> slots, degree histogram --------
__global__ __launch_bounds__(256) void k_compact(int* __restrict__ slotmap,
                                                 int* __restrict__ cells,
                                                 int* __restrict__ nC,
                                                 int* __restrict__ cntA) {
  int cell = blockIdx.x * 256 + threadIdx.x;
  if (slotmap[cell] != -2) return;
  int s = atomicAdd(nC, 1);
  slotmap[cell] = s;
  cells[s] = cell;
  atomicAdd(&cntA[cell >> 9], 1);   // group by first coord a
}

// ---------------- K5: prefix sum for the CSR ---------------------------------
__global__ __launch_bounds__(512) void k_scan(const int* __restrict__ cntA,
                                              int* __restrict__ offA,
                                              int* __restrict__ curA) {
  __shared__ int sA[512];
  int t = threadIdx.x;
  int a0 = cntA[t];
  sA[t] = a0;
  for (int off = 1; off < 512; off <<= 1) {
    __syncthreads();
    int a = (t >= off) ? sA[t - off] : 0;
    __syncthreads();
    sA[t] += a;
  }
  __syncthreads();
  offA[t] = sA[t] - a0;
  curA[t] = sA[t] - a0;
}

// -------- K6: fill CSR list, packing slot | (second-coord << 18) -------------
__global__ __launch_bounds__(256) void k_fill(const int* __restrict__ cells, const int* __restrict__ nC,
                                              int* __restrict__ curA,
                                              int* __restrict__ listAJ) {
  int s = blockIdx.x * 256 + threadIdx.x;
  if (s >= *nC) return;
  int cell = cells[s];
  listAJ[atomicAdd(&curA[cell >> 9], 1)] = s | ((cell & 511) << 18);
}

// ---------------- K7: nb_feat scatter-add into COMPACT Tc (2 edges/block) ----
__global__ __launch_bounds__(192) void k_scatterT(
    const int* __restrict__ nb_edge, const int* __restrict__ slotmap,
    const float* __restrict__ coord_diff, const float* __restrict__ efn,
    float* __restrict__ Tc) {
  int t = threadIdx.x;
  int sub = (t >= 96) ? 1 : 0;
  int c = t - sub * 96;
  int m = blockIdx.x * 2 + sub;
  int a = nb_edge[m], b = nb_edge[MM + m];
  int s = slotmap[a * 512 + b];
  float val;
  if (c < 32) {
    float vtv = coord_diff[a * 3 + 0] * coord_diff[b * 3 + 0]
              + coord_diff[a * 3 + 1] * coord_diff[b * 3 + 1]
              + coord_diff[a * 3 + 2] * coord_diff[b * 3 + 2];
    int i = c >> 1;
    float ang = vtv * 16.0f * __expf(-0.57564627324851143f * (float)i);
    val = (c & 1) ? cosf(ang) : sinf(ang);
  } else {
    int f = c - 32;
    val = efn[a * 64 + f] * efn[b * 64 + f];
  }
  atomicAdd(&Tc[s * 96 + c], val);
}

// ------- K8: batched (8 cells/block) MLPs -> D1/D2, sums A,B; TWc = Tc@w1T ---
__global__ __launch_bounds__(128) void k_mlp96b(
    const int* __restrict__ cells, const int* __restrict__ nC, const float* __restrict__ Tc,
    const float* __restrict__ w11, const float* __restrict__ b11,
    const float* __restrict__ w12, const float* __restrict__ b12,
    const float* __restrict__ w21, const float* __restrict__ b21,
    const float* __restrict__ w22, const float* __restrict__ b22,
    const float* __restrict__ c1, const float* __restrict__ c2,
    const float* __restrict__ p3w1,
    float* __restrict__ D1, float* __restrict__ D2,
    float* __restrict__ A, float* __restrict__ B,
    float* __restrict__ TWc) {
  __shared__ float xsT[96 * 8];    // [k][cell] transposed for b128 reads
  __shared__ float hid[8][128];
  __shared__ int cl[8];
  int t = threadIdx.x;
  int nc = *nC;
  int s0 = blockIdx.x * 8;
  if (s0 >= nc) return;
  for (int e = t; e < 768; e += 128) xsT[(e % 96) * 8 + e / 96] = Tc[s0 * 96 + e];
  if (t < 8) cl[t] = (s0 + t < nc) ? cells[s0 + t] : 0;
  __syncthreads();
  float tw[8], a1[8], a2[8];
#pragma unroll
  for (int c = 0; c < 8; ++c) { tw[c] = 0.f; a1[c] = b11[t]; a2[c] = b21[t]; }
  for (int k = 0; k < 96; ++k) {
    float wt = p3w1[k * 128 + t];
    float w1v = w11[k * 128 + t];
    float w2v = w21[k * 128 + t];
    float4 xlo = *(const float4*)&xsT[k * 8];
    float4 xhi = *(const float4*)&xsT[k * 8 + 4];
    float xv[8] = {xlo.x, xlo.y, xlo.z, xlo.w, xhi.x, xhi.y, xhi.z, xhi.w};
#pragma unroll
    for (int c = 0; c < 8; ++c) {
      tw[c] += xv[c] * wt; a1[c] += xv[c] * w1v; a2[c] += xv[c] * w2v;
    }
  }
#pragma unroll
  for (int c = 0; c < 8; ++c) {
    if (s0 + c < nc) TWc[(s0 + c) * 128 + t] = tw[c];
    hid[c][t] = silu_f(a1[c]);
  }
  __syncthreads();
  {
    int hh = t & 63, cq = t >> 6;
    float o[4];
#pragma unroll
    for (int cc = 0; cc < 4; ++cc) o[cc] = b12[hh];
    for (int k = 0; k < 128; ++k) {
      float w = w12[k * 64 + hh];
#pragma unroll
      for (int cc = 0; cc < 4; ++cc) o[cc] += hid[cq * 4 + cc][k] * w;
    }
#pragma unroll
    for (int cc = 0; cc < 4; ++cc) {
      int c = cq * 4 + cc;
      if (s0 + c < nc) {
        float d = o[cc] - c1[hh];
        D1[(s0 + c) * 64 + hh] = d;
        atomicAdd(&A[(cl[c] >> 9) * 64 + hh], d);
      }
    }
  }
  __syncthreads();
#pragma unroll
  for (int c = 0; c < 8; ++c) hid[c][t] = silu_f(a2[c]);
  __syncthreads();
  {
    int hh = t & 63, cq = t >> 6;
    float o[4];
#pragma unroll
    for (int cc = 0; cc < 4; ++cc) o[cc] = b22[hh];
    for (int k = 0; k < 128; ++k) {
      float w = w22[k * 64 + hh];
#pragma unroll
      for (int cc = 0; cc < 4; ++cc) o[cc] += hid[cq * 4 + cc][k] * w;
    }
#pragma unroll
    for (int cc = 0; cc < 4; ++cc) {
      int c = cq * 4 + cc;
      if (s0 + c < nc) {
        float d = o[cc] - c2[hh];
        D2[(s0 + c) * 64 + hh] = d;
        atomicAdd(&B[(cl[c] & 511) * 64 + hh], d);
      }
    }
  }
}

// ---------------- K10: u[i] = b1 + (512 c1c2 + c2*A[i])@w1m ; v[j] = (c1*B[j])@w1m
__global__ __launch_bounds__(128) void k_uv(
    const float* __restrict__ A, const float* __restrict__ B,
    const float* __restrict__ c1, const float* __restrict__ c2,
    const float* __restrict__ p3w1, const float* __restrict__ p3b1,
    float* __restrict__ u, float* __restrict__ v) {
  __shared__ float vec[64];
  int i = blockIdx.x, y = blockIdx.y, t = threadIdx.x;
  if (t < 64)
    vec[t] = (y == 0) ? (512.0f * c1[t] * c2[t] + c2[t] * A[i * 64 + t])
                      : (c1[t] * B[i * 64 + t]);
  __syncthreads();
  float a = (y == 0) ? p3b1[t] : 0.f;
  for (int f = 0; f < 64; ++f) a += vec[f] * p3w1[(96 + f) * 128 + t];
  (y == 0 ? u : v)[i * 128 + t] = a;
}

// ---------------- K11: S row accumulation, k-step, feature-PAIR b64 ----------
// Block = (row i, half). 512 thr: p = t&15 owns features {2p,2p+1}; g = t>>4
// (32 j-groups). Within a step all touched (j, feature-pair) slots are unique
// -> plain b64 read-fma-write, no atomics. XOR swizzle (f + 2*(j&15))&31 keeps
// banks spread at 64 KB LDS. bf16 writeback.
__global__ __launch_bounds__(512) void k_pairs_steps(
    const int* __restrict__ cntA, const int* __restrict__ offA,
    const int* __restrict__ listAJ,
    const float* __restrict__ D1, const float* __restrict__ D2,
    __hip_bfloat16* __restrict__ S) {
  __shared__ float Srow[512 * 32];   // 64 KB
  int i = blockIdx.x, half = blockIdx.y;
  int t = threadIdx.x;
  int p = t & 15, g = t >> 4;
  for (int e = t; e < 16384; e += 512) Srow[e] = 0.f;
  __syncthreads();
  int n1 = cntA[i], o1 = offA[i];
  int fofs = half * 32 + p * 2;
  for (int p1 = 0; p1 < n1; ++p1) {
    int e1 = listAJ[o1 + p1];
    int s1 = e1 & 0x3FFFF;
    int k = e1 >> 18;
    float2 d1 = *(const float2*)&D1[s1 * 64 + fofs];
    int n2 = cntA[k], o2 = offA[k];
    for (int jj = g; jj < n2; jj += 32) {
      int e2 = listAJ[o2 + jj];
      float2 d2 = *(const float2*)&D2[(e2 & 0x3FFFF) * 64 + fofs];
      int j = e2 >> 18;
      float2* sp = (float2*)&Srow[j * 32 + ((p * 2 + 2 * (j & 15)) & 31)];
      float2 sv = *sp;
      sv.x += d1.x * d2.x; sv.y += d1.y * d2.y;
      *sp = sv;
    }
    __syncthreads();
  }
  for (int e = t; e < 16384; e += 512) {
    int j = e >> 5, f = e & 31;
    float val = Srow[j * 32 + ((f + 2 * (j & 15)) & 31)];
    S[(i * 512 + j) * 64 + half * 32 + f] = __float2bfloat16(val);
  }
}

// ------- K12: MFMA z = S@Wt + u[i]+v[j]+TW, silu, row/col/diag reduce --------
// Block = 8x8 cells (bi,bj); 4 waves; wave w owns cells w*16..w*16+15.
// A-frag: S rows (bf16, f contiguous). B-frag: Wt[h][f] bf16 staged in LDS.
// C layout: h = n0+(lane&15), cell = w*16 + quad*4 + reg  [m89-verified].
__global__ __launch_bounds__(256) void k_tout_mfma(
    const __hip_bfloat16* __restrict__ S, const float* __restrict__ u,
    const float* __restrict__ v, const float* __restrict__ TWc,
    const int* __restrict__ slotmap, const __hip_bfloat16* __restrict__ Wt,
    float* __restrict__ row_part, float* __restrict__ col_part,
    float* __restrict__ diag_silu) {
  __shared__ __hip_bfloat16 WtL[128 * 72];   // 18,432 B (pad 72 -> 2-way banks)
  __shared__ float uvL[2048];                // u rows | v rows, 8 KB
  __shared__ float colbuf[4][8][128];        // 16 KB
  __shared__ int slotL[64];
  int t = threadIdx.x;
  int w = t >> 6, lane = t & 63;
  int q = lane >> 4, l15 = lane & 15;
  int bi = blockIdx.x >> 6, bj = blockIdx.x & 63;
  int i0 = bi * 8, j0 = bj * 8;
  for (int e = t; e < 4096; e += 256) {      // Wt as uint pairs -> padded LDS
    int row = e >> 5, c2 = e & 31;
    ((unsigned*)WtL)[row * 36 + c2] = ((const unsigned*)Wt)[row * 32 + c2];
  }
  for (int e = t; e < 1024; e += 256) uvL[e] = u[(i0 + (e >> 7)) * 128 + (e & 127)];
  for (int e = t; e < 1024; e += 256) uvL[1024 + e] = v[(j0 + (e >> 7)) * 128 + (e & 127)];
  if (t < 64) slotL[t] = slotmap[(i0 + (t >> 3)) * 512 + j0 + (t & 7)];
  // A-frags (global, 16B each): cell by lane&15, k = quad*8..+7 (+32 for step 2)
  int cellA = w * 16 + l15;
  const short8v* sp = (const short8v*)&S[((i0 + (cellA >> 3)) * 512 + j0 + (cellA & 7)) * 64];
  short8v a0 = sp[q];
  short8v a1 = sp[4 + q];
  __syncthreads();
  v4f acc[8];
#pragma unroll
  for (int nt = 0; nt < 8; ++nt) {
    const short8v* b0 = (const short8v*)&WtL[(nt * 16 + l15) * 72 + q * 8];
    const short8v* b1 = (const short8v*)&WtL[(nt * 16 + l15) * 72 + 32 + q * 8];
    v4f c = {0.f, 0.f, 0.f, 0.f};
    c = __builtin_amdgcn_mfma_f32_16x16x32_bf16(a0, *b0, c, 0, 0, 0);
    c = __builtin_amdgcn_mfma_f32_16x16x32_bf16(a1, *b1, c, 0, 0, 0);
    acc[nt] = c;
  }
  float colp[8][4];
#pragma unroll
  for (int nt = 0; nt < 8; ++nt) {
    int hh = nt * 16 + l15;
    float rsum = 0.f;
#pragma unroll
    for (int r = 0; r < 4; ++r) {
      int c = w * 16 + q * 4 + r;
      int iL = c >> 3, jL = c & 7;
      float z = acc[nt][r] + uvL[iL * 128 + hh] + uvL[1024 + jL * 128 + hh];
      int s = slotL[c];
      if (s >= 0) z += TWc[s * 128 + hh];
      float sv = silu_f(z);
      rsum += sv;
      colp[nt][r] = sv + __shfl_xor(sv, 32);      // sum over the wave's 2 iL
      if (bi == bj && iL == jL) diag_silu[(i0 + iL) * 128 + hh] = sv;
    }
    rsum += __shfl_xor(rsum, 16);                 // sum over all 8 jL
    if ((q & 1) == 0)
      row_part[(bj * 512 + i0 + 2 * w + (q >> 1)) * 128 + hh] = rsum;
  }
  // cross-wave col reduce: lanes q<2 hold jL = q*4+r partials
  if (q < 2) {
#pragma unroll
    for (int nt = 0; nt < 8; ++nt)
#pragma unroll
      for (int r = 0; r < 4; ++r)
        colbuf[w][q * 4 + r][nt * 16 + l15] = colp[nt][r];
  }
  __syncthreads();
  for (int e = t; e < 1024; e += 256) {
    int jL = e >> 7, hh = e & 127;
    float a = colbuf[0][jL][hh] + colbuf[1][jL][hh] + colbuf[2][jL][hh] + colbuf[3][jL][hh];
    col_part[(bi * 512 + j0 + jL) * 128 + hh] = a;
  }
}

// ---------------- K13: reduce 64 partial slices ------------------------------
__global__ __launch_bounds__(256) void k_sumparts(
    const float* __restrict__ row_part, const float* __restrict__ col_part,
    float* __restrict__ rowsum, float* __restrict__ colsum) {
  int i = blockIdx.x, t = threadIdx.x;
  const float* src = (t < 128) ? row_part : col_part;
  float* dst = (t < 128) ? rowsum : colsum;
  int hc = t & 127;
  float a = 0.f;
  for (int p = 0; p < 64; ++p) a += src[(p * 512 + i) * 128 + hc];
  dst[i * 128 + hc] = a;
}

// ---------------- K14: second layer of p3 MLP on reduced silu sums -----------
__global__ __launch_bounds__(64) void k_tout2(
    const float* __restrict__ diag_silu, const float* __restrict__ rowsum_silu,
    const float* __restrict__ colsum_silu,
    const float* __restrict__ w2, const float* __restrict__ b2,
    float* __restrict__ diag_T, float* __restrict__ row_T, float* __restrict__ col_T) {
  __shared__ float in[128];
  int e = blockIdx.x, which = blockIdx.y, t = threadIdx.x;
  const float* src = (which == 0) ? diag_silu : (which == 1) ? rowsum_silu : colsum_silu;
  in[t] = src[e * 128 + t]; in[64 + t] = src[e * 128 + 64 + t];
  __syncthreads();
  float a = 0.f;
  for (int k = 0; k < 128; ++k) a += in[k] * w2[k * 64 + t];
  float bias = b2[t] * ((which == 0) ? 1.0f : 512.0f);
  float* dst = (which == 0) ? diag_T : (which == 1) ? row_T : col_T;
  dst[e * 64 + t] = a + bias;
}

// ---------------- K15: tot / tr ----------------------------------------------
__global__ __launch_bounds__(128) void k_totr(
    const float* __restrict__ row_T, const float* __restrict__ diag_T,
    float* __restrict__ tot, float* __restrict__ tr) {
  int t = threadIdx.x;
  const float* src = (t < 64) ? row_T : diag_T;
  int f = t & 63;
  float a = 0.f;
  for (int e = 0; e < 512; ++e) a += src[e * 64 + f];
  if (t < 64) tot[f] = a; else tr[f] = a;
}

// ---------------- K16: nb_t1 = [diag|row|col|tot|tr] @ ign_w + ign_b ---------
__global__ __launch_bounds__(64) void k_nbt1(
    const float* __restrict__ diag_T, const float* __restrict__ row_T,
    const float* __restrict__ col_T, const float* __restrict__ tot,
    const float* __restrict__ tr,
    const float* __restrict__ gw, const float* __restrict__ gb,
    float* __restrict__ nb_t1) {
  __shared__ float in[320];
  int e = blockIdx.x, t = threadIdx.x;
  in[t] = diag_T[e * 64 + t]; in[64 + t] = row_T[e * 64 + t];
  in[128 + t] = col_T[e * 64 + t]; in[192 + t] = tot[t]; in[256 + t] = tr[t];
  __syncthreads();
  float a = gb[t];
  for (int k = 0; k < 320; ++k) a += in[k] * gw[k * 64 + t];
  nb_t1[e * 64 + t] = a;
}

// ----- K17: coord weight w_e, seg/cnt/nb_t0 scatters, edge_attr passthrough --
__global__ __launch_bounds__(128) void k_edge_out(
    const int* __restrict__ edges, const float* __restrict__ coord_diff,
    const float* __restrict__ nb_t1, const float* __restrict__ edge_attr,
    const float* __restrict__ cw1, const float* __restrict__ cb1,
    const float* __restrict__ cw2,
    float* __restrict__ seg, float* __restrict__ cnt, float* __restrict__ nb_t0,
    float* __restrict__ out_ea) {
  __shared__ float in[64];
  __shared__ float red[128];
  int e = blockIdx.x, t = threadIdx.x;
  if (t < 64) in[t] = nb_t1[e * 64 + t];
  __syncthreads();
  float a = cb1[t];
  for (int k = 0; k < 64; ++k) a += in[k] * cw1[k * 128 + t];
  red[t] = silu_f(a) * cw2[t];
  __syncthreads();
  for (int s2 = 64; s2 > 0; s2 >>= 1) {
    if (t < s2) red[t] += red[t + s2];
    __syncthreads();
  }
  float w = red[0];
  int r = edges[e];
  if (t < 3) atomicAdd(&seg[r * 3 + t], coord_diff[e * 3 + t] * w);
  if (t == 64) atomicAdd(&cnt[r], 1.0f);
  if (t < 64) atomicAdd(&nb_t0[r * 64 + t], in[t]);
  if (t < 4) out_ea[e * 4 + t] = edge_attr[e * 4 + t];
}

// ---------------- K18: x_new and h_new ---------------------------------------
__global__ __launch_bounds__(128) void k_node_out(
    const float* __restrict__ h, const float* __restrict__ x,
    const float* __restrict__ seg, const float* __restrict__ cnt,
    const float* __restrict__ nb_t0,
    const float* __restrict__ w1, const float* __restrict__ b1,
    const float* __restrict__ w2, const float* __restrict__ b2,
    float* __restrict__ out_h, float* __restrict__ out_x) {
  __shared__ float in[64];
  __shared__ float hs[128];
  int n = blockIdx.x, t = threadIdx.x;
  if (t < 3) {
    float c = cnt[n]; if (c < 1.f) c = 1.f;
    out_x[n * 3 + t] = x[n * 3 + t] + seg[n * 3 + t] / c;
  }
  if (t < 64) in[t] = nb_t0[n * 64 + t];
  __syncthreads();
  float a = b1[t];
  for (int k = 0; k < 64; ++k) a += in[k] * w1[k * 128 + t];
  hs[t] = silu_f(a);
  __syncthreads();
  if (t < 64) {
    float o = b2[t];
    for (int k = 0; k < 128; ++k) o += hs[k] * w2[k * 64 + t];
    out_h[n * 64 + t] = h[n * 64 + t] + o;
  }
}

extern "C" void kernel_launch(void* const* d_in, const int* in_sizes, int n_in,
                              void* d_out, int out_size, void* d_ws, size_t ws_size,
                              hipStream_t stream) {
  (void)in_sizes; (void)n_in; (void)out_size; (void)ws_size;
  const float* h  = (const float*)d_in[0];
  const float* x  = (const float*)d_in[1];
  const int* edges   = (const int*)d_in[2];
  const int* nb_edge = (const int*)d_in[3];
  const float* edge_attr = (const float*)d_in[4];
  const float* ew1 = (const float*)d_in[6],  *eb1 = (const float*)d_in[7];
  const float* ew2 = (const float*)d_in[8],  *eb2 = (const float*)d_in[9];
  const float* p1w1 = (const float*)d_in[10], *p1b1 = (const float*)d_in[11];
  const float* p1w2 = (const float*)d_in[12], *p1b2 = (const float*)d_in[13];
  const float* p2w1 = (const float*)d_in[14], *p2b1 = (const float*)d_in[15];
  const float* p2w2 = (const float*)d_in[16], *p2b2 = (const float*)d_in[17];
  const float* p3w1 = (const float*)d_in[18], *p3b1 = (const float*)d_in[19];
  const float* p3w2 = (const float*)d_in[20], *p3b2 = (const float*)d_in[21];
  const float* ignw = (const float*)d_in[22], *ignb = (const float*)d_in[23];
  const float* cw1 = (const float*)d_in[24], *cb1 = (const float*)d_in[25];
  const float* cw2 = (const float*)d_in[26];
  const float* ndw1 = (const float*)d_in[27], *ndb1 = (const float*)d_in[28];
  const float* ndw2 = (const float*)d_in[29], *ndb2 = (const float*)d_in[30];

  // ---- workspace layout (~94 MB) ----
  char* ws = (char*)d_ws;
  __hip_bfloat16* S = (__hip_bfloat16*)(ws + 0);   // [262144][64] bf16 = 33,554,432 B
  float* row_part = (float*)(ws + 33554432);       // [64][512][128] = 16,777,216 B
  float* col_part = (float*)(ws + 50331648);       // 16,777,216 B
  // ---- single zero-memset block [67,108,864 .. 73,803,792) ----
  float* Tc    = (float*)(ws + 67108864);          // [16384][96] = 6,291,456 B
  int*   cntA  = (int*)(ws + 73400320);            // 512 ints
  int*   nC    = (int*)(ws + 73402368);            // 1 int (+pad)
  float* A     = (float*)(ws + 73402384);          // 32768 floats
  float* B     = (float*)(ws + 73533456);          // 32768 floats
  float* seg   = (float*)(ws + 73664528);          // 1536 floats
  float* cnt   = (float*)(ws + 73670672);          // 512 floats
  float* nb_t0 = (float*)(ws + 73672720);          // 32768 floats -> end 73,803,792
  // ---- rest ----
  int*   slotmap = (int*)(ws + 73803792);          // 262144 ints (memset 0xFF)
  int*   cells   = (int*)(ws + 74852368);          // 16384 ints
  int*   offA    = (int*)(ws + 74917904);          // 512 ints
  int*   curA    = (int*)(ws + 74919952);          // 512 ints
  int*   listAJ  = (int*)(ws + 74922000);          // 16384 ints
  float* D1      = (float*)(ws + 74987536);        // [16384][64]
  float* D2      = (float*)(ws + 79181840);        // [16384][64]
  float* TWc     = (float*)(ws + 83376144);        // [16384][128]
  float* c1      = (float*)(ws + 91764752);        // 64
  float* c2      = (float*)(ws + 91765008);        // 64
  float* u       = (float*)(ws + 91765264);        // [512][128]
  float* v       = (float*)(ws + 92027408);        // [512][128]
  float* coord_diff  = (float*)(ws + 92289552);    // [512][3]
  float* efn         = (float*)(ws + 92295696);    // [512][64]
  float* diag_silu   = (float*)(ws + 92426768);    // [512][128]
  float* rowsum_silu = (float*)(ws + 92688912);
  float* colsum_silu = (float*)(ws + 92951056);
  float* diag_T      = (float*)(ws + 93213200);    // [512][64]
  float* row_T       = (float*)(ws + 93344272);
  float* col_T       = (float*)(ws + 93475344);
  float* tot         = (float*)(ws + 93606416);    // 64
  float* tr          = (float*)(ws + 93606672);    // 64
  float* nb_t1       = (float*)(ws + 93606928);    // [512][64] -> end 93,738,000
  __hip_bfloat16* Wt = (__hip_bfloat16*)(ws + 93738000);  // [128][64] bf16 = 16,384 B

  float* out_h  = (float*)d_out;
  float* out_x  = out_h + 512 * 64;
  float* out_ea = out_x + 512 * 3;

  hipMemsetAsync(slotmap, 0xFF, 1048576, stream);          // -1
  hipMemsetAsync(ws + 67108864, 0, 6694928, stream);       // Tc..nb_t0

  k_edge<<<512, 128, 0, stream>>>(h, x, edges, ew1, eb1, ew2, eb2, coord_diff, efn);
  k_consts<<<1, 128, 0, stream>>>(p1b1, p1w2, p1b2, p2b1, p2w2, p2b2, c1, c2);
  k_prep<<<32, 256, 0, stream>>>(p3w1, Wt);
  k_mark<<<64, 256, 0, stream>>>(nb_edge, slotmap);
  k_compact<<<1024, 256, 0, stream>>>(slotmap, cells, nC, cntA);
  k_scan<<<1, 512, 0, stream>>>(cntA, offA, curA);
  k_fill<<<64, 256, 0, stream>>>(cells, nC, curA, listAJ);
  k_scatterT<<<8192, 192, 0, stream>>>(nb_edge, slotmap, coord_diff, efn, Tc);
  k_mlp96b<<<2048, 128, 0, stream>>>(cells, nC, Tc,
                                     p1w1, p1b1, p1w2, p1b2,
                                     p2w1, p2b1, p2w2, p2b2,
                                     c1, c2, p3w1, D1, D2, A, B, TWc);
  k_uv<<<dim3(512, 2), 128, 0, stream>>>(A, B, c1, c2, p3w1, p3b1, u, v);
  k_pairs_steps<<<dim3(512, 2), 512, 0, stream>>>(cntA, offA, listAJ, D1, D2, S);
  k_tout_mfma<<<4096, 256, 0, stream>>>(S, u, v, TWc, slotmap, Wt,
                                        row_part, col_part, diag_silu);
  k_sumparts<<<512, 256, 0, stream>>>(row_part, col_part, rowsum_silu, colsum_silu);
  k_tout2<<<dim3(512, 3), 64, 0, stream>>>(diag_silu, rowsum_silu, colsum_silu,
                                           p3w2, p3b2, diag_T, row_T, col_T);
  k_totr<<<1, 128, 0, stream>>>(row_T, diag_T, tot, tr);
  k_nbt1<<<512, 64, 0, stream>>>(diag_T, row_T, col_T, tot, tr, ignw, ignb, nb_t1);
  k_edge_out<<<512, 128, 0, stream>>>(edges, coord_diff, nb_t1, edge_attr,
                                      cw1, cb1, cw2, seg, cnt, nb_t0, out_ea);
  k_node_out<<<512, 128, 0, stream>>>(h, x, seg, cnt, nb_t0,
                                      ndw1, ndb1, ndw2, ndb2, out_h, out_x);
}

// Round 7
// 459.081 us; speedup vs baseline: 9.4723x; 1.0026x over previous
//
#include <hip/hip_runtime.h>
#include <hip/hip_bf16.h>

// Problem constants (static per reference)
#define NN   512    // nodes
#define EE   512    // edges == nb-graph nodes (En)
#define MM   16384  // nb-graph edges

typedef float v4f __attribute__((ext_vector_type(4)));
typedef short short8v __attribute__((ext_vector_type(8)));

__device__ __forceinline__ float silu_f(float v) { return v / (1.0f + __expf(-v)); }

// ---------------- K1: per original edge: coord_diff + efn = MLP([h_r|h_c]) ----
__global__ __launch_bounds__(128) void k_edge(
    const float* __restrict__ h, const float* __restrict__ x,
    const int* __restrict__ edges,
    const float* __restrict__ ew1, const float* __restrict__ eb1,
    const float* __restrict__ ew2, const float* __restrict__ eb2,
    float* __restrict__ coord_diff, float* __restrict__ efn) {
  __shared__ float hin[128];
  __shared__ float hs[128];
  int e = blockIdx.x;
  int t = threadIdx.x;
  int r = edges[e], c = edges[EE + e];
  if (t < 3) coord_diff[e * 3 + t] = x[r * 3 + t] - x[c * 3 + t];
  if (t < 64) { hin[t] = h[r * 64 + t]; hin[64 + t] = h[c * 64 + t]; }
  __syncthreads();
  float acc = eb1[t];
  for (int k = 0; k < 128; ++k) acc += hin[k] * ew1[k * 128 + t];
  hs[t] = silu_f(acc);
  __syncthreads();
  if (t < 64) {
    float o = eb2[t];
    for (int k = 0; k < 128; ++k) o += hs[k] * ew2[k * 64 + t];
    efn[e * 64 + t] = o;
  }
}

// ---------------- K2: constants c1 = MLP1(0), c2 = MLP2(0) -------------------
__global__ __launch_bounds__(128) void k_consts(
    const float* __restrict__ p1b1, const float* __restrict__ p1w2, const float* __restrict__ p1b2,
    const float* __restrict__ p2b1, const float* __restrict__ p2w2, const float* __restrict__ p2b2,
    float* __restrict__ c1, float* __restrict__ c2) {
  __shared__ float h1[128], h2[128];
  int t = threadIdx.x;
  h1[t] = silu_f(p1b1[t]); h2[t] = silu_f(p2b1[t]);
  __syncthreads();
  if (t < 64) {
    float a1 = p1b2[t], a2 = p2b2[t];
    for (int k = 0; k < 128; ++k) { a1 += h1[k] * p1w2[k * 64 + t]; a2 += h2[k] * p2w2[k * 64 + t]; }
    c1[t] = a1; c2[t] = a2;
  }
}

// ---------------- K2b: Wt[h][f] = bf16(p3w1[96+f][h]) (B-operand for MFMA) ---
__global__ __launch_bounds__(256) void k_prep(const float* __restrict__ p3w1,
                                              __hip_bfloat16* __restrict__ Wt) {
  int e = blockIdx.x * 256 + threadIdx.x;   // 8192 = 128 h x 64 f
  int hh = e >> 6, f = e & 63;
  Wt[hh * 64 + f] = __float2bfloat16(p3w1[(96 + f) * 128 + hh]);
}

// ---------------- K3: mark touched cells -------------------------------------
__global__ __launch_bounds__(256) void k_mark(const int* __restrict__ nb_edge,
                                              int* __restrict__ slotmap) {
  int m = blockIdx.x * 256 + threadIdx.x;
  if (m >= MM) return;
  int cell = nb_edge[m] * 512 + nb_edge[MM + m];
  atomicCAS(&slotmap[cell], -1, -2);
}

// ---------------- K4: compact marked cells -> slots, degree histogram --------
__global__ __launch_bounds__(256) void k_compact(int* __restrict__ slotmap,
                                                 int* __restrict__ cells,
                                                 int* __restrict__ nC,
                                                 int* __restrict__ cntA) {
  int cell = blockIdx.x * 256 + threadIdx.x;
  if (slotmap[cell] != -2) return;
  int s = atomicAdd(nC, 1);
  slotmap[cell] = s;
  cells[s] = cell;
  atomicAdd(&cntA[cell >> 9], 1);   // group by first coord a
}

// ---------------- K5: prefix sum for the CSR ---------------------------------
__global__ __launch_bounds__(512) void k_scan(const int* __restrict__ cntA,
                                              int* __restrict__ offA,
                                              int* __restrict__ curA) {
  __shared__ int sA[512];
  int t = threadIdx.x;
  int a0 = cntA[t];
  sA[t] = a0;
  for (int off = 1; off < 512; off <<= 1) {
    __syncthreads();
    int a = (t >= off) ? sA[t - off] : 0;
    __syncthreads();
    sA[t] += a;
  }
  __syncthreads();
  offA[t] = sA[t] - a0;
  curA[t] = sA[t] - a0;
}

// -------- K6: fill CSR list, packing slot | (second-coord << 18) -------------
__global__ __launch_bounds__(256) void k_fill(const int* __restrict__ cells, const int* __restrict__ nC,
                                              int* __restrict__ curA,
                                              int* __restrict__ listAJ) {
  int s = blockIdx.x * 256 + threadIdx.x;
  if (s >= *nC) return;
  int cell = cells[s];
  listAJ[atomicAdd(&curA[cell >> 9], 1)] = s | ((cell & 511) << 18);
}

// ---------------- K7: nb_feat scatter-add into COMPACT Tc (2 edges/block) ----
__global__ __launch_bounds__(192) void k_scatterT(
    const int* __restrict__ nb_edge, const int* __restrict__ slotmap,
    const float* __restrict__ coord_diff, const float* __restrict__ efn,
    float* __restrict__ Tc) {
  int t = threadIdx.x;
  int sub = (t >= 96) ? 1 : 0;
  int c = t - sub * 96;
  int m = blockIdx.x * 2 + sub;
  int a = nb_edge[m], b = nb_edge[MM + m];
  int s = slotmap[a * 512 + b];
  float val;
  if (c < 32) {
    float vtv = coord_diff[a * 3 + 0] * coord_diff[b * 3 + 0]
              + coord_diff[a * 3 + 1] * coord_diff[b * 3 + 1]
              + coord_diff[a * 3 + 2] * coord_diff[b * 3 + 2];
    int i = c >> 1;
    float ang = vtv * 16.0f * __expf(-0.57564627324851143f * (float)i);
    val = (c & 1) ? cosf(ang) : sinf(ang);
  } else {
    int f = c - 32;
    val = efn[a * 64 + f] * efn[b * 64 + f];
  }
  atomicAdd(&Tc[s * 96 + c], val);
}

// ------- K8: batched (8 cells/block) MLPs -> D1/D2, sums A,B; TWc = Tc@w1T ---
__global__ __launch_bounds__(128) void k_mlp96b(
    const int* __restrict__ cells, const int* __restrict__ nC, const float* __restrict__ Tc,
    const float* __restrict__ w11, const float* __restrict__ b11,
    const float* __restrict__ w12, const float* __restrict__ b12,
    const float* __restrict__ w21, const float* __restrict__ b21,
    const float* __restrict__ w22, const float* __restrict__ b22,
    const float* __restrict__ c1, const float* __restrict__ c2,
    const float* __restrict__ p3w1,
    float* __restrict__ D1, float* __restrict__ D2,
    float* __restrict__ A, float* __restrict__ B,
    float* __restrict__ TWc) {
  __shared__ float xsT[96 * 8];    // [k][cell] transposed for b128 reads
  __shared__ float hid[8][128];
  __shared__ int cl[8];
  int t = threadIdx.x;
  int nc = *nC;
  int s0 = blockIdx.x * 8;
  if (s0 >= nc) return;
  for (int e = t; e < 768; e += 128) xsT[(e % 96) * 8 + e / 96] = Tc[s0 * 96 + e];
  if (t < 8) cl[t] = (s0 + t < nc) ? cells[s0 + t] : 0;
  __syncthreads();
  float tw[8], a1[8], a2[8];
#pragma unroll
  for (int c = 0; c < 8; ++c) { tw[c] = 0.f; a1[c] = b11[t]; a2[c] = b21[t]; }
  for (int k = 0; k < 96; ++k) {
    float wt = p3w1[k * 128 + t];
    float w1v = w11[k * 128 + t];
    float w2v = w21[k * 128 + t];
    float4 xlo = *(const float4*)&xsT[k * 8];
    float4 xhi = *(const float4*)&xsT[k * 8 + 4];
    float xv[8] = {xlo.x, xlo.y, xlo.z, xlo.w, xhi.x, xhi.y, xhi.z, xhi.w};
#pragma unroll
    for (int c = 0; c < 8; ++c) {
      tw[c] += xv[c] * wt; a1[c] += xv[c] * w1v; a2[c] += xv[c] * w2v;
    }
  }
#pragma unroll
  for (int c = 0; c < 8; ++c) {
    if (s0 + c < nc) TWc[(s0 + c) * 128 + t] = tw[c];
    hid[c][t] = silu_f(a1[c]);
  }
  __syncthreads();
  {
    int hh = t & 63, cq = t >> 6;
    float o[4];
#pragma unroll
    for (int cc = 0; cc < 4; ++cc) o[cc] = b12[hh];
    for (int k = 0; k < 128; ++k) {
      float w = w12[k * 64 + hh];
#pragma unroll
      for (int cc = 0; cc < 4; ++cc) o[cc] += hid[cq * 4 + cc][k] * w;
    }
#pragma unroll
    for (int cc = 0; cc < 4; ++cc) {
      int c = cq * 4 + cc;
      if (s0 + c < nc) {
        float d = o[cc] - c1[hh];
        D1[(s0 + c) * 64 + hh] = d;
        atomicAdd(&A[(cl[c] >> 9) * 64 + hh], d);
      }
    }
  }
  __syncthreads();
#pragma unroll
  for (int c = 0; c < 8; ++c) hid[c][t] = silu_f(a2[c]);
  __syncthreads();
  {
    int hh = t & 63, cq = t >> 6;
    float o[4];
#pragma unroll
    for (int cc = 0; cc < 4; ++cc) o[cc] = b22[hh];
    for (int k = 0; k < 128; ++k) {
      float w = w22[k * 64 + hh];
#pragma unroll
      for (int cc = 0; cc < 4; ++cc) o[cc] += hid[cq * 4 + cc][k] * w;
    }
#pragma unroll
    for (int cc = 0; cc < 4; ++cc) {
      int c = cq * 4 + cc;
      if (s0 + c < nc) {
        float d = o[cc] - c2[hh];
        D2[(s0 + c) * 64 + hh] = d;
        atomicAdd(&B[(cl[c] & 511) * 64 + hh], d);
      }
    }
  }
}

// ---------------- K10: u[i] = b1 + (512 c1c2 + c2*A[i])@w1m ; v[j] = (c1*B[j])@w1m
__global__ __launch_bounds__(128) void k_uv(
    const float* __restrict__ A, const float* __restrict__ B,
    const float* __restrict__ c1, const float* __restrict__ c2,
    const float* __restrict__ p3w1, const float* __restrict__ p3b1,
    float* __restrict__ u, float* __restrict__ v) {
  __shared__ float vec[64];
  int i = blockIdx.x, y = blockIdx.y, t = threadIdx.x;
  if (t < 64)
    vec[t] = (y == 0) ? (512.0f * c1[t] * c2[t] + c2[t] * A[i * 64 + t])
                      : (c1[t] * B[i * 64 + t]);
  __syncthreads();
  float a = (y == 0) ? p3b1[t] : 0.f;
  for (int f = 0; f < 64; ++f) a += vec[f] * p3w1[(96 + f) * 128 + t];
  (y == 0 ? u : v)[i * 128 + t] = a;
}

// ---------------- K11: S row accumulation, PIPELINED k-steps, no atomics -----
// Block = (row i, quarter of features). 512 thr: p = t&7 -> feature pair,
// g = t>>3 -> 64 j-groups. Step metadata (s1, offA[k], cntA[k]) hoisted to LDS
// up front; 2-stage software pipeline: e2 loaded 2 steps ahead, D1/D2 rows 1
// step ahead -> per-step critical path = LDS RMW + barrier, loads in flight.
// Distinct-j-per-step invariant -> plain b64 RMW. Srow stride 18 spreads banks.
__global__ __launch_bounds__(512) void k_pairs_steps(
    const int* __restrict__ cntA, const int* __restrict__ offA,
    const int* __restrict__ listAJ,
    const float* __restrict__ D1, const float* __restrict__ D2,
    __hip_bfloat16* __restrict__ S) {
  __shared__ float Srow[512 * 18];   // 36,864 B (16 used + 2 pad per j)
  __shared__ int s1s[512], o2s[512], n2s[512];
  int i = blockIdx.x, qt = blockIdx.y;
  int t = threadIdx.x;
  int p = t & 7, g = t >> 3;
  int n1 = cntA[i], o1 = offA[i];
  for (int q = t; q < n1; q += 512) {
    int e1 = listAJ[o1 + q];
    int kv = e1 >> 18;
    s1s[q] = e1 & 0x3FFFF;
    o2s[q] = offA[kv];
    n2s[q] = cntA[kv];
  }
  for (int e = t; e < 9216; e += 512) Srow[e] = 0.f;
  __syncthreads();
  int fofs = qt * 16 + p * 2;
  float2 d1c = make_float2(0.f, 0.f), d2c = make_float2(0.f, 0.f);
  int e2c = 0, e2n = 0;
  bool vc = false, vn = false;
  if (n1 > 0) {               // prologue (chain exposed once)
    d1c = *(const float2*)&D1[s1s[0] * 64 + fofs];
    vc = (g < n2s[0]);
    if (vc) {
      e2c = listAJ[o2s[0] + g];
      d2c = *(const float2*)&D2[(e2c & 0x3FFFF) * 64 + fofs];
    }
  }
  if (n1 > 1) {
    vn = (g < n2s[1]);
    if (vn) e2n = listAJ[o2s[1] + g];
  }
  for (int p1 = 0; p1 < n1; ++p1) {
    // stage 1: e2 for step p1+2
    bool vnn = false; int e2nn = 0;
    if (p1 + 2 < n1) {
      vnn = (g < n2s[p1 + 2]);
      if (vnn) e2nn = listAJ[o2s[p1 + 2] + g];
    }
    // stage 2: d1/d2 for step p1+1 (e2n already resident)
    float2 d1n = make_float2(0.f, 0.f), d2n = make_float2(0.f, 0.f);
    if (p1 + 1 < n1) {
      d1n = *(const float2*)&D1[s1s[p1 + 1] * 64 + fofs];
      if (vn) d2n = *(const float2*)&D2[(e2n & 0x3FFFF) * 64 + fofs];
    }
    // stage 3: compute current step
    if (vc) {
      int j = e2c >> 18;
      int idx = j * 18 + ((p + (j & 7)) & 7) * 2;
      float2 sv = *(float2*)&Srow[idx];
      sv.x += d1c.x * d2c.x; sv.y += d1c.y * d2c.y;
      *(float2*)&Srow[idx] = sv;
    }
    // rare slow path: rows with degree > 64
    int n2 = n2s[p1];
    for (int jj = g + 64; jj < n2; jj += 64) {
      int e2x = listAJ[o2s[p1] + jj];
      float2 d2x = *(const float2*)&D2[(e2x & 0x3FFFF) * 64 + fofs];
      int j = e2x >> 18;
      int idx = j * 18 + ((p + (j & 7)) & 7) * 2;
      float2 sv = *(float2*)&Srow[idx];
      sv.x += d1c.x * d2x.x; sv.y += d1c.y * d2x.y;
      *(float2*)&Srow[idx] = sv;
    }
    __syncthreads();
    d1c = d1n; d2c = d2n; e2c = e2n; vc = vn; e2n = e2nn; vn = vnn;
  }
  for (int e = t; e < 8192; e += 512) {
    int j = e >> 4, f = e & 15;
    int fp = f >> 1;
    float val = Srow[j * 18 + ((fp + (j & 7)) & 7) * 2 + (f & 1)];
    S[(i * 512 + j) * 64 + qt * 16 + f] = __float2bfloat16(val);
  }
}

// ------- K12: MFMA z = S@Wt + u[i]+v[j]+TW, silu, row/col/diag reduce --------
// Block = 8x8 cells (bi,bj); 4 waves; wave w owns cells w*16..w*16+15.
// C layout: h = n0+(lane&15), cell = w*16 + quad*4 + reg  [m89-verified].
__global__ __launch_bounds__(256) void k_tout_mfma(
    const __hip_bfloat16* __restrict__ S, const float* __restrict__ u,
    const float* __restrict__ v, const float* __restrict__ TWc,
    const int* __restrict__ slotmap, const __hip_bfloat16* __restrict__ Wt,
    float* __restrict__ row_part, float* __restrict__ col_part,
    float* __restrict__ diag_silu) {
  __shared__ __hip_bfloat16 WtL[128 * 72];   // 18,432 B (pad 72 -> 2-way banks)
  __shared__ float uvL[2048];                // u rows | v rows, 8 KB
  __shared__ float colbuf[4][8][128];        // 16 KB
  __shared__ int slotL[64];
  int t = threadIdx.x;
  int w = t >> 6, lane = t & 63;
  int q = lane >> 4, l15 = lane & 15;
  int bi = blockIdx.x >> 6, bj = blockIdx.x & 63;
  int i0 = bi * 8, j0 = bj * 8;
  for (int e = t; e < 4096; e += 256) {
    int row = e >> 5, c2 = e & 31;
    ((unsigned*)WtL)[row * 36 + c2] = ((const unsigned*)Wt)[row * 32 + c2];
  }
  for (int e = t; e < 1024; e += 256) uvL[e] = u[(i0 + (e >> 7)) * 128 + (e & 127)];
  for (int e = t; e < 1024; e += 256) uvL[1024 + e] = v[(j0 + (e >> 7)) * 128 + (e & 127)];
  if (t < 64) slotL[t] = slotmap[(i0 + (t >> 3)) * 512 + j0 + (t & 7)];
  int cellA = w * 16 + l15;
  const short8v* sp = (const short8v*)&S[((i0 + (cellA >> 3)) * 512 + j0 + (cellA & 7)) * 64];
  short8v a0 = sp[q];
  short8v a1 = sp[4 + q];
  __syncthreads();
  v4f acc[8];
#pragma unroll
  for (int nt = 0; nt < 8; ++nt) {
    const short8v* b0 = (const short8v*)&WtL[(nt * 16 + l15) * 72 + q * 8];
    const short8v* b1 = (const short8v*)&WtL[(nt * 16 + l15) * 72 + 32 + q * 8];
    v4f c = {0.f, 0.f, 0.f, 0.f};
    c = __builtin_amdgcn_mfma_f32_16x16x32_bf16(a0, *b0, c, 0, 0, 0);
    c = __builtin_amdgcn_mfma_f32_16x16x32_bf16(a1, *b1, c, 0, 0, 0);
    acc[nt] = c;
  }
  float colp[8][4];
#pragma unroll
  for (int nt = 0; nt < 8; ++nt) {
    int hh = nt * 16 + l15;
    float rsum = 0.f;
#pragma unroll
    for (int r = 0; r < 4; ++r) {
      int c = w * 16 + q * 4 + r;
      int iL = c >> 3, jL = c & 7;
      float z = acc[nt][r] + uvL[iL * 128 + hh] + uvL[1024 + jL * 128 + hh];
      int s = slotL[c];
      if (s >= 0) z += TWc[s * 128 + hh];
      float sv = silu_f(z);
      rsum += sv;
      colp[nt][r] = sv + __shfl_xor(sv, 32);
      if (bi == bj && iL == jL) diag_silu[(i0 + iL) * 128 + hh] = sv;
    }
    rsum += __shfl_xor(rsum, 16);
    if ((q & 1) == 0)
      row_part[(bj * 512 + i0 + 2 * w + (q >> 1)) * 128 + hh] = rsum;
  }
  if (q < 2) {
#pragma unroll
    for (int nt = 0; nt < 8; ++nt)
#pragma unroll
      for (int r = 0; r < 4; ++r)
        colbuf[w][q * 4 + r][nt * 16 + l15] = colp[nt][r];
  }
  __syncthreads();
  for (int e = t; e < 1024; e += 256) {
    int jL = e >> 7, hh = e & 127;
    float a = colbuf[0][jL][hh] + colbuf[1][jL][hh] + colbuf[2][jL][hh] + colbuf[3][jL][hh];
    col_part[(bi * 512 + j0 + jL) * 128 + hh] = a;
  }
}

// ---------------- K13: reduce 64 partial slices ------------------------------
__global__ __launch_bounds__(256) void k_sumparts(
    const float* __restrict__ row_part, const float* __restrict__ col_part,
    float* __restrict__ rowsum, float* __restrict__ colsum) {
  int i = blockIdx.x, t = threadIdx.x;
  const float* src = (t < 128) ? row_part : col_part;
  float* dst = (t < 128) ? rowsum : colsum;
  int hc = t & 127;
  float a = 0.f;
  for (int p = 0; p < 64; ++p) a += src[(p * 512 + i) * 128 + hc];
  dst[i * 128 + hc] = a;
}

// ---------------- K14: second layer of p3 MLP on reduced silu sums -----------
__global__ __launch_bounds__(64) void k_tout2(
    const float* __restrict__ diag_silu, const float* __restrict__ rowsum_silu,
    const float* __restrict__ colsum_silu,
    const float* __restrict__ w2, const float* __restrict__ b2,
    float* __restrict__ diag_T, float* __restrict__ row_T, float* __restrict__ col_T) {
  __shared__ float in[128];
  int e = blockIdx.x, which = blockIdx.y, t = threadIdx.x;
  const float* src = (which == 0) ? diag_silu : (which == 1) ? rowsum_silu : colsum_silu;
  in[t] = src[e * 128 + t]; in[64 + t] = src[e * 128 + 64 + t];
  __syncthreads();
  float a = 0.f;
  for (int k = 0; k < 128; ++k) a += in[k] * w2[k * 64 + t];
  float bias = b2[t] * ((which == 0) ? 1.0f : 512.0f);
  float* dst = (which == 0) ? diag_T : (which == 1) ? row_T : col_T;
  dst[e * 64 + t] = a + bias;
}

// ---------------- K15: tot / tr ----------------------------------------------
__global__ __launch_bounds__(128) void k_totr(
    const float* __restrict__ row_T, const float* __restrict__ diag_T,
    float* __restrict__ tot, float* __restrict__ tr) {
  int t = threadIdx.x;
  const float* src = (t < 64) ? row_T : diag_T;
  int f = t & 63;
  float a = 0.f;
  for (int e = 0; e < 512; ++e) a += src[e * 64 + f];
  if (t < 64) tot[f] = a; else tr[f] = a;
}

// ---------------- K16: nb_t1 = [diag|row|col|tot|tr] @ ign_w + ign_b ---------
__global__ __launch_bounds__(64) void k_nbt1(
    const float* __restrict__ diag_T, const float* __restrict__ row_T,
    const float* __restrict__ col_T, const float* __restrict__ tot,
    const float* __restrict__ tr,
    const float* __restrict__ gw, const float* __restrict__ gb,
    float* __restrict__ nb_t1) {
  __shared__ float in[320];
  int e = blockIdx.x, t = threadIdx.x;
  in[t] = diag_T[e * 64 + t]; in[64 + t] = row_T[e * 64 + t];
  in[128 + t] = col_T[e * 64 + t]; in[192 + t] = tot[t]; in[256 + t] = tr[t];
  __syncthreads();
  float a = gb[t];
  for (int k = 0; k < 320; ++k) a += in[k] * gw[k * 64 + t];
  nb_t1[e * 64 + t] = a;
}

// ----- K17: coord weight w_e, seg/cnt/nb_t0 scatters, edge_attr passthrough --
__global__ __launch_bounds__(128) void k_edge_out(
    const int* __restrict__ edges, const float* __restrict__ coord_diff,
    const float* __restrict__ nb_t1, const float* __restrict__ edge_attr,
    const float* __restrict__ cw1, const float* __restrict__ cb1,
    const float* __restrict__ cw2,
    float* __restrict__ seg, float* __restrict__ cnt, float* __restrict__ nb_t0,
    float* __restrict__ out_ea) {
  __shared__ float in[64];
  __shared__ float red[128];
  int e = blockIdx.x, t = threadIdx.x;
  if (t < 64) in[t] = nb_t1[e * 64 + t];
  __syncthreads();
  float a = cb1[t];
  for (int k = 0; k < 64; ++k) a += in[k] * cw1[k * 128 + t];
  red[t] = silu_f(a) * cw2[t];
  __syncthreads();
  for (int s2 = 64; s2 > 0; s2 >>= 1) {
    if (t < s2) red[t] += red[t + s2];
    __syncthreads();
  }
  float w = red[0];
  int r = edges[e];
  if (t < 3) atomicAdd(&seg[r * 3 + t], coord_diff[e * 3 + t] * w);
  if (t == 64) atomicAdd(&cnt[r], 1.0f);
  if (t < 64) atomicAdd(&nb_t0[r * 64 + t], in[t]);
  if (t < 4) out_ea[e * 4 + t] = edge_attr[e * 4 + t];
}

// ---------------- K18: x_new and h_new ---------------------------------------
__global__ __launch_bounds__(128) void k_node_out(
    const float* __restrict__ h, const float* __restrict__ x,
    const float* __restrict__ seg, const float* __restrict__ cnt,
    const float* __restrict__ nb_t0,
    const float* __restrict__ w1, const float* __restrict__ b1,
    const float* __restrict__ w2, const float* __restrict__ b2,
    float* __restrict__ out_h, float* __restrict__ out_x) {
  __shared__ float in[64];
  __shared__ float hs[128];
  int n = blockIdx.x, t = threadIdx.x;
  if (t < 3) {
    float c = cnt[n]; if (c < 1.f) c = 1.f;
    out_x[n * 3 + t] = x[n * 3 + t] + seg[n * 3 + t] / c;
  }
  if (t < 64) in[t] = nb_t0[n * 64 + t];
  __syncthreads();
  float a = b1[t];
  for (int k = 0; k < 64; ++k) a += in[k] * w1[k * 128 + t];
  hs[t] = silu_f(a);
  __syncthreads();
  if (t < 64) {
    float o = b2[t];
    for (int k = 0; k < 128; ++k) o += hs[k] * w2[k * 64 + t];
    out_h[n * 64 + t] = h[n * 64 + t] + o;
  }
}

extern "C" void kernel_launch(void* const* d_in, const int* in_sizes, int n_in,
                              void* d_out, int out_size, void* d_ws, size_t ws_size,
                              hipStream_t stream) {
  (void)in_sizes; (void)n_in; (void)out_size; (void)ws_size;
  const float* h  = (const float*)d_in[0];
  const float* x  = (const float*)d_in[1];
  const int* edges   = (const int*)d_in[2];
  const int* nb_edge = (const int*)d_in[3];
  const float* edge_attr = (const float*)d_in[4];
  const float* ew1 = (const float*)d_in[6],  *eb1 = (const float*)d_in[7];
  const float* ew2 = (const float*)d_in[8],  *eb2 = (const float*)d_in[9];
  const float* p1w1 = (const float*)d_in[10], *p1b1 = (const float*)d_in[11];
  const float* p1w2 = (const float*)d_in[12], *p1b2 = (const float*)d_in[13];
  const float* p2w1 = (const float*)d_in[14], *p2b1 = (const float*)d_in[15];
  const float* p2w2 = (const float*)d_in[16], *p2b2 = (const float*)d_in[17];
  const float* p3w1 = (const float*)d_in[18], *p3b1 = (const float*)d_in[19];
  const float* p3w2 = (const float*)d_in[20], *p3b2 = (const float*)d_in[21];
  const float* ignw = (const float*)d_in[22], *ignb = (const float*)d_in[23];
  const float* cw1 = (const float*)d_in[24], *cb1 = (const float*)d_in[25];
  const float* cw2 = (const float*)d_in[26];
  const float* ndw1 = (const float*)d_in[27], *ndb1 = (const float*)d_in[28];
  const float* ndw2 = (const float*)d_in[29], *ndb2 = (const float*)d_in[30];

  // ---- workspace layout (~94 MB) ----
  char* ws = (char*)d_ws;
  __hip_bfloat16* S = (__hip_bfloat16*)(ws + 0);   // [262144][64] bf16 = 33,554,432 B
  float* row_part = (float*)(ws + 33554432);       // [64][512][128] = 16,777,216 B
  float* col_part = (float*)(ws + 50331648);       // 16,777,216 B
  // ---- single zero-memset block [67,108,864 .. 73,803,792) ----
  float* Tc    = (float*)(ws + 67108864);          // [16384][96] = 6,291,456 B
  int*   cntA  = (int*)(ws + 73400320);            // 512 ints
  int*   nC    = (int*)(ws + 73402368);            // 1 int (+pad)
  float* A     = (float*)(ws + 73402384);          // 32768 floats
  float* B     = (float*)(ws + 73533456);          // 32768 floats
  float* seg   = (float*)(ws + 73664528);          // 1536 floats
  float* cnt   = (float*)(ws + 73670672);          // 512 floats
  float* nb_t0 = (float*)(ws + 73672720);          // 32768 floats -> end 73,803,792
  // ---- rest ----
  int*   slotmap = (int*)(ws + 73803792);          // 262144 ints (memset 0xFF)
  int*   cells   = (int*)(ws + 74852368);          // 16384 ints
  int*   offA    = (int*)(ws + 74917904);          // 512 ints
  int*   curA    = (int*)(ws + 74919952);          // 512 ints
  int*   listAJ  = (int*)(ws + 74922000);          // 16384 ints
  float* D1      = (float*)(ws + 74987536);        // [16384][64]
  float* D2      = (float*)(ws + 79181840);        // [16384][64]
  float* TWc     = (float*)(ws + 83376144);        // [16384][128]
  float* c1      = (float*)(ws + 91764752);        // 64
  float* c2      = (float*)(ws + 91765008);        // 64
  float* u       = (float*)(ws + 91765264);        // [512][128]
  float* v       = (float*)(ws + 92027408);        // [512][128]
  float* coord_diff  = (float*)(ws + 92289552);    // [512][3]
  float* efn         = (float*)(ws + 92295696);    // [512][64]
  float* diag_silu   = (float*)(ws + 92426768);    // [512][128]
  float* rowsum_silu = (float*)(ws + 92688912);
  float* colsum_silu = (float*)(ws + 92951056);
  float* diag_T      = (float*)(ws + 93213200);    // [512][64]
  float* row_T       = (float*)(ws + 93344272);
  float* col_T       = (float*)(ws + 93475344);
  float* tot         = (float*)(ws + 93606416);    // 64
  float* tr          = (float*)(ws + 93606672);    // 64
  float* nb_t1       = (float*)(ws + 93606928);    // [512][64] -> end 93,738,000
  __hip_bfloat16* Wt = (__hip_bfloat16*)(ws + 93738000);  // [128][64] bf16 = 16,384 B

  float* out_h  = (float*)d_out;
  float* out_x  = out_h + 512 * 64;
  float* out_ea = out_x + 512 * 3;

  hipMemsetAsync(slotmap, 0xFF, 1048576, stream);          // -1
  hipMemsetAsync(ws + 67108864, 0, 6694928, stream);       // Tc..nb_t0

  k_edge<<<512, 128, 0, stream>>>(h, x, edges, ew1, eb1, ew2, eb2, coord_diff, efn);
  k_consts<<<1, 128, 0, stream>>>(p1b1, p1w2, p1b2, p2b1, p2w2, p2b2, c1, c2);
  k_prep<<<32, 256, 0, stream>>>(p3w1, Wt);
  k_mark<<<64, 256, 0, stream>>>(nb_edge, slotmap);
  k_compact<<<1024, 256, 0, stream>>>(slotmap, cells, nC, cntA);
  k_scan<<<1, 512, 0, stream>>>(cntA, offA, curA);
  k_fill<<<64, 256, 0, stream>>>(cells, nC, curA, listAJ);
  k_scatterT<<<8192, 192, 0, stream>>>(nb_edge, slotmap, coord_diff, efn, Tc);
  k_mlp96b<<<2048, 128, 0, stream>>>(cells, nC, Tc,
                                     p1w1, p1b1, p1w2, p1b2,
                                     p2w1, p2b1, p2w2, p2b2,
                                     c1, c2, p3w1, D1, D2, A, B, TWc);
  k_uv<<<dim3(512, 2), 128, 0, stream>>>(A, B, c1, c2, p3w1, p3b1, u, v);
  k_pairs_steps<<<dim3(512, 4), 512, 0, stream>>>(cntA, offA, listAJ, D1, D2, S);
  k_tout_mfma<<<4096, 256, 0, stream>>>(S, u, v, TWc, slotmap, Wt,
                                        row_part, col_part, diag_silu);
  k_sumparts<<<512, 256, 0, stream>>>(row_part, col_part, rowsum_silu, colsum_silu);
  k_tout2<<<dim3(512, 3), 64, 0, stream>>>(diag_silu, rowsum_silu, colsum_silu,
                                           p3w2, p3b2, diag_T, row_T, col_T);
  k_totr<<<1, 128, 0, stream>>>(row_T, diag_T, tot, tr);
  k_nbt1<<<512, 64, 0, stream>>>(diag_T, row_T, col_T, tot, tr, ignw, ignb, nb_t1);
  k_edge_out<<<512, 128, 0, stream>>>(edges, coord_diff, nb_t1, edge_attr,
                                      cw1, cb1, cw2, seg, cnt, nb_t0, out_ea);
  k_node_out<<<512, 128, 0, stream>>>(h, x, seg, cnt, nb_t0,
                                      ndw1, ndb1, ndw2, ndb2, out_h, out_x);
}